// Round 1
// baseline (751.328 us; speedup 1.0000x reference)
//
#include <hip/hip_runtime.h>
#include <math.h>

// Problem constants (fixed by reference: B=4, L=2048, D=512, H=8, dk=64, FACTOR=5)
constexpr int Bn  = 4;
constexpr int Ln  = 2048;
constexpr int Dn  = 512;
constexpr int Hn  = 8;
constexpr int DKn = 64;
constexpr int US  = 40;   // U = min(5*ceil(ln(2049)), 2048) = 40
constexpr int UT  = 40;   // u = 40 (top-k count)
constexpr int NCk = 8;    // key chunks for sparse attention
constexpr int CKn = 256;  // keys per chunk (NCk*CKn == Ln)

// ---------------------------------------------------------------------------
// f32 NT GEMM: C[m,n] = sum_k A[m,k]*W[n,k] + bias[n];  M=8192, N=512, K=512
// mode 0: write to (B,H,L,dk) layout (projections). mode 1: row-major.
// ---------------------------------------------------------------------------
#define TM 128
#define TN 128
#define TK 16

__global__ __launch_bounds__(256) void gemm_nt(const float* __restrict__ A,
    const float* __restrict__ W, const float* __restrict__ bias,
    float* __restrict__ out, int mode)
{
  __shared__ float sA[TK][TM + 4];
  __shared__ float sB[TK][TN + 4];
  const int tid = threadIdx.x;
  const int m0 = blockIdx.y * TM, n0 = blockIdx.x * TN;
  const int tx = tid & 15, ty = tid >> 4;
  const int lr = tid >> 2, lc = (tid & 3) << 2;
  float acc[8][8] = {};

  for (int k0 = 0; k0 < 512; k0 += TK) {
#pragma unroll
    for (int it = 0; it < 2; ++it) {
      int m = m0 + lr + it * 64;
      float4 av = *reinterpret_cast<const float4*>(A + (size_t)m * 512 + k0 + lc);
      sA[lc + 0][lr + it * 64] = av.x; sA[lc + 1][lr + it * 64] = av.y;
      sA[lc + 2][lr + it * 64] = av.z; sA[lc + 3][lr + it * 64] = av.w;
      int n = n0 + lr + it * 64;
      float4 bv = *reinterpret_cast<const float4*>(W + (size_t)n * 512 + k0 + lc);
      sB[lc + 0][lr + it * 64] = bv.x; sB[lc + 1][lr + it * 64] = bv.y;
      sB[lc + 2][lr + it * 64] = bv.z; sB[lc + 3][lr + it * 64] = bv.w;
    }
    __syncthreads();
#pragma unroll
    for (int k = 0; k < TK; ++k) {
      // split each 8-wide per-thread range into [4*t, 4*t+4) and [64+4*t, ...)
      // so one b-read instruction spreads across all 8 bank-quads (2-way, free)
      float4 a0 = *reinterpret_cast<const float4*>(&sA[k][ty * 4]);
      float4 a1 = *reinterpret_cast<const float4*>(&sA[k][64 + ty * 4]);
      float4 b0 = *reinterpret_cast<const float4*>(&sB[k][tx * 4]);
      float4 b1 = *reinterpret_cast<const float4*>(&sB[k][64 + tx * 4]);
      float a[8] = {a0.x, a0.y, a0.z, a0.w, a1.x, a1.y, a1.z, a1.w};
      float b[8] = {b0.x, b0.y, b0.z, b0.w, b1.x, b1.y, b1.z, b1.w};
#pragma unroll
      for (int i = 0; i < 8; ++i)
#pragma unroll
        for (int j = 0; j < 8; ++j) acc[i][j] += a[i] * b[j];
    }
    __syncthreads();
  }

#pragma unroll
  for (int i = 0; i < 8; ++i) {
    int m = m0 + ((i < 4) ? (ty * 4 + i) : (64 + ty * 4 + (i - 4)));
#pragma unroll
    for (int j = 0; j < 8; ++j) {
      int n = n0 + ((j < 4) ? (tx * 4 + j) : (64 + tx * 4 + (j - 4)));
      float v = acc[i][j] + bias[n];
      if (mode == 0) {
        int b = m >> 11, l = m & 2047, h = n >> 6, dd = n & 63;
        out[(size_t)((b * Hn + h) * Ln + l) * DKn + dd] = v;
      } else {
        out[(size_t)m * Dn + n] = v;
      }
    }
  }
}

// ---------------------------------------------------------------------------
// meanV[bh][d] = mean_l V[bh][l][d]
// ---------------------------------------------------------------------------
__global__ __launch_bounds__(256) void vmean(const float* __restrict__ Vf,
                                             float* __restrict__ meanV)
{
  int bh = blockIdx.x;
  int d = threadIdx.x & 63, sub = threadIdx.x >> 6;
  __shared__ float red[4][64];
  float s = 0.f;
  for (int l = sub; l < Ln; l += 4) s += Vf[(size_t)(bh * Ln + l) * DKn + d];
  red[sub][d] = s;
  __syncthreads();
  if (sub == 0) {
    float tot = red[0][d] + red[1][d] + red[2][d] + red[3][d];
    meanV[bh * DKn + d] = tot * (1.f / 2048.f);
  }
}

// ---------------------------------------------------------------------------
// M[bh][q] = max_u(Q[q]·K[idx_u]) - sum_u(Q[q]·K[idx_u]) / LK
// one wave per query, lane = u (40 of 64 active)
// ---------------------------------------------------------------------------
__global__ __launch_bounds__(256) void qk_sample_m(const float* __restrict__ Qf,
    const float* __restrict__ Kf, const int* __restrict__ isamp,
    float* __restrict__ Mout)
{
  int wq = blockIdx.x * 4 + (threadIdx.x >> 6);  // global q over B*H*L
  int lane = threadIdx.x & 63;
  int bh = wq >> 11, q = wq & 2047;
  const float* Qrow = Qf + (size_t)(bh * Ln + q) * DKn;
  float dot;
  if (lane < US) {
    int idx = isamp[q * US + lane];
    const float* Krow = Kf + (size_t)(bh * Ln + idx) * DKn;
    float s = 0.f;
#pragma unroll
    for (int g = 0; g < 16; ++g) {
      float4 kv = *reinterpret_cast<const float4*>(&Krow[g * 4]);
      float4 qv = *reinterpret_cast<const float4*>(&Qrow[g * 4]);
      s += qv.x * kv.x + qv.y * kv.y + qv.z * kv.z + qv.w * kv.w;
    }
    dot = s;
  } else {
    dot = -INFINITY;
  }
  float mx = dot, sm = (lane < US) ? dot : 0.f;
#pragma unroll
  for (int off = 32; off; off >>= 1) {
    mx = fmaxf(mx, __shfl_xor(mx, off));
    sm += __shfl_xor(sm, off);
  }
  if (lane == 0) Mout[wq] = mx - sm * (1.f / 2048.f);
}

// ---------------------------------------------------------------------------
// top-40 indices of M[bh][0..2047] (iterative argmax; tie -> lower index)
// ---------------------------------------------------------------------------
__global__ __launch_bounds__(256) void topk40(const float* __restrict__ Mv,
                                              int* __restrict__ Mtop)
{
  int bh = blockIdx.x, tid = threadIdx.x;
  __shared__ float v[2048];
  __shared__ float rv[256];
  __shared__ int ri[256];
  for (int i = tid; i < 2048; i += 256) v[i] = Mv[bh * Ln + i];
  __syncthreads();
  for (int sel = 0; sel < UT; ++sel) {
    float best = -INFINITY;
    int bidx = 1 << 30;
    for (int i = tid; i < 2048; i += 256) {
      if (v[i] > best) { best = v[i]; bidx = i; }
    }
    rv[tid] = best; ri[tid] = bidx;
    __syncthreads();
    for (int s = 128; s > 0; s >>= 1) {
      if (tid < s) {
        float ov = rv[tid + s]; int oi = ri[tid + s];
        if (ov > rv[tid] || (ov == rv[tid] && oi < ri[tid])) { rv[tid] = ov; ri[tid] = oi; }
      }
      __syncthreads();
    }
    if (tid == 0) { Mtop[bh * UT + sel] = ri[0]; v[ri[0]] = -INFINITY; }
    __syncthreads();
  }
}

// ---------------------------------------------------------------------------
// Sparse attention, chunked: block (bh, c) handles 256 keys for all 40
// selected queries; emits partial (m, l, acc[64]) per (bh, c, i).
// ---------------------------------------------------------------------------
__global__ __launch_bounds__(256) void attn_partial(const float* __restrict__ Qf,
    const float* __restrict__ Kf, const float* __restrict__ Vf,
    const int* __restrict__ Mtop, float* __restrict__ pmv,
    float* __restrict__ plv, float* __restrict__ pacc)
{
  const int bh = blockIdx.x, c = blockIdx.y;
  const int tid = threadIdx.x;
  const int w = tid >> 6, lane = tid & 63;
  __shared__ float sQ[UT][DKn];   // 10 KB
  __shared__ float sS[UT][CKn];   // 40 KB (scores -> exp(p))
  __shared__ float sK[64 * 64];   // 16 KB, XOR-swizzled

  for (int i = tid; i < UT * DKn; i += 256) {
    int r = i >> 6, d = i & 63;
    sQ[r][d] = Qf[(size_t)(bh * Ln + Mtop[bh * UT + r]) * DKn + d];
  }
  __syncthreads();

  const float* Kc = Kf + (size_t)(bh * Ln + c * CKn) * DKn;
  for (int sub = 0; sub < 4; ++sub) {
    for (int i = tid; i < 64 * DKn; i += 256) {
      int r = i >> 6, d = i & 63;
      sK[r * 64 + (d ^ ((r & 7) << 2))] = Kc[(size_t)(sub * 64 + r) * DKn + d];
    }
    __syncthreads();
    for (int it = 0; it < 10; ++it) {   // i = w + 4*it (wave-uniform), kk = lane
      int i = w + it * 4, kk = lane;
      float s = 0.f;
#pragma unroll
      for (int g = 0; g < 16; ++g) {
        float4 qv = *reinterpret_cast<const float4*>(&sQ[i][g * 4]);
        float4 kv = *reinterpret_cast<const float4*>(&sK[kk * 64 + ((g * 4) ^ ((kk & 7) << 2))]);
        s += qv.x * kv.x + qv.y * kv.y + qv.z * kv.z + qv.w * kv.w;
      }
      sS[i][sub * 64 + kk] = s * 0.125f;
    }
    __syncthreads();
  }

  // partial softmax per row
  for (int it = 0; it < 10; ++it) {
    int i = w + it * 4;
    float s0 = sS[i][lane], s1 = sS[i][lane + 64];
    float s2 = sS[i][lane + 128], s3 = sS[i][lane + 192];
    float mx = fmaxf(fmaxf(s0, s1), fmaxf(s2, s3));
#pragma unroll
    for (int off = 32; off; off >>= 1) mx = fmaxf(mx, __shfl_xor(mx, off));
    float p0 = expf(s0 - mx), p1 = expf(s1 - mx);
    float p2 = expf(s2 - mx), p3 = expf(s3 - mx);
    sS[i][lane] = p0; sS[i][lane + 64] = p1;
    sS[i][lane + 128] = p2; sS[i][lane + 192] = p3;
    float ls = p0 + p1 + p2 + p3;
#pragma unroll
    for (int off = 32; off; off >>= 1) ls += __shfl_xor(ls, off);
    if (lane == 0) {
      pmv[(bh * NCk + c) * UT + i] = mx;
      plv[(bh * NCk + c) * UT + i] = ls;
    }
  }
  __syncthreads();

  // PV partial: lane = (ksub, dq); V read straight from global (coalesced 1KB)
  const int ksub = lane >> 4, dq = lane & 15;
  const float* Vc = Vf + (size_t)(bh * Ln + c * CKn) * DKn;
  float4 acc[10];
#pragma unroll
  for (int t = 0; t < 10; ++t) acc[t] = make_float4(0.f, 0.f, 0.f, 0.f);
  for (int ko = 0; ko < 64; ++ko) {
    int kk = ko * 4 + ksub;
    float4 v4 = *reinterpret_cast<const float4*>(&Vc[(size_t)kk * DKn + dq * 4]);
#pragma unroll
    for (int t = 0; t < 10; ++t) {
      float wgt = sS[w + t * 4][kk];
      acc[t].x += wgt * v4.x; acc[t].y += wgt * v4.y;
      acc[t].z += wgt * v4.z; acc[t].w += wgt * v4.w;
    }
  }
#pragma unroll
  for (int t = 0; t < 10; ++t) {
#pragma unroll
    for (int off = 16; off <= 32; off <<= 1) {
      acc[t].x += __shfl_xor(acc[t].x, off);
      acc[t].y += __shfl_xor(acc[t].y, off);
      acc[t].z += __shfl_xor(acc[t].z, off);
      acc[t].w += __shfl_xor(acc[t].w, off);
    }
  }
  if (ksub == 0) {
#pragma unroll
    for (int t = 0; t < 10; ++t) {
      int i = w + t * 4;
      *reinterpret_cast<float4*>(&pacc[(size_t)((bh * NCk + c) * UT + i) * DKn + dq * 4]) = acc[t];
    }
  }
}

// ---------------------------------------------------------------------------
// base[b][n] = meanrow_b @ Wo.T + bo   (meanV[b*512 + k] IS meanrow_b[k])
// ---------------------------------------------------------------------------
__global__ __launch_bounds__(256) void base_proj(const float* __restrict__ meanV,
    const float* __restrict__ Wo, const float* __restrict__ bo,
    float* __restrict__ base)
{
  int b = blockIdx.x, tid = threadIdx.x;
#pragma unroll
  for (int rep = 0; rep < 2; ++rep) {
    int n = tid + rep * 256;
    float s = bo[n];
#pragma unroll 8
    for (int g = 0; g < 128; ++g) {
      float4 wv = *reinterpret_cast<const float4*>(&Wo[(size_t)n * Dn + g * 4]);
      float4 mv = *reinterpret_cast<const float4*>(&meanV[b * Dn + g * 4]);
      s += wv.x * mv.x + wv.y * mv.y + wv.z * mv.z + wv.w * mv.w;
    }
    base[b * Dn + n] = s;
  }
}

__global__ __launch_bounds__(256) void base_fill(const float* __restrict__ base,
                                                 float* __restrict__ out)
{
  int idx = blockIdx.x * 256 + threadIdx.x;  // float4 index, 1048576 total
  int row = idx >> 7, col4 = idx & 127;
  int b = row >> 11;
  reinterpret_cast<float4*>(out)[idx] =
      reinterpret_cast<const float4*>(base)[b * 128 + col4];
}

// ---------------------------------------------------------------------------
// combine partials -> context row; delta = row - meanV; scatter-add
// delta @ Wo_hblock into the output row (only this h's input block changes).
// ---------------------------------------------------------------------------
__global__ __launch_bounds__(256) void combine_scatter(const float* __restrict__ pmv,
    const float* __restrict__ plv, const float* __restrict__ pacc,
    const int* __restrict__ Mtop, const float* __restrict__ meanV,
    const float* __restrict__ Wo, float* __restrict__ out)
{
  int bi = blockIdx.x;            // 0..1279
  int bh = bi / UT, i = bi % UT;
  int b = bh >> 3, h = bh & 7;
  int tid = threadIdx.x;
  __shared__ float v[DKn];
  if (tid < 64) {
    int d = tid;
    float mg = -INFINITY;
#pragma unroll
    for (int cc = 0; cc < NCk; ++cc) mg = fmaxf(mg, pmv[(bh * NCk + cc) * UT + i]);
    float den = 0.f, num = 0.f;
#pragma unroll
    for (int cc = 0; cc < NCk; ++cc) {
      float e = expf(pmv[(bh * NCk + cc) * UT + i] - mg);
      den += plv[(bh * NCk + cc) * UT + i] * e;
      num += e * pacc[(size_t)((bh * NCk + cc) * UT + i) * DKn + d];
    }
    v[d] = num / den - meanV[bh * DKn + d];
  }
  __syncthreads();
  int q = Mtop[bh * UT + i];
  float* orow = out + (size_t)(b * Ln + q) * Dn;
  const float* Wh = Wo + h * DKn;
#pragma unroll
  for (int rep = 0; rep < 2; ++rep) {
    int n = tid + rep * 256;
    float s = 0.f;
#pragma unroll
    for (int g = 0; g < 16; ++g) {
      float4 wv = *reinterpret_cast<const float4*>(&Wh[(size_t)n * Dn + g * 4]);
      float4 vv = *reinterpret_cast<const float4*>(&v[g * 4]);
      s += wv.x * vv.x + wv.y * vv.y + wv.z * vv.z + wv.w * vv.w;
    }
    atomicAdd(&orow[n], s);
  }
}

// ---------------------------------------------------------------------------
extern "C" void kernel_launch(void* const* d_in, const int* in_sizes, int n_in,
                              void* d_out, int out_size, void* d_ws, size_t ws_size,
                              hipStream_t stream)
{
  const float* queries = (const float*)d_in[0];
  const float* keys    = (const float*)d_in[1];
  const float* values  = (const float*)d_in[2];
  const float* Wq = (const float*)d_in[3];
  const float* bq = (const float*)d_in[4];
  const float* Wk = (const float*)d_in[5];
  const float* bk = (const float*)d_in[6];
  const float* Wv = (const float*)d_in[7];
  const float* bv = (const float*)d_in[8];
  const float* Wo = (const float*)d_in[9];
  const float* bo = (const float*)d_in[10];
  const int* isamp = (const int*)d_in[11];
  float* out = (float*)d_out;

  float* ws = (float*)d_ws;
  const size_t NBL = (size_t)Bn * Hn * Ln * DKn;  // 4194304
  float* Qf    = ws;
  float* Kf    = Qf + NBL;
  float* Vf    = Kf + NBL;
  float* meanV = Vf + NBL;                       // 2048
  float* Mv    = meanV + Bn * Hn * DKn;          // 65536
  float* pmv   = Mv + Bn * Hn * Ln;              // 10240
  float* plv   = pmv + Bn * Hn * NCk * UT;       // 10240
  float* pacc  = plv + Bn * Hn * NCk * UT;       // 655360
  float* base  = pacc + (size_t)Bn * Hn * NCk * UT * DKn;  // 2048
  int* Mtop    = (int*)(base + Bn * Dn);         // 1280 ints

  dim3 gg(4, 64);  // (N/128, M/128)
  gemm_nt<<<gg, 256, 0, stream>>>(queries, Wq, bq, Qf, 0);
  gemm_nt<<<gg, 256, 0, stream>>>(keys,    Wk, bk, Kf, 0);
  gemm_nt<<<gg, 256, 0, stream>>>(values,  Wv, bv, Vf, 0);
  vmean<<<Bn * Hn, 256, 0, stream>>>(Vf, meanV);
  qk_sample_m<<<Bn * Hn * Ln / 4, 256, 0, stream>>>(Qf, Kf, isamp, Mv);
  topk40<<<Bn * Hn, 256, 0, stream>>>(Mv, Mtop);
  attn_partial<<<dim3(Bn * Hn, NCk), 256, 0, stream>>>(Qf, Kf, Vf, Mtop, pmv, plv, pacc);
  base_proj<<<Bn, 256, 0, stream>>>(meanV, Wo, bo, base);
  base_fill<<<4096, 256, 0, stream>>>(base, out);
  combine_scatter<<<Bn * Hn * UT, 256, 0, stream>>>(pmv, plv, pacc, Mtop, meanV, Wo, out);
}

// Round 2
// 534.684 us; speedup vs baseline: 1.4052x; 1.4052x over previous
//
#include <hip/hip_runtime.h>
#include <math.h>

// Problem constants (fixed by reference: B=4, L=2048, D=512, H=8, dk=64, FACTOR=5)
constexpr int Bn  = 4;
constexpr int Ln  = 2048;
constexpr int Dn  = 512;
constexpr int Hn  = 8;
constexpr int DKn = 64;
constexpr int US  = 40;   // U = min(5*ceil(ln(2049)), 2048) = 40
constexpr int UT  = 40;   // u = 40 (top-k count)
constexpr int NCk = 8;    // key chunks for sparse attention
constexpr int CKn = 256;  // keys per chunk (NCk*CKn == Ln)

typedef unsigned short ushort_t;

// ---------------------------------------------------------------------------
// bf16 split helpers (RNE)
// ---------------------------------------------------------------------------
__device__ __forceinline__ ushort_t f2bf_rne(float x) {
  unsigned u = __float_as_uint(x);
  unsigned r = u + 0x7fffu + ((u >> 16) & 1u);
  return (ushort_t)(r >> 16);
}
__device__ __forceinline__ float bf2f(ushort_t h) {
  return __uint_as_float(((unsigned)h) << 16);
}

// X f32 [8192][512] -> A ushort [8192][1024] = [hi | lo]
__global__ __launch_bounds__(256) void split_in(const float* __restrict__ X,
                                                ushort_t* __restrict__ A)
{
  int i = blockIdx.x * 256 + threadIdx.x;      // 0..1048575
  int m = i >> 7, c4 = (i & 127) << 2;
  float4 x = *reinterpret_cast<const float4*>(&X[(size_t)m * 512 + c4]);
  ushort_t h0 = f2bf_rne(x.x), h1 = f2bf_rne(x.y), h2 = f2bf_rne(x.z), h3 = f2bf_rne(x.w);
  ushort_t l0 = f2bf_rne(x.x - bf2f(h0)), l1 = f2bf_rne(x.y - bf2f(h1));
  ushort_t l2 = f2bf_rne(x.z - bf2f(h2)), l3 = f2bf_rne(x.w - bf2f(h3));
  *reinterpret_cast<ushort4*>(&A[(size_t)m * 1024 + c4])       = make_ushort4(h0, h1, h2, h3);
  *reinterpret_cast<ushort4*>(&A[(size_t)m * 1024 + 512 + c4]) = make_ushort4(l0, l1, l2, l3);
}

// W f32 [512][512] -> Wcat ushort [512][1536] = [hi | lo | hi]
__global__ __launch_bounds__(256) void split_w(const float* __restrict__ W,
                                               ushort_t* __restrict__ Wc)
{
  int i = blockIdx.x * 256 + threadIdx.x;      // 0..65535
  int n = i >> 7, c4 = (i & 127) << 2;
  float4 x = *reinterpret_cast<const float4*>(&W[(size_t)n * 512 + c4]);
  ushort_t h0 = f2bf_rne(x.x), h1 = f2bf_rne(x.y), h2 = f2bf_rne(x.z), h3 = f2bf_rne(x.w);
  ushort_t l0 = f2bf_rne(x.x - bf2f(h0)), l1 = f2bf_rne(x.y - bf2f(h1));
  ushort_t l2 = f2bf_rne(x.z - bf2f(h2)), l3 = f2bf_rne(x.w - bf2f(h3));
  ushort4 hv = make_ushort4(h0, h1, h2, h3);
  ushort4 lv = make_ushort4(l0, l1, l2, l3);
  *reinterpret_cast<ushort4*>(&Wc[(size_t)n * 1536 + c4])        = hv;
  *reinterpret_cast<ushort4*>(&Wc[(size_t)n * 1536 + 512 + c4])  = lv;
  *reinterpret_cast<ushort4*>(&Wc[(size_t)n * 1536 + 1024 + c4]) = hv;
}

// ---------------------------------------------------------------------------
// bf16 3-term MFMA NT GEMM: C[m,n] = sum over logical K=1536 of
// Acat[m,k]*Wcat[n,k] + bias[n].  A storage is [hi|lo] (1024 wide): k-blocks
// [0,512)->hi, [512,1024)->hi, [1024,1536)->lo.  B storage [hi|lo|hi] (1536).
// Tile 64(M)x128(N), BK=64, 4 waves (each 32x64), grid (4, 128).
// Output scatter to (B,H,L,dk).
// ---------------------------------------------------------------------------
using bf16x8 = short __attribute__((ext_vector_type(8)));
using f32x4  = float __attribute__((ext_vector_type(4)));

__device__ __forceinline__ void gload_lds16(const void* g, void* l) {
  __builtin_amdgcn_global_load_lds((const __attribute__((address_space(1))) void*)g,
                                   (__attribute__((address_space(3))) void*)l, 16, 0, 0);
}

__global__ __launch_bounds__(256) void gemm3_bf16(const ushort_t* __restrict__ Ast,
    const ushort_t* __restrict__ Bst, const float* __restrict__ bias,
    float* __restrict__ out)
{
  __shared__ __attribute__((aligned(16))) ushort_t sA[64 * 64];    // 8 KB
  __shared__ __attribute__((aligned(16))) ushort_t sB[128 * 64];   // 16 KB
  const int tid = threadIdx.x;
  const int w = tid >> 6, lane = tid & 63;
  const int m0 = blockIdx.y * 64, n0 = blockIdx.x * 128;
  const int wr = w >> 1, wc = w & 1;          // wave subtile (wr*32, wc*64)
  const int r16 = lane & 15, ko = (lane >> 4) * 8;

  f32x4 acc[2][4];
#pragma unroll
  for (int m = 0; m < 2; ++m)
#pragma unroll
    for (int n = 0; n < 4; ++n) acc[m][n] = (f32x4){0.f, 0.f, 0.f, 0.f};

  for (int k0 = 0; k0 < 1536; k0 += 64) {
    const int ka0 = (k0 < 1024) ? (k0 & 511) : (k0 - 512);
    __syncthreads();   // previous compute done before LDS overwrite
#pragma unroll
    for (int i = 0; i < 2; ++i) {              // stage A: 64 rows x 64 cols
      int e = i * 256 + tid, r = e >> 3, c8 = e & 7;
      gload_lds16(Ast + (size_t)(m0 + r) * 1024 + ka0 + c8 * 8,
                  (void*)(sA + (size_t)(i * 256 + w * 64) * 8));
    }
#pragma unroll
    for (int i = 0; i < 4; ++i) {              // stage B: 128 rows x 64 cols
      int e = i * 256 + tid, r = e >> 3, c8 = e & 7;
      gload_lds16(Bst + (size_t)(n0 + r) * 1536 + k0 + c8 * 8,
                  (void*)(sB + (size_t)(i * 256 + w * 64) * 8));
    }
    __syncthreads();   // drains vmcnt(0) before barrier
#pragma unroll
    for (int kk = 0; kk < 64; kk += 32) {
      bf16x8 a[2], b[4];
#pragma unroll
      for (int m = 0; m < 2; ++m)
        a[m] = *reinterpret_cast<const bf16x8*>(&sA[(wr * 32 + m * 16 + r16) * 64 + kk + ko]);
#pragma unroll
      for (int n = 0; n < 4; ++n)
        b[n] = *reinterpret_cast<const bf16x8*>(&sB[(wc * 64 + n * 16 + r16) * 64 + kk + ko]);
#pragma unroll
      for (int m = 0; m < 2; ++m)
#pragma unroll
        for (int n = 0; n < 4; ++n)
          acc[m][n] = __builtin_amdgcn_mfma_f32_16x16x32_bf16(a[m], b[n], acc[m][n], 0, 0, 0);
    }
  }

  // epilogue: C row = (lane>>4)*4 + reg, col = lane&15 (m89-verified layout)
#pragma unroll
  for (int m = 0; m < 2; ++m) {
#pragma unroll
    for (int n = 0; n < 4; ++n) {
#pragma unroll
      for (int r = 0; r < 4; ++r) {
        int row = m0 + wr * 32 + m * 16 + (lane >> 4) * 4 + r;
        int col = n0 + wc * 64 + n * 16 + (lane & 15);
        float v = acc[m][n][r] + bias[col];
        int b = row >> 11, l = row & 2047, h = col >> 6, dd = col & 63;
        out[(size_t)((b * Hn + h) * Ln + l) * DKn + dd] = v;
      }
    }
  }
}

// ---------------------------------------------------------------------------
// meanV[bh][d] = mean_l V[bh][l][d]
// ---------------------------------------------------------------------------
__global__ __launch_bounds__(256) void vmean(const float* __restrict__ Vf,
                                             float* __restrict__ meanV)
{
  int bh = blockIdx.x;
  int d = threadIdx.x & 63, sub = threadIdx.x >> 6;
  __shared__ float red[4][64];
  float s = 0.f;
  for (int l = sub; l < Ln; l += 4) s += Vf[(size_t)(bh * Ln + l) * DKn + d];
  red[sub][d] = s;
  __syncthreads();
  if (sub == 0) {
    float tot = red[0][d] + red[1][d] + red[2][d] + red[3][d];
    meanV[bh * DKn + d] = tot * (1.f / 2048.f);
  }
}

// ---------------------------------------------------------------------------
// M[bh][q] = max_u(Q[q]·K[idx_u]) - sum_u(Q[q]·K[idx_u]) / LK
// one wave per query; lanes as (group g=lane>>4, s=lane&15); each group
// cooperatively loads one K row per pass (coalesced 256B), 10 passes.
// ---------------------------------------------------------------------------
__global__ __launch_bounds__(256) void qk_sample_m2(const float* __restrict__ Qf,
    const float* __restrict__ Kf, const int* __restrict__ isamp,
    float* __restrict__ Mout)
{
  int wq = blockIdx.x * 4 + (threadIdx.x >> 6);  // global q over B*H*L
  int lane = threadIdx.x & 63;
  int g = lane >> 4, s = lane & 15;
  int bh = wq >> 11, q = wq & 2047;
  const float* Kb = Kf + (size_t)bh * Ln * DKn;
  float4 qv = *reinterpret_cast<const float4*>(&Qf[(size_t)(bh * Ln + q) * DKn + s * 4]);
  float mx = -INFINITY, sm = 0.f;
#pragma unroll
  for (int p = 0; p < 10; ++p) {
    int u = p * 4 + g;
    int idx = isamp[q * US + u];
    float4 kv = *reinterpret_cast<const float4*>(&Kb[(size_t)idx * DKn + s * 4]);
    float d = qv.x * kv.x + qv.y * kv.y + qv.z * kv.z + qv.w * kv.w;
#pragma unroll
    for (int off = 1; off < 16; off <<= 1) d += __shfl_xor(d, off);
    mx = fmaxf(mx, d);
    sm += d;
  }
#pragma unroll
  for (int off = 16; off <= 32; off <<= 1) {
    mx = fmaxf(mx, __shfl_xor(mx, off));
    sm += __shfl_xor(sm, off);
  }
  if (lane == 0) Mout[wq] = mx - sm * (1.f / 2048.f);
}

// ---------------------------------------------------------------------------
// top-40 indices of M[bh][0..2047] (iterative argmax; tie -> lower index)
// ---------------------------------------------------------------------------
__global__ __launch_bounds__(256) void topk40(const float* __restrict__ Mv,
                                              int* __restrict__ Mtop)
{
  int bh = blockIdx.x, tid = threadIdx.x;
  __shared__ float v[2048];
  __shared__ float rv[256];
  __shared__ int ri[256];
  for (int i = tid; i < 2048; i += 256) v[i] = Mv[bh * Ln + i];
  __syncthreads();
  for (int sel = 0; sel < UT; ++sel) {
    float best = -INFINITY;
    int bidx = 1 << 30;
    for (int i = tid; i < 2048; i += 256) {
      if (v[i] > best) { best = v[i]; bidx = i; }
    }
    rv[tid] = best; ri[tid] = bidx;
    __syncthreads();
    for (int s = 128; s > 0; s >>= 1) {
      if (tid < s) {
        float ov = rv[tid + s]; int oi = ri[tid + s];
        if (ov > rv[tid] || (ov == rv[tid] && oi < ri[tid])) { rv[tid] = ov; ri[tid] = oi; }
      }
      __syncthreads();
    }
    if (tid == 0) { Mtop[bh * UT + sel] = ri[0]; v[ri[0]] = -INFINITY; }
    __syncthreads();
  }
}

// ---------------------------------------------------------------------------
// Sparse attention, chunked: block (bh, c) handles 256 keys for all 40
// selected queries; emits partial (m, l, acc[64]) per (bh, c, i).
// ---------------------------------------------------------------------------
__global__ __launch_bounds__(256) void attn_partial(const float* __restrict__ Qf,
    const float* __restrict__ Kf, const float* __restrict__ Vf,
    const int* __restrict__ Mtop, float* __restrict__ pmv,
    float* __restrict__ plv, float* __restrict__ pacc)
{
  const int bh = blockIdx.x, c = blockIdx.y;
  const int tid = threadIdx.x;
  const int w = tid >> 6, lane = tid & 63;
  __shared__ float sQ[UT][DKn];   // 10 KB
  __shared__ float sS[UT][CKn];   // 40 KB (scores -> exp(p))
  __shared__ float sK[64 * 64];   // 16 KB, XOR-swizzled

  for (int i = tid; i < UT * DKn; i += 256) {
    int r = i >> 6, d = i & 63;
    sQ[r][d] = Qf[(size_t)(bh * Ln + Mtop[bh * UT + r]) * DKn + d];
  }
  __syncthreads();

  const float* Kc = Kf + (size_t)(bh * Ln + c * CKn) * DKn;
  for (int sub = 0; sub < 4; ++sub) {
    for (int i = tid; i < 64 * DKn; i += 256) {
      int r = i >> 6, d = i & 63;
      sK[r * 64 + (d ^ ((r & 7) << 2))] = Kc[(size_t)(sub * 64 + r) * DKn + d];
    }
    __syncthreads();
    for (int it = 0; it < 10; ++it) {   // i = w + 4*it (wave-uniform), kk = lane
      int i = w + it * 4, kk = lane;
      float s = 0.f;
#pragma unroll
      for (int g = 0; g < 16; ++g) {
        float4 qv = *reinterpret_cast<const float4*>(&sQ[i][g * 4]);
        float4 kv = *reinterpret_cast<const float4*>(&sK[kk * 64 + ((g * 4) ^ ((kk & 7) << 2))]);
        s += qv.x * kv.x + qv.y * kv.y + qv.z * kv.z + qv.w * kv.w;
      }
      sS[i][sub * 64 + kk] = s * 0.125f;
    }
    __syncthreads();
  }

  // partial softmax per row
  for (int it = 0; it < 10; ++it) {
    int i = w + it * 4;
    float s0 = sS[i][lane], s1 = sS[i][lane + 64];
    float s2 = sS[i][lane + 128], s3 = sS[i][lane + 192];
    float mx = fmaxf(fmaxf(s0, s1), fmaxf(s2, s3));
#pragma unroll
    for (int off = 32; off; off >>= 1) mx = fmaxf(mx, __shfl_xor(mx, off));
    float p0 = expf(s0 - mx), p1 = expf(s1 - mx);
    float p2 = expf(s2 - mx), p3 = expf(s3 - mx);
    sS[i][lane] = p0; sS[i][lane + 64] = p1;
    sS[i][lane + 128] = p2; sS[i][lane + 192] = p3;
    float ls = p0 + p1 + p2 + p3;
#pragma unroll
    for (int off = 32; off; off >>= 1) ls += __shfl_xor(ls, off);
    if (lane == 0) {
      pmv[(bh * NCk + c) * UT + i] = mx;
      plv[(bh * NCk + c) * UT + i] = ls;
    }
  }
  __syncthreads();

  // PV partial: lane = (ksub, dq); V read straight from global (coalesced 1KB)
  const int ksub = lane >> 4, dq = lane & 15;
  const float* Vc = Vf + (size_t)(bh * Ln + c * CKn) * DKn;
  float4 acc[10];
#pragma unroll
  for (int t = 0; t < 10; ++t) acc[t] = make_float4(0.f, 0.f, 0.f, 0.f);
  for (int ko = 0; ko < 64; ++ko) {
    int kk = ko * 4 + ksub;
    float4 v4 = *reinterpret_cast<const float4*>(&Vc[(size_t)kk * DKn + dq * 4]);
#pragma unroll
    for (int t = 0; t < 10; ++t) {
      float wgt = sS[w + t * 4][kk];
      acc[t].x += wgt * v4.x; acc[t].y += wgt * v4.y;
      acc[t].z += wgt * v4.z; acc[t].w += wgt * v4.w;
    }
  }
#pragma unroll
  for (int t = 0; t < 10; ++t) {
#pragma unroll
    for (int off = 16; off <= 32; off <<= 1) {
      acc[t].x += __shfl_xor(acc[t].x, off);
      acc[t].y += __shfl_xor(acc[t].y, off);
      acc[t].z += __shfl_xor(acc[t].z, off);
      acc[t].w += __shfl_xor(acc[t].w, off);
    }
  }
  if (ksub == 0) {
#pragma unroll
    for (int t = 0; t < 10; ++t) {
      int i = w + t * 4;
      *reinterpret_cast<float4*>(&pacc[(size_t)((bh * NCk + c) * UT + i) * DKn + dq * 4]) = acc[t];
    }
  }
}

// ---------------------------------------------------------------------------
// base[b][n] = meanrow_b @ Wo.T + bo
// ---------------------------------------------------------------------------
__global__ __launch_bounds__(256) void base_proj(const float* __restrict__ meanV,
    const float* __restrict__ Wo, const float* __restrict__ bo,
    float* __restrict__ base)
{
  int b = blockIdx.x, tid = threadIdx.x;
#pragma unroll
  for (int rep = 0; rep < 2; ++rep) {
    int n = tid + rep * 256;
    float s = bo[n];
#pragma unroll 8
    for (int g = 0; g < 128; ++g) {
      float4 wv = *reinterpret_cast<const float4*>(&Wo[(size_t)n * Dn + g * 4]);
      float4 mv = *reinterpret_cast<const float4*>(&meanV[b * Dn + g * 4]);
      s += wv.x * mv.x + wv.y * mv.y + wv.z * mv.z + wv.w * mv.w;
    }
    base[b * Dn + n] = s;
  }
}

__global__ __launch_bounds__(256) void base_fill(const float* __restrict__ base,
                                                 float* __restrict__ out)
{
  int idx = blockIdx.x * 256 + threadIdx.x;  // float4 index, 1048576 total
  int row = idx >> 7, col4 = idx & 127;
  int b = row >> 11;
  reinterpret_cast<float4*>(out)[idx] =
      reinterpret_cast<const float4*>(base)[b * 128 + col4];
}

// ---------------------------------------------------------------------------
// combine partials -> context row; delta = row - meanV; scatter-add
// delta @ Wo_hblock into the output row.
// ---------------------------------------------------------------------------
__global__ __launch_bounds__(256) void combine_scatter(const float* __restrict__ pmv,
    const float* __restrict__ plv, const float* __restrict__ pacc,
    const int* __restrict__ Mtop, const float* __restrict__ meanV,
    const float* __restrict__ Wo, float* __restrict__ out)
{
  int bi = blockIdx.x;            // 0..1279
  int bh = bi / UT, i = bi % UT;
  int b = bh >> 3, h = bh & 7;
  int tid = threadIdx.x;
  __shared__ float v[DKn];
  if (tid < 64) {
    int d = tid;
    float mg = -INFINITY;
#pragma unroll
    for (int cc = 0; cc < NCk; ++cc) mg = fmaxf(mg, pmv[(bh * NCk + cc) * UT + i]);
    float den = 0.f, num = 0.f;
#pragma unroll
    for (int cc = 0; cc < NCk; ++cc) {
      float e = expf(pmv[(bh * NCk + cc) * UT + i] - mg);
      den += plv[(bh * NCk + cc) * UT + i] * e;
      num += e * pacc[(size_t)((bh * NCk + cc) * UT + i) * DKn + d];
    }
    v[d] = num / den - meanV[bh * DKn + d];
  }
  __syncthreads();
  int q = Mtop[bh * UT + i];
  float* orow = out + (size_t)(b * Ln + q) * Dn;
  const float* Wh = Wo + h * DKn;
#pragma unroll
  for (int rep = 0; rep < 2; ++rep) {
    int n = tid + rep * 256;
    float s = 0.f;
#pragma unroll
    for (int g = 0; g < 16; ++g) {
      float4 wv = *reinterpret_cast<const float4*>(&Wh[(size_t)n * Dn + g * 4]);
      float4 vv = *reinterpret_cast<const float4*>(&v[g * 4]);
      s += wv.x * vv.x + wv.y * vv.y + wv.z * vv.z + wv.w * vv.w;
    }
    atomicAdd(&orow[n], s);
  }
}

// ---------------------------------------------------------------------------
extern "C" void kernel_launch(void* const* d_in, const int* in_sizes, int n_in,
                              void* d_out, int out_size, void* d_ws, size_t ws_size,
                              hipStream_t stream)
{
  const float* queries = (const float*)d_in[0];
  const float* keys    = (const float*)d_in[1];
  const float* values  = (const float*)d_in[2];
  const float* Wq = (const float*)d_in[3];
  const float* bq = (const float*)d_in[4];
  const float* Wk = (const float*)d_in[5];
  const float* bk = (const float*)d_in[6];
  const float* Wv = (const float*)d_in[7];
  const float* bv = (const float*)d_in[8];
  const float* Wo = (const float*)d_in[9];
  const float* bo = (const float*)d_in[10];
  const int* isamp = (const int*)d_in[11];
  float* out = (float*)d_out;

  float* ws = (float*)d_ws;
  const size_t NBL = (size_t)Bn * Hn * Ln * DKn;  // 4194304
  float* Qf    = ws;
  float* Kf    = Qf + NBL;
  float* Vf    = Kf + NBL;
  float* meanV = Vf + NBL;                       // 2048
  float* Mv    = meanV + Bn * Hn * DKn;          // 65536
  float* pmv   = Mv + Bn * Hn * Ln;              // 10240
  float* plv   = pmv + Bn * Hn * NCk * UT;       // 10240
  float* pacc  = plv + Bn * Hn * NCk * UT;       // 655360
  float* base  = pacc + (size_t)Bn * Hn * NCk * UT * DKn;  // 2048
  int* Mtop    = (int*)(base + Bn * Dn);         // 1280 ints
  ushort_t* Acat = (ushort_t*)(base + Bn * Dn + 1280);     // 8192*1024 ushort
  ushort_t* Wcat = Acat + (size_t)8192 * 1024;             // 512*1536 ushort

  dim3 gg(4, 128);  // (N/128, M/64)
  split_in<<<4096, 256, 0, stream>>>(queries, Acat);
  split_w<<<256, 256, 0, stream>>>(Wq, Wcat);
  gemm3_bf16<<<gg, 256, 0, stream>>>(Acat, Wcat, bq, Qf);
  split_in<<<4096, 256, 0, stream>>>(keys, Acat);
  split_w<<<256, 256, 0, stream>>>(Wk, Wcat);
  gemm3_bf16<<<gg, 256, 0, stream>>>(Acat, Wcat, bk, Kf);
  split_in<<<4096, 256, 0, stream>>>(values, Acat);
  split_w<<<256, 256, 0, stream>>>(Wv, Wcat);
  gemm3_bf16<<<gg, 256, 0, stream>>>(Acat, Wcat, bv, Vf);

  vmean<<<Bn * Hn, 256, 0, stream>>>(Vf, meanV);
  qk_sample_m2<<<Bn * Hn * Ln / 4, 256, 0, stream>>>(Qf, Kf, isamp, Mv);
  topk40<<<Bn * Hn, 256, 0, stream>>>(Mv, Mtop);
  attn_partial<<<dim3(Bn * Hn, NCk), 256, 0, stream>>>(Qf, Kf, Vf, Mtop, pmv, plv, pacc);
  base_proj<<<Bn, 256, 0, stream>>>(meanV, Wo, bo, base);
  base_fill<<<4096, 256, 0, stream>>>(base, out);
  combine_scatter<<<Bn * Hn * UT, 256, 0, stream>>>(pmv, plv, pacc, Mtop, meanV, Wo, out);
}

// Round 4
// 438.405 us; speedup vs baseline: 1.7138x; 1.2196x over previous
//
#include <hip/hip_runtime.h>
#include <math.h>

// Problem constants (fixed by reference: B=4, L=2048, D=512, H=8, dk=64, FACTOR=5)
constexpr int Bn  = 4;
constexpr int Ln  = 2048;
constexpr int Dn  = 512;
constexpr int Hn  = 8;
constexpr int DKn = 64;
constexpr int US  = 40;   // U = min(5*ceil(ln(2049)), 2048) = 40
constexpr int UT  = 40;   // u = 40 (top-k count)
constexpr int NCk = 8;    // key chunks for sparse attention
constexpr int CKn = 256;  // keys per chunk (NCk*CKn == Ln)

typedef unsigned short ushort_t;

// ---------------------------------------------------------------------------
// bf16 split helpers (RNE)
// ---------------------------------------------------------------------------
__device__ __forceinline__ ushort_t f2bf_rne(float x) {
  unsigned u = __float_as_uint(x);
  unsigned r = u + 0x7fffu + ((u >> 16) & 1u);
  return (ushort_t)(r >> 16);
}
__device__ __forceinline__ float bf2f(ushort_t h) {
  return __uint_as_float(((unsigned)h) << 16);
}

// X f32 [8192][512] -> A ushort [8192][1024] = [hi | lo]
__global__ __launch_bounds__(256) void split_in(const float* __restrict__ X,
                                                ushort_t* __restrict__ A)
{
  int i = blockIdx.x * 256 + threadIdx.x;      // 0..1048575
  int m = i >> 7, c4 = (i & 127) << 2;
  float4 x = *reinterpret_cast<const float4*>(&X[(size_t)m * 512 + c4]);
  ushort_t h0 = f2bf_rne(x.x), h1 = f2bf_rne(x.y), h2 = f2bf_rne(x.z), h3 = f2bf_rne(x.w);
  ushort_t l0 = f2bf_rne(x.x - bf2f(h0)), l1 = f2bf_rne(x.y - bf2f(h1));
  ushort_t l2 = f2bf_rne(x.z - bf2f(h2)), l3 = f2bf_rne(x.w - bf2f(h3));
  *reinterpret_cast<ushort4*>(&A[(size_t)m * 1024 + c4])       = make_ushort4(h0, h1, h2, h3);
  *reinterpret_cast<ushort4*>(&A[(size_t)m * 1024 + 512 + c4]) = make_ushort4(l0, l1, l2, l3);
}

// W f32 [512][512] -> Wcat ushort [512][1536] = [hi | lo | hi]
__global__ __launch_bounds__(256) void split_w(const float* __restrict__ W,
                                               ushort_t* __restrict__ Wc)
{
  int i = blockIdx.x * 256 + threadIdx.x;      // 0..65535
  int n = i >> 7, c4 = (i & 127) << 2;
  float4 x = *reinterpret_cast<const float4*>(&W[(size_t)n * 512 + c4]);
  ushort_t h0 = f2bf_rne(x.x), h1 = f2bf_rne(x.y), h2 = f2bf_rne(x.z), h3 = f2bf_rne(x.w);
  ushort_t l0 = f2bf_rne(x.x - bf2f(h0)), l1 = f2bf_rne(x.y - bf2f(h1));
  ushort_t l2 = f2bf_rne(x.z - bf2f(h2)), l3 = f2bf_rne(x.w - bf2f(h3));
  ushort4 hv = make_ushort4(h0, h1, h2, h3);
  ushort4 lv = make_ushort4(l0, l1, l2, l3);
  *reinterpret_cast<ushort4*>(&Wc[(size_t)n * 1536 + c4])        = hv;
  *reinterpret_cast<ushort4*>(&Wc[(size_t)n * 1536 + 512 + c4])  = lv;
  *reinterpret_cast<ushort4*>(&Wc[(size_t)n * 1536 + 1024 + c4]) = hv;
}

// ---------------------------------------------------------------------------
// bf16 3-term MFMA NT GEMM (unchanged; ref-checked in rounds 2-3)
// ---------------------------------------------------------------------------
using bf16x8 = short __attribute__((ext_vector_type(8)));
using f32x4  = float __attribute__((ext_vector_type(4)));

__device__ __forceinline__ void gload_lds16(const void* g, void* l) {
  __builtin_amdgcn_global_load_lds((const __attribute__((address_space(1))) void*)g,
                                   (__attribute__((address_space(3))) void*)l, 16, 0, 0);
}

__global__ __launch_bounds__(256) void gemm3_bf16(const ushort_t* __restrict__ Ast,
    const ushort_t* __restrict__ Bst, const float* __restrict__ bias,
    float* __restrict__ out)
{
  __shared__ __attribute__((aligned(16))) ushort_t sA[64 * 64];    // 8 KB
  __shared__ __attribute__((aligned(16))) ushort_t sB[128 * 64];   // 16 KB
  const int tid = threadIdx.x;
  const int w = tid >> 6, lane = tid & 63;
  const int m0 = blockIdx.y * 64, n0 = blockIdx.x * 128;
  const int wr = w >> 1, wc = w & 1;          // wave subtile (wr*32, wc*64)
  const int r16 = lane & 15, ko = (lane >> 4) * 8;

  f32x4 acc[2][4];
#pragma unroll
  for (int m = 0; m < 2; ++m)
#pragma unroll
    for (int n = 0; n < 4; ++n) acc[m][n] = (f32x4){0.f, 0.f, 0.f, 0.f};

  for (int k0 = 0; k0 < 1536; k0 += 64) {
    const int ka0 = (k0 < 1024) ? (k0 & 511) : (k0 - 512);
    __syncthreads();   // previous compute done before LDS overwrite
#pragma unroll
    for (int i = 0; i < 2; ++i) {              // stage A: 64 rows x 64 cols
      int e = i * 256 + tid, r = e >> 3, c8 = e & 7;
      gload_lds16(Ast + (size_t)(m0 + r) * 1024 + ka0 + c8 * 8,
                  (void*)(sA + (size_t)(i * 256 + w * 64) * 8));
    }
#pragma unroll
    for (int i = 0; i < 4; ++i) {              // stage B: 128 rows x 64 cols
      int e = i * 256 + tid, r = e >> 3, c8 = e & 7;
      gload_lds16(Bst + (size_t)(n0 + r) * 1536 + k0 + c8 * 8,
                  (void*)(sB + (size_t)(i * 256 + w * 64) * 8));
    }
    __syncthreads();   // drains vmcnt(0) before barrier
#pragma unroll
    for (int kk = 0; kk < 64; kk += 32) {
      bf16x8 a[2], b[4];
#pragma unroll
      for (int m = 0; m < 2; ++m)
        a[m] = *reinterpret_cast<const bf16x8*>(&sA[(wr * 32 + m * 16 + r16) * 64 + kk + ko]);
#pragma unroll
      for (int n = 0; n < 4; ++n)
        b[n] = *reinterpret_cast<const bf16x8*>(&sB[(wc * 64 + n * 16 + r16) * 64 + kk + ko]);
#pragma unroll
      for (int m = 0; m < 2; ++m)
#pragma unroll
        for (int n = 0; n < 4; ++n)
          acc[m][n] = __builtin_amdgcn_mfma_f32_16x16x32_bf16(a[m], b[n], acc[m][n], 0, 0, 0);
    }
  }

  // epilogue: C row = (lane>>4)*4 + reg, col = lane&15 (m89-verified layout)
#pragma unroll
  for (int m = 0; m < 2; ++m) {
#pragma unroll
    for (int n = 0; n < 4; ++n) {
#pragma unroll
      for (int r = 0; r < 4; ++r) {
        int row = m0 + wr * 32 + m * 16 + (lane >> 4) * 4 + r;
        int col = n0 + wc * 64 + n * 16 + (lane & 15);
        float v = acc[m][n][r] + bias[col];
        int b = row >> 11, l = row & 2047, h = col >> 6, dd = col & 63;
        out[(size_t)((b * Hn + h) * Ln + l) * DKn + dd] = v;
      }
    }
  }
}

// ---------------------------------------------------------------------------
// vmean, two-stage
// ---------------------------------------------------------------------------
__global__ __launch_bounds__(256) void vmean1(const float* __restrict__ Vf,
                                              float* __restrict__ part)
{
  int bh = blockIdx.x, ch = blockIdx.y;       // 32 x 16
  int t = threadIdx.x;
  int d4 = t & 15, ls = t >> 4;
  const float* base = Vf + ((size_t)bh * Ln + ch * 128) * DKn;
  float4 s = make_float4(0.f, 0.f, 0.f, 0.f);
#pragma unroll
  for (int i = 0; i < 8; ++i) {
    float4 x = *reinterpret_cast<const float4*>(&base[(size_t)(ls + i * 16) * DKn + d4 * 4]);
    s.x += x.x; s.y += x.y; s.z += x.z; s.w += x.w;
  }
  __shared__ float4 red[16][16];
  red[ls][d4] = s;
  __syncthreads();
  if (t < 64) {
    int dd = t & 15, g = t >> 4;
    float4 a = red[g * 4 + 0][dd], b = red[g * 4 + 1][dd];
    float4 c = red[g * 4 + 2][dd], d = red[g * 4 + 3][dd];
    red[g * 4][dd] = make_float4(a.x + b.x + c.x + d.x, a.y + b.y + c.y + d.y,
                                 a.z + b.z + c.z + d.z, a.w + b.w + c.w + d.w);
  }
  __syncthreads();
  if (t < 16) {
    float4 a = red[0][t], b = red[4][t], c = red[8][t], d = red[12][t];
    float4 r = make_float4(a.x + b.x + c.x + d.x, a.y + b.y + c.y + d.y,
                           a.z + b.z + c.z + d.z, a.w + b.w + c.w + d.w);
    *reinterpret_cast<float4*>(&part[((size_t)(bh * 16 + ch)) * DKn + t * 4]) = r;
  }
}

__global__ __launch_bounds__(64) void vmean2(const float* __restrict__ part,
                                             float* __restrict__ meanV)
{
  int bh = blockIdx.x, d = threadIdx.x;
  float s = 0.f;
#pragma unroll
  for (int ch = 0; ch < 16; ++ch) s += part[((size_t)(bh * 16 + ch)) * DKn + d];
  meanV[bh * DKn + d] = s * (1.f / 2048.f);
}

// ---------------------------------------------------------------------------
// M[bh][q] = max_u(Q[q]·K[idx_u]) - sum_u(Q[q]·K[idx_u]) / LK
// ---------------------------------------------------------------------------
__global__ __launch_bounds__(256) void qk_sample_m2(const float* __restrict__ Qf,
    const float* __restrict__ Kf, const int* __restrict__ isamp,
    float* __restrict__ Mout)
{
  int wq = blockIdx.x * 4 + (threadIdx.x >> 6);  // global q over B*H*L
  int lane = threadIdx.x & 63;
  int g = lane >> 4, s = lane & 15;
  int bh = wq >> 11, q = wq & 2047;
  const float* Kb = Kf + (size_t)bh * Ln * DKn;
  float4 qv = *reinterpret_cast<const float4*>(&Qf[(size_t)(bh * Ln + q) * DKn + s * 4]);
  float mx = -INFINITY, sm = 0.f;
#pragma unroll
  for (int p = 0; p < 10; ++p) {
    int u = p * 4 + g;
    int idx = isamp[q * US + u];
    float4 kv = *reinterpret_cast<const float4*>(&Kb[(size_t)idx * DKn + s * 4]);
    float d = qv.x * kv.x + qv.y * kv.y + qv.z * kv.z + qv.w * kv.w;
#pragma unroll
    for (int off = 1; off < 16; off <<= 1) d += __shfl_xor(d, off);
    mx = fmaxf(mx, d);
    sm += d;
  }
#pragma unroll
  for (int off = 16; off <= 32; off <<= 1) {
    mx = fmaxf(mx, __shfl_xor(mx, off));
    sm += __shfl_xor(sm, off);
  }
  if (lane == 0) Mout[wq] = mx - sm * (1.f / 2048.f);
}

// ---------------------------------------------------------------------------
// top-40 of M[bh][0..2047], register/shuffle version.
// Wave w extracts its slice's top-40 (shfl-only argmax, tie -> lower index);
// wave 0 merges ALL 4*40=160 candidates (4 regs/lane covers slots 0..255 —
// round-3 bug was j<3 dropping wave 3's slice).
// ---------------------------------------------------------------------------
__global__ __launch_bounds__(256) void topk40(const float* __restrict__ Mv,
                                              int* __restrict__ Mtop)
{
  int bh = blockIdx.x, tid = threadIdx.x;
  int w = tid >> 6, lane = tid & 63;
  __shared__ float cval[256];
  __shared__ int cidx[256];

  // wave-local: slice [w*512, w*512+512), lane holds 8 strided elements
  float v[8];
#pragma unroll
  for (int i = 0; i < 8; ++i) v[i] = Mv[bh * Ln + w * 512 + i * 64 + lane];
  int taken = 0;
  for (int sel = 0; sel < UT; ++sel) {
    float bv = -INFINITY; int bi = 1 << 30;
#pragma unroll
    for (int i = 0; i < 8; ++i) {
      if (!((taken >> i) & 1)) {
        int ii = w * 512 + i * 64 + lane;
        if (v[i] > bv || (v[i] == bv && ii < bi)) { bv = v[i]; bi = ii; }
      }
    }
#pragma unroll
    for (int off = 1; off < 64; off <<= 1) {
      float ov = __shfl_xor(bv, off); int oi = __shfl_xor(bi, off);
      if (ov > bv || (ov == bv && oi < bi)) { bv = ov; bi = oi; }
    }
    if ((bi & 63) == lane) taken |= 1 << ((bi >> 6) & 7);
    if (lane == 0) { cval[w * 64 + sel] = bv; cidx[w * 64 + sel] = bi; }
  }
  __syncthreads();

  // merge 160 candidates (slots w*64+sel, w<4, sel<40) by wave 0
  if (w == 0) {
    float cv[4]; int ci[4]; int tk = 0;
#pragma unroll
    for (int j = 0; j < 4; ++j) {
      int c = lane + j * 64;                 // covers all 256 slots
      bool ok = (lane < UT);                 // valid candidates: sel = lane < 40
      cv[j] = ok ? cval[c] : -INFINITY;
      ci[j] = ok ? cidx[c] : (1 << 30);
      if (!ok) tk |= 1 << j;
    }
    for (int sel = 0; sel < UT; ++sel) {
      float bv = -INFINITY; int bi = 1 << 30;
#pragma unroll
      for (int j = 0; j < 4; ++j) {
        if (!((tk >> j) & 1) && (cv[j] > bv || (cv[j] == bv && ci[j] < bi))) {
          bv = cv[j]; bi = ci[j];
        }
      }
#pragma unroll
      for (int off = 1; off < 64; off <<= 1) {
        float ov = __shfl_xor(bv, off); int oi = __shfl_xor(bi, off);
        if (ov > bv || (ov == bv && oi < bi)) { bv = ov; bi = oi; }
      }
      if (lane == 0) Mtop[bh * UT + sel] = bi;
#pragma unroll
      for (int j = 0; j < 4; ++j)
        if (ci[j] == bi) tk |= 1 << j;   // indices unique across candidates
    }
  }
}

// ---------------------------------------------------------------------------
// Sparse attention, chunked (unchanged)
// ---------------------------------------------------------------------------
__global__ __launch_bounds__(256) void attn_partial(const float* __restrict__ Qf,
    const float* __restrict__ Kf, const float* __restrict__ Vf,
    const int* __restrict__ Mtop, float* __restrict__ pmv,
    float* __restrict__ plv, float* __restrict__ pacc)
{
  const int bh = blockIdx.x, c = blockIdx.y;
  const int tid = threadIdx.x;
  const int w = tid >> 6, lane = tid & 63;
  __shared__ float sQ[UT][DKn];   // 10 KB
  __shared__ float sS[UT][CKn];   // 40 KB (scores -> exp(p))
  __shared__ float sK[64 * 64];   // 16 KB, XOR-swizzled

  for (int i = tid; i < UT * DKn; i += 256) {
    int r = i >> 6, d = i & 63;
    sQ[r][d] = Qf[(size_t)(bh * Ln + Mtop[bh * UT + r]) * DKn + d];
  }
  __syncthreads();

  const float* Kc = Kf + (size_t)(bh * Ln + c * CKn) * DKn;
  for (int sub = 0; sub < 4; ++sub) {
    for (int i = tid; i < 64 * DKn; i += 256) {
      int r = i >> 6, d = i & 63;
      sK[r * 64 + (d ^ ((r & 7) << 2))] = Kc[(size_t)(sub * 64 + r) * DKn + d];
    }
    __syncthreads();
    for (int it = 0; it < 10; ++it) {   // i = w + 4*it (wave-uniform), kk = lane
      int i = w + it * 4, kk = lane;
      float s = 0.f;
#pragma unroll
      for (int g = 0; g < 16; ++g) {
        float4 qv = *reinterpret_cast<const float4*>(&sQ[i][g * 4]);
        float4 kv = *reinterpret_cast<const float4*>(&sK[kk * 64 + ((g * 4) ^ ((kk & 7) << 2))]);
        s += qv.x * kv.x + qv.y * kv.y + qv.z * kv.z + qv.w * kv.w;
      }
      sS[i][sub * 64 + kk] = s * 0.125f;
    }
    __syncthreads();
  }

  // partial softmax per row
  for (int it = 0; it < 10; ++it) {
    int i = w + it * 4;
    float s0 = sS[i][lane], s1 = sS[i][lane + 64];
    float s2 = sS[i][lane + 128], s3 = sS[i][lane + 192];
    float mx = fmaxf(fmaxf(s0, s1), fmaxf(s2, s3));
#pragma unroll
    for (int off = 32; off; off >>= 1) mx = fmaxf(mx, __shfl_xor(mx, off));
    float p0 = expf(s0 - mx), p1 = expf(s1 - mx);
    float p2 = expf(s2 - mx), p3 = expf(s3 - mx);
    sS[i][lane] = p0; sS[i][lane + 64] = p1;
    sS[i][lane + 128] = p2; sS[i][lane + 192] = p3;
    float ls = p0 + p1 + p2 + p3;
#pragma unroll
    for (int off = 32; off; off >>= 1) ls += __shfl_xor(ls, off);
    if (lane == 0) {
      pmv[(bh * NCk + c) * UT + i] = mx;
      plv[(bh * NCk + c) * UT + i] = ls;
    }
  }
  __syncthreads();

  // PV partial: lane = (ksub, dq); V read straight from global (coalesced 1KB)
  const int ksub = lane >> 4, dq = lane & 15;
  const float* Vc = Vf + (size_t)(bh * Ln + c * CKn) * DKn;
  float4 acc[10];
#pragma unroll
  for (int t = 0; t < 10; ++t) acc[t] = make_float4(0.f, 0.f, 0.f, 0.f);
  for (int ko = 0; ko < 64; ++ko) {
    int kk = ko * 4 + ksub;
    float4 v4 = *reinterpret_cast<const float4*>(&Vc[(size_t)kk * DKn + dq * 4]);
#pragma unroll
    for (int t = 0; t < 10; ++t) {
      float wgt = sS[w + t * 4][kk];
      acc[t].x += wgt * v4.x; acc[t].y += wgt * v4.y;
      acc[t].z += wgt * v4.z; acc[t].w += wgt * v4.w;
    }
  }
#pragma unroll
  for (int t = 0; t < 10; ++t) {
#pragma unroll
    for (int off = 16; off <= 32; off <<= 1) {
      acc[t].x += __shfl_xor(acc[t].x, off);
      acc[t].y += __shfl_xor(acc[t].y, off);
      acc[t].z += __shfl_xor(acc[t].z, off);
      acc[t].w += __shfl_xor(acc[t].w, off);
    }
  }
  if (ksub == 0) {
#pragma unroll
    for (int t = 0; t < 10; ++t) {
      int i = w + t * 4;
      *reinterpret_cast<float4*>(&pacc[(size_t)((bh * NCk + c) * UT + i) * DKn + dq * 4]) = acc[t];
    }
  }
}

// ---------------------------------------------------------------------------
// base[b][n] = meanrow_b @ Wo.T + bo
// ---------------------------------------------------------------------------
__global__ __launch_bounds__(256) void base_proj(const float* __restrict__ meanV,
    const float* __restrict__ Wo, const float* __restrict__ bo,
    float* __restrict__ base)
{
  int b = blockIdx.x, tid = threadIdx.x;
#pragma unroll
  for (int rep = 0; rep < 2; ++rep) {
    int n = tid + rep * 256;
    float s = bo[n];
#pragma unroll 8
    for (int g = 0; g < 128; ++g) {
      float4 wv = *reinterpret_cast<const float4*>(&Wo[(size_t)n * Dn + g * 4]);
      float4 mv = *reinterpret_cast<const float4*>(&meanV[b * Dn + g * 4]);
      s += wv.x * mv.x + wv.y * mv.y + wv.z * mv.z + wv.w * mv.w;
    }
    base[b * Dn + n] = s;
  }
}

__global__ __launch_bounds__(256) void base_fill(const float* __restrict__ base,
                                                 float* __restrict__ out)
{
  int idx = blockIdx.x * 256 + threadIdx.x;  // float4 index, 1048576 total
  int row = idx >> 7, col4 = idx & 127;
  int b = row >> 11;
  reinterpret_cast<float4*>(out)[idx] =
      reinterpret_cast<const float4*>(base)[b * 128 + col4];
}

// ---------------------------------------------------------------------------
// combine partials -> context row; delta = row - meanV; scatter-add
// ---------------------------------------------------------------------------
__global__ __launch_bounds__(256) void combine_scatter(const float* __restrict__ pmv,
    const float* __restrict__ plv, const float* __restrict__ pacc,
    const int* __restrict__ Mtop, const float* __restrict__ meanV,
    const float* __restrict__ Wo, float* __restrict__ out)
{
  int bi = blockIdx.x;            // 0..1279
  int bh = bi / UT, i = bi % UT;
  int b = bh >> 3, h = bh & 7;
  int tid = threadIdx.x;
  __shared__ float v[DKn];
  if (tid < 64) {
    int d = tid;
    float mg = -INFINITY;
#pragma unroll
    for (int cc = 0; cc < NCk; ++cc) mg = fmaxf(mg, pmv[(bh * NCk + cc) * UT + i]);
    float den = 0.f, num = 0.f;
#pragma unroll
    for (int cc = 0; cc < NCk; ++cc) {
      float e = expf(pmv[(bh * NCk + cc) * UT + i] - mg);
      den += plv[(bh * NCk + cc) * UT + i] * e;
      num += e * pacc[(size_t)((bh * NCk + cc) * UT + i) * DKn + d];
    }
    v[d] = num / den - meanV[bh * DKn + d];
  }
  __syncthreads();
  int q = Mtop[bh * UT + i];
  float* orow = out + (size_t)(b * Ln + q) * Dn;
  const float* Wh = Wo + h * DKn;
#pragma unroll
  for (int rep = 0; rep < 2; ++rep) {
    int n = tid + rep * 256;
    float s = 0.f;
#pragma unroll
    for (int g = 0; g < 16; ++g) {
      float4 wv = *reinterpret_cast<const float4*>(&Wh[(size_t)n * Dn + g * 4]);
      float4 vv = *reinterpret_cast<const float4*>(&v[g * 4]);
      s += wv.x * vv.x + wv.y * vv.y + wv.z * vv.z + wv.w * vv.w;
    }
    atomicAdd(&orow[n], s);
  }
}

// ---------------------------------------------------------------------------
extern "C" void kernel_launch(void* const* d_in, const int* in_sizes, int n_in,
                              void* d_out, int out_size, void* d_ws, size_t ws_size,
                              hipStream_t stream)
{
  const float* queries = (const float*)d_in[0];
  const float* keys    = (const float*)d_in[1];
  const float* values  = (const float*)d_in[2];
  const float* Wq = (const float*)d_in[3];
  const float* bq = (const float*)d_in[4];
  const float* Wk = (const float*)d_in[5];
  const float* bk = (const float*)d_in[6];
  const float* Wv = (const float*)d_in[7];
  const float* bv = (const float*)d_in[8];
  const float* Wo = (const float*)d_in[9];
  const float* bo = (const float*)d_in[10];
  const int* isamp = (const int*)d_in[11];
  float* out = (float*)d_out;

  float* ws = (float*)d_ws;
  const size_t NBL = (size_t)Bn * Hn * Ln * DKn;  // 4194304
  float* Qf    = ws;
  float* Kf    = Qf + NBL;
  float* Vf    = Kf + NBL;
  float* meanV = Vf + NBL;                       // 2048
  float* Mv    = meanV + Bn * Hn * DKn;          // 65536
  float* pmv   = Mv + Bn * Hn * Ln;              // 10240
  float* plv   = pmv + Bn * Hn * NCk * UT;       // 10240
  float* pacc  = plv + Bn * Hn * NCk * UT;       // 655360
  float* base  = pacc + (size_t)Bn * Hn * NCk * UT * DKn;  // 2048
  int* Mtop    = (int*)(base + Bn * Dn);         // 1280 ints
  ushort_t* Acat = (ushort_t*)(base + Bn * Dn + 1280);     // 8192*1024 ushort
  ushort_t* Wcat = Acat + (size_t)8192 * 1024;             // 512*1536 ushort
  float* vpart = (float*)(Wcat + (size_t)512 * 1536);      // 32*16*64 floats

  dim3 gg(4, 128);  // (N/128, M/64)
  split_in<<<4096, 256, 0, stream>>>(queries, Acat);
  split_w<<<256, 256, 0, stream>>>(Wq, Wcat);
  gemm3_bf16<<<gg, 256, 0, stream>>>(Acat, Wcat, bq, Qf);
  split_in<<<4096, 256, 0, stream>>>(keys, Acat);
  split_w<<<256, 256, 0, stream>>>(Wk, Wcat);
  gemm3_bf16<<<gg, 256, 0, stream>>>(Acat, Wcat, bk, Kf);
  split_in<<<4096, 256, 0, stream>>>(values, Acat);
  split_w<<<256, 256, 0, stream>>>(Wv, Wcat);
  gemm3_bf16<<<gg, 256, 0, stream>>>(Acat, Wcat, bv, Vf);

  vmean1<<<dim3(Bn * Hn, 16), 256, 0, stream>>>(Vf, vpart);
  vmean2<<<Bn * Hn, 64, 0, stream>>>(vpart, meanV);
  qk_sample_m2<<<Bn * Hn * Ln / 4, 256, 0, stream>>>(Qf, Kf, isamp, Mv);
  topk40<<<Bn * Hn, 256, 0, stream>>>(Mv, Mtop);
  attn_partial<<<dim3(Bn * Hn, NCk), 256, 0, stream>>>(Qf, Kf, Vf, Mtop, pmv, plv, pacc);
  base_proj<<<Bn, 256, 0, stream>>>(meanV, Wo, bo, base);
  base_fill<<<4096, 256, 0, stream>>>(base, out);
  combine_scatter<<<Bn * Hn * UT, 256, 0, stream>>>(pmv, plv, pacc, Mtop, meanV, Wo, out);
}

// Round 5
// 377.775 us; speedup vs baseline: 1.9888x; 1.1605x over previous
//
#include <hip/hip_runtime.h>
#include <math.h>

// Problem constants (fixed by reference: B=4, L=2048, D=512, H=8, dk=64, FACTOR=5)
constexpr int Bn  = 4;
constexpr int Ln  = 2048;
constexpr int Dn  = 512;
constexpr int Hn  = 8;
constexpr int DKn = 64;
constexpr int US  = 40;   // U = min(5*ceil(ln(2049)), 2048) = 40
constexpr int UT  = 40;   // u = 40 (top-k count)
constexpr int NCk = 8;    // key chunks for sparse attention
constexpr int CKn = 256;  // keys per chunk (NCk*CKn == Ln)

typedef unsigned short ushort_t;

// ---------------------------------------------------------------------------
// bf16 split helpers (RNE)
// ---------------------------------------------------------------------------
__device__ __forceinline__ ushort_t f2bf_rne(float x) {
  unsigned u = __float_as_uint(x);
  unsigned r = u + 0x7fffu + ((u >> 16) & 1u);
  return (ushort_t)(r >> 16);
}
__device__ __forceinline__ float bf2f(ushort_t h) {
  return __uint_as_float(((unsigned)h) << 16);
}

// X f32 [8192][512] -> A ushort [8192][1024] = [hi | lo]
__global__ __launch_bounds__(256) void split_in(const float* __restrict__ X,
                                                ushort_t* __restrict__ A)
{
  int i = blockIdx.x * 256 + threadIdx.x;      // 0..1048575
  int m = i >> 7, c4 = (i & 127) << 2;
  float4 x = *reinterpret_cast<const float4*>(&X[(size_t)m * 512 + c4]);
  ushort_t h0 = f2bf_rne(x.x), h1 = f2bf_rne(x.y), h2 = f2bf_rne(x.z), h3 = f2bf_rne(x.w);
  ushort_t l0 = f2bf_rne(x.x - bf2f(h0)), l1 = f2bf_rne(x.y - bf2f(h1));
  ushort_t l2 = f2bf_rne(x.z - bf2f(h2)), l3 = f2bf_rne(x.w - bf2f(h3));
  *reinterpret_cast<ushort4*>(&A[(size_t)m * 1024 + c4])       = make_ushort4(h0, h1, h2, h3);
  *reinterpret_cast<ushort4*>(&A[(size_t)m * 1024 + 512 + c4]) = make_ushort4(l0, l1, l2, l3);
}

// W f32 [512][512] -> Wcat ushort [512][1536] = [hi | lo | hi]
__global__ __launch_bounds__(256) void split_w(const float* __restrict__ W,
                                               ushort_t* __restrict__ Wc)
{
  int i = blockIdx.x * 256 + threadIdx.x;      // 0..65535
  int n = i >> 7, c4 = (i & 127) << 2;
  float4 x = *reinterpret_cast<const float4*>(&W[(size_t)n * 512 + c4]);
  ushort_t h0 = f2bf_rne(x.x), h1 = f2bf_rne(x.y), h2 = f2bf_rne(x.z), h3 = f2bf_rne(x.w);
  ushort_t l0 = f2bf_rne(x.x - bf2f(h0)), l1 = f2bf_rne(x.y - bf2f(h1));
  ushort_t l2 = f2bf_rne(x.z - bf2f(h2)), l3 = f2bf_rne(x.w - bf2f(h3));
  ushort4 hv = make_ushort4(h0, h1, h2, h3);
  ushort4 lv = make_ushort4(l0, l1, l2, l3);
  *reinterpret_cast<ushort4*>(&Wc[(size_t)n * 1536 + c4])        = hv;
  *reinterpret_cast<ushort4*>(&Wc[(size_t)n * 1536 + 512 + c4])  = lv;
  *reinterpret_cast<ushort4*>(&Wc[(size_t)n * 1536 + 1024 + c4]) = hv;
}

// ---------------------------------------------------------------------------
// bf16 3-term MFMA NT GEMM (unchanged; ref-checked in rounds 2-4)
// ---------------------------------------------------------------------------
using bf16x8 = short __attribute__((ext_vector_type(8)));
using f32x4  = float __attribute__((ext_vector_type(4)));

__device__ __forceinline__ void gload_lds16(const void* g, void* l) {
  __builtin_amdgcn_global_load_lds((const __attribute__((address_space(1))) void*)g,
                                   (__attribute__((address_space(3))) void*)l, 16, 0, 0);
}

__global__ __launch_bounds__(256) void gemm3_bf16(const ushort_t* __restrict__ Ast,
    const ushort_t* __restrict__ Bst, const float* __restrict__ bias,
    float* __restrict__ out)
{
  __shared__ __attribute__((aligned(16))) ushort_t sA[64 * 64];    // 8 KB
  __shared__ __attribute__((aligned(16))) ushort_t sB[128 * 64];   // 16 KB
  const int tid = threadIdx.x;
  const int w = tid >> 6, lane = tid & 63;
  const int m0 = blockIdx.y * 64, n0 = blockIdx.x * 128;
  const int wr = w >> 1, wc = w & 1;          // wave subtile (wr*32, wc*64)
  const int r16 = lane & 15, ko = (lane >> 4) * 8;

  f32x4 acc[2][4];
#pragma unroll
  for (int m = 0; m < 2; ++m)
#pragma unroll
    for (int n = 0; n < 4; ++n) acc[m][n] = (f32x4){0.f, 0.f, 0.f, 0.f};

  for (int k0 = 0; k0 < 1536; k0 += 64) {
    const int ka0 = (k0 < 1024) ? (k0 & 511) : (k0 - 512);
    __syncthreads();   // previous compute done before LDS overwrite
#pragma unroll
    for (int i = 0; i < 2; ++i) {              // stage A: 64 rows x 64 cols
      int e = i * 256 + tid, r = e >> 3, c8 = e & 7;
      gload_lds16(Ast + (size_t)(m0 + r) * 1024 + ka0 + c8 * 8,
                  (void*)(sA + (size_t)(i * 256 + w * 64) * 8));
    }
#pragma unroll
    for (int i = 0; i < 4; ++i) {              // stage B: 128 rows x 64 cols
      int e = i * 256 + tid, r = e >> 3, c8 = e & 7;
      gload_lds16(Bst + (size_t)(n0 + r) * 1536 + k0 + c8 * 8,
                  (void*)(sB + (size_t)(i * 256 + w * 64) * 8));
    }
    __syncthreads();   // drains vmcnt(0) before barrier
#pragma unroll
    for (int kk = 0; kk < 64; kk += 32) {
      bf16x8 a[2], b[4];
#pragma unroll
      for (int m = 0; m < 2; ++m)
        a[m] = *reinterpret_cast<const bf16x8*>(&sA[(wr * 32 + m * 16 + r16) * 64 + kk + ko]);
#pragma unroll
      for (int n = 0; n < 4; ++n)
        b[n] = *reinterpret_cast<const bf16x8*>(&sB[(wc * 64 + n * 16 + r16) * 64 + kk + ko]);
#pragma unroll
      for (int m = 0; m < 2; ++m)
#pragma unroll
        for (int n = 0; n < 4; ++n)
          acc[m][n] = __builtin_amdgcn_mfma_f32_16x16x32_bf16(a[m], b[n], acc[m][n], 0, 0, 0);
    }
  }

  // epilogue: C row = (lane>>4)*4 + reg, col = lane&15 (m89-verified layout)
#pragma unroll
  for (int m = 0; m < 2; ++m) {
#pragma unroll
    for (int n = 0; n < 4; ++n) {
#pragma unroll
      for (int r = 0; r < 4; ++r) {
        int row = m0 + wr * 32 + m * 16 + (lane >> 4) * 4 + r;
        int col = n0 + wc * 64 + n * 16 + (lane & 15);
        float v = acc[m][n][r] + bias[col];
        int b = row >> 11, l = row & 2047, h = col >> 6, dd = col & 63;
        out[(size_t)((b * Hn + h) * Ln + l) * DKn + dd] = v;
      }
    }
  }
}

// ---------------------------------------------------------------------------
// vmean, two-stage
// ---------------------------------------------------------------------------
__global__ __launch_bounds__(256) void vmean1(const float* __restrict__ Vf,
                                              float* __restrict__ part)
{
  int bh = blockIdx.x, ch = blockIdx.y;       // 32 x 16
  int t = threadIdx.x;
  int d4 = t & 15, ls = t >> 4;
  const float* base = Vf + ((size_t)bh * Ln + ch * 128) * DKn;
  float4 s = make_float4(0.f, 0.f, 0.f, 0.f);
#pragma unroll
  for (int i = 0; i < 8; ++i) {
    float4 x = *reinterpret_cast<const float4*>(&base[(size_t)(ls + i * 16) * DKn + d4 * 4]);
    s.x += x.x; s.y += x.y; s.z += x.z; s.w += x.w;
  }
  __shared__ float4 red[16][16];
  red[ls][d4] = s;
  __syncthreads();
  if (t < 64) {
    int dd = t & 15, g = t >> 4;
    float4 a = red[g * 4 + 0][dd], b = red[g * 4 + 1][dd];
    float4 c = red[g * 4 + 2][dd], d = red[g * 4 + 3][dd];
    red[g * 4][dd] = make_float4(a.x + b.x + c.x + d.x, a.y + b.y + c.y + d.y,
                                 a.z + b.z + c.z + d.z, a.w + b.w + c.w + d.w);
  }
  __syncthreads();
  if (t < 16) {
    float4 a = red[0][t], b = red[4][t], c = red[8][t], d = red[12][t];
    float4 r = make_float4(a.x + b.x + c.x + d.x, a.y + b.y + c.y + d.y,
                           a.z + b.z + c.z + d.z, a.w + b.w + c.w + d.w);
    *reinterpret_cast<float4*>(&part[((size_t)(bh * 16 + ch)) * DKn + t * 4]) = r;
  }
}

__global__ __launch_bounds__(64) void vmean2(const float* __restrict__ part,
                                             float* __restrict__ meanV)
{
  int bh = blockIdx.x, d = threadIdx.x;
  float s = 0.f;
#pragma unroll
  for (int ch = 0; ch < 16; ++ch) s += part[((size_t)(bh * 16 + ch)) * DKn + d];
  meanV[bh * DKn + d] = s * (1.f / 2048.f);
}

// ---------------------------------------------------------------------------
// M[bh][q] = max_u(Q[q]·K[idx_u]) - sum_u(Q[q]·K[idx_u]) / LK
// ---------------------------------------------------------------------------
__global__ __launch_bounds__(256) void qk_sample_m2(const float* __restrict__ Qf,
    const float* __restrict__ Kf, const int* __restrict__ isamp,
    float* __restrict__ Mout)
{
  int wq = blockIdx.x * 4 + (threadIdx.x >> 6);  // global q over B*H*L
  int lane = threadIdx.x & 63;
  int g = lane >> 4, s = lane & 15;
  int bh = wq >> 11, q = wq & 2047;
  const float* Kb = Kf + (size_t)bh * Ln * DKn;
  float4 qv = *reinterpret_cast<const float4*>(&Qf[(size_t)(bh * Ln + q) * DKn + s * 4]);
  float mx = -INFINITY, sm = 0.f;
#pragma unroll
  for (int p = 0; p < 10; ++p) {
    int u = p * 4 + g;
    int idx = isamp[q * US + u];
    float4 kv = *reinterpret_cast<const float4*>(&Kb[(size_t)idx * DKn + s * 4]);
    float d = qv.x * kv.x + qv.y * kv.y + qv.z * kv.z + qv.w * kv.w;
#pragma unroll
    for (int off = 1; off < 16; off <<= 1) d += __shfl_xor(d, off);
    mx = fmaxf(mx, d);
    sm += d;
  }
#pragma unroll
  for (int off = 16; off <= 32; off <<= 1) {
    mx = fmaxf(mx, __shfl_xor(mx, off));
    sm += __shfl_xor(sm, off);
  }
  if (lane == 0) Mout[wq] = mx - sm * (1.f / 2048.f);
}

// ---------------------------------------------------------------------------
// top-40 of M[bh][0..2047] via radix-select (descending) on monotone u32 keys.
// 4 passes of 8 bits: histogram + suffix-scan locate the bin holding the
// 40th-largest; T = full key of rank 40. Emit all keys > T, then the
// (40 - count) lowest indices among keys == T (jax.lax.top_k tie semantics).
// Output is an unordered index set (consumers don't depend on order).
// ---------------------------------------------------------------------------
__global__ __launch_bounds__(256) void topk40(const float* __restrict__ Mv,
                                              int* __restrict__ Mtop)
{
  int bh = blockIdx.x, tid = threadIdx.x;
  __shared__ unsigned hist[256];
  __shared__ unsigned sfx[256];
  __shared__ unsigned prefix_s, k_s;
  __shared__ int outcnt, tiecnt;
  __shared__ int tlist[256];

  unsigned key[8];
#pragma unroll
  for (int i = 0; i < 8; ++i) {
    unsigned u = __float_as_uint(Mv[bh * Ln + tid + i * 256]);
    key[i] = (u & 0x80000000u) ? ~u : (u | 0x80000000u);  // monotone inc map
  }
  if (tid == 0) { prefix_s = 0u; k_s = UT; outcnt = 0; tiecnt = 0; }
  __syncthreads();

  for (int d = 24; d >= 0; d -= 8) {
    hist[tid] = 0u;
    __syncthreads();
    unsigned pref = prefix_s;
    unsigned mask = (d == 24) ? 0u : (0xFFFFFFFFu << (d + 8));
#pragma unroll
    for (int i = 0; i < 8; ++i)
      if ((key[i] & mask) == pref) atomicAdd(&hist[(key[i] >> d) & 255u], 1u);
    __syncthreads();
    sfx[tid] = hist[tid];
    __syncthreads();
    // Hillis-Steele suffix sum: sfx[b] = count of elements in bins >= b
    for (int off = 1; off < 256; off <<= 1) {
      unsigned add = (tid + off < 256) ? sfx[tid + off] : 0u;
      __syncthreads();
      sfx[tid] += add;
      __syncthreads();
    }
    unsigned k = k_s;
    unsigned nxt = (tid < 255) ? sfx[tid + 1] : 0u;
    if (sfx[tid] >= k && nxt < k) {      // unique crossing bin
      prefix_s = pref | ((unsigned)tid << d);
      k_s = k - nxt;                      // still needed inside this bin
    }
    __syncthreads();
  }

  unsigned T = prefix_s;
  int kf = (int)k_s;                      // # to take among key == T
#pragma unroll
  for (int i = 0; i < 8; ++i) {
    int idx = tid + i * 256;
    if (key[i] > T) {
      int s = atomicAdd(&outcnt, 1);
      Mtop[bh * UT + s] = idx;
    } else if (key[i] == T) {
      int s = atomicAdd(&tiecnt, 1);
      if (s < 256) tlist[s] = idx;
    }
  }
  __syncthreads();
  if (tid == 0) {
    int n = tiecnt < 256 ? tiecnt : 256;
    int basep = outcnt;                   // = 40 - kf
    for (int a = 0; a < kf; ++a) {
      int best = 1 << 30, bj = 0;
      for (int j = 0; j < n; ++j)
        if (tlist[j] < best) { best = tlist[j]; bj = j; }
      Mtop[bh * UT + basep + a] = best;
      tlist[bj] = 1 << 30;
    }
  }
}

// ---------------------------------------------------------------------------
// Sparse attention, chunked (unchanged)
// ---------------------------------------------------------------------------
__global__ __launch_bounds__(256) void attn_partial(const float* __restrict__ Qf,
    const float* __restrict__ Kf, const float* __restrict__ Vf,
    const int* __restrict__ Mtop, float* __restrict__ pmv,
    float* __restrict__ plv, float* __restrict__ pacc)
{
  const int bh = blockIdx.x, c = blockIdx.y;
  const int tid = threadIdx.x;
  const int w = tid >> 6, lane = tid & 63;
  __shared__ float sQ[UT][DKn];   // 10 KB
  __shared__ float sS[UT][CKn];   // 40 KB (scores -> exp(p))
  __shared__ float sK[64 * 64];   // 16 KB, XOR-swizzled

  for (int i = tid; i < UT * DKn; i += 256) {
    int r = i >> 6, d = i & 63;
    sQ[r][d] = Qf[(size_t)(bh * Ln + Mtop[bh * UT + r]) * DKn + d];
  }
  __syncthreads();

  const float* Kc = Kf + (size_t)(bh * Ln + c * CKn) * DKn;
  for (int sub = 0; sub < 4; ++sub) {
    for (int i = tid; i < 64 * DKn; i += 256) {
      int r = i >> 6, d = i & 63;
      sK[r * 64 + (d ^ ((r & 7) << 2))] = Kc[(size_t)(sub * 64 + r) * DKn + d];
    }
    __syncthreads();
    for (int it = 0; it < 10; ++it) {   // i = w + 4*it (wave-uniform), kk = lane
      int i = w + it * 4, kk = lane;
      float s = 0.f;
#pragma unroll
      for (int g = 0; g < 16; ++g) {
        float4 qv = *reinterpret_cast<const float4*>(&sQ[i][g * 4]);
        float4 kv = *reinterpret_cast<const float4*>(&sK[kk * 64 + ((g * 4) ^ ((kk & 7) << 2))]);
        s += qv.x * kv.x + qv.y * kv.y + qv.z * kv.z + qv.w * kv.w;
      }
      sS[i][sub * 64 + kk] = s * 0.125f;
    }
    __syncthreads();
  }

  // partial softmax per row
  for (int it = 0; it < 10; ++it) {
    int i = w + it * 4;
    float s0 = sS[i][lane], s1 = sS[i][lane + 64];
    float s2 = sS[i][lane + 128], s3 = sS[i][lane + 192];
    float mx = fmaxf(fmaxf(s0, s1), fmaxf(s2, s3));
#pragma unroll
    for (int off = 32; off; off >>= 1) mx = fmaxf(mx, __shfl_xor(mx, off));
    float p0 = expf(s0 - mx), p1 = expf(s1 - mx);
    float p2 = expf(s2 - mx), p3 = expf(s3 - mx);
    sS[i][lane] = p0; sS[i][lane + 64] = p1;
    sS[i][lane + 128] = p2; sS[i][lane + 192] = p3;
    float ls = p0 + p1 + p2 + p3;
#pragma unroll
    for (int off = 32; off; off >>= 1) ls += __shfl_xor(ls, off);
    if (lane == 0) {
      pmv[(bh * NCk + c) * UT + i] = mx;
      plv[(bh * NCk + c) * UT + i] = ls;
    }
  }
  __syncthreads();

  // PV partial: lane = (ksub, dq); V read straight from global (coalesced 1KB)
  const int ksub = lane >> 4, dq = lane & 15;
  const float* Vc = Vf + (size_t)(bh * Ln + c * CKn) * DKn;
  float4 acc[10];
#pragma unroll
  for (int t = 0; t < 10; ++t) acc[t] = make_float4(0.f, 0.f, 0.f, 0.f);
  for (int ko = 0; ko < 64; ++ko) {
    int kk = ko * 4 + ksub;
    float4 v4 = *reinterpret_cast<const float4*>(&Vc[(size_t)kk * DKn + dq * 4]);
#pragma unroll
    for (int t = 0; t < 10; ++t) {
      float wgt = sS[w + t * 4][kk];
      acc[t].x += wgt * v4.x; acc[t].y += wgt * v4.y;
      acc[t].z += wgt * v4.z; acc[t].w += wgt * v4.w;
    }
  }
#pragma unroll
  for (int t = 0; t < 10; ++t) {
#pragma unroll
    for (int off = 16; off <= 32; off <<= 1) {
      acc[t].x += __shfl_xor(acc[t].x, off);
      acc[t].y += __shfl_xor(acc[t].y, off);
      acc[t].z += __shfl_xor(acc[t].z, off);
      acc[t].w += __shfl_xor(acc[t].w, off);
    }
  }
  if (ksub == 0) {
#pragma unroll
    for (int t = 0; t < 10; ++t) {
      int i = w + t * 4;
      *reinterpret_cast<float4*>(&pacc[(size_t)((bh * NCk + c) * UT + i) * DKn + dq * 4]) = acc[t];
    }
  }
}

// ---------------------------------------------------------------------------
// base[b][n] = meanrow_b @ Wo.T + bo
// ---------------------------------------------------------------------------
__global__ __launch_bounds__(256) void base_proj(const float* __restrict__ meanV,
    const float* __restrict__ Wo, const float* __restrict__ bo,
    float* __restrict__ base)
{
  int b = blockIdx.x, tid = threadIdx.x;
#pragma unroll
  for (int rep = 0; rep < 2; ++rep) {
    int n = tid + rep * 256;
    float s = bo[n];
#pragma unroll 8
    for (int g = 0; g < 128; ++g) {
      float4 wv = *reinterpret_cast<const float4*>(&Wo[(size_t)n * Dn + g * 4]);
      float4 mv = *reinterpret_cast<const float4*>(&meanV[b * Dn + g * 4]);
      s += wv.x * mv.x + wv.y * mv.y + wv.z * mv.z + wv.w * mv.w;
    }
    base[b * Dn + n] = s;
  }
}

__global__ __launch_bounds__(256) void base_fill(const float* __restrict__ base,
                                                 float* __restrict__ out)
{
  int idx = blockIdx.x * 256 + threadIdx.x;  // float4 index, 1048576 total
  int row = idx >> 7, col4 = idx & 127;
  int b = row >> 11;
  reinterpret_cast<float4*>(out)[idx] =
      reinterpret_cast<const float4*>(base)[b * 128 + col4];
}

// ---------------------------------------------------------------------------
// combine partials -> context row; delta = row - meanV; scatter-add
// ---------------------------------------------------------------------------
__global__ __launch_bounds__(256) void combine_scatter(const float* __restrict__ pmv,
    const float* __restrict__ plv, const float* __restrict__ pacc,
    const int* __restrict__ Mtop, const float* __restrict__ meanV,
    const float* __restrict__ Wo, float* __restrict__ out)
{
  int bi = blockIdx.x;            // 0..1279
  int bh = bi / UT, i = bi % UT;
  int b = bh >> 3, h = bh & 7;
  int tid = threadIdx.x;
  __shared__ float v[DKn];
  if (tid < 64) {
    int d = tid;
    float mg = -INFINITY;
#pragma unroll
    for (int cc = 0; cc < NCk; ++cc) mg = fmaxf(mg, pmv[(bh * NCk + cc) * UT + i]);
    float den = 0.f, num = 0.f;
#pragma unroll
    for (int cc = 0; cc < NCk; ++cc) {
      float e = expf(pmv[(bh * NCk + cc) * UT + i] - mg);
      den += plv[(bh * NCk + cc) * UT + i] * e;
      num += e * pacc[(size_t)((bh * NCk + cc) * UT + i) * DKn + d];
    }
    v[d] = num / den - meanV[bh * DKn + d];
  }
  __syncthreads();
  int q = Mtop[bh * UT + i];
  float* orow = out + (size_t)(b * Ln + q) * Dn;
  const float* Wh = Wo + h * DKn;
#pragma unroll
  for (int rep = 0; rep < 2; ++rep) {
    int n = tid + rep * 256;
    float s = 0.f;
#pragma unroll
    for (int g = 0; g < 16; ++g) {
      float4 wv = *reinterpret_cast<const float4*>(&Wh[(size_t)n * Dn + g * 4]);
      float4 vv = *reinterpret_cast<const float4*>(&v[g * 4]);
      s += wv.x * vv.x + wv.y * vv.y + wv.z * vv.z + wv.w * vv.w;
    }
    atomicAdd(&orow[n], s);
  }
}

// ---------------------------------------------------------------------------
extern "C" void kernel_launch(void* const* d_in, const int* in_sizes, int n_in,
                              void* d_out, int out_size, void* d_ws, size_t ws_size,
                              hipStream_t stream)
{
  const float* queries = (const float*)d_in[0];
  const float* keys    = (const float*)d_in[1];
  const float* values  = (const float*)d_in[2];
  const float* Wq = (const float*)d_in[3];
  const float* bq = (const float*)d_in[4];
  const float* Wk = (const float*)d_in[5];
  const float* bk = (const float*)d_in[6];
  const float* Wv = (const float*)d_in[7];
  const float* bv = (const float*)d_in[8];
  const float* Wo = (const float*)d_in[9];
  const float* bo = (const float*)d_in[10];
  const int* isamp = (const int*)d_in[11];
  float* out = (float*)d_out;

  float* ws = (float*)d_ws;
  const size_t NBL = (size_t)Bn * Hn * Ln * DKn;  // 4194304
  float* Qf    = ws;
  float* Kf    = Qf + NBL;
  float* Vf    = Kf + NBL;
  float* meanV = Vf + NBL;                       // 2048
  float* Mv    = meanV + Bn * Hn * DKn;          // 65536
  float* pmv   = Mv + Bn * Hn * Ln;              // 10240
  float* plv   = pmv + Bn * Hn * NCk * UT;       // 10240
  float* pacc  = plv + Bn * Hn * NCk * UT;       // 655360
  float* base  = pacc + (size_t)Bn * Hn * NCk * UT * DKn;  // 2048
  int* Mtop    = (int*)(base + Bn * Dn);         // 1280 ints
  ushort_t* Acat = (ushort_t*)(base + Bn * Dn + 1280);     // 8192*1024 ushort
  ushort_t* Wcat = Acat + (size_t)8192 * 1024;             // 512*1536 ushort
  float* vpart = (float*)(Wcat + (size_t)512 * 1536);      // 32*16*64 floats

  dim3 gg(4, 128);  // (N/128, M/64)
  split_in<<<4096, 256, 0, stream>>>(queries, Acat);
  split_w<<<256, 256, 0, stream>>>(Wq, Wcat);
  gemm3_bf16<<<gg, 256, 0, stream>>>(Acat, Wcat, bq, Qf);
  split_in<<<4096, 256, 0, stream>>>(keys, Acat);
  split_w<<<256, 256, 0, stream>>>(Wk, Wcat);
  gemm3_bf16<<<gg, 256, 0, stream>>>(Acat, Wcat, bk, Kf);
  split_in<<<4096, 256, 0, stream>>>(values, Acat);
  split_w<<<256, 256, 0, stream>>>(Wv, Wcat);
  gemm3_bf16<<<gg, 256, 0, stream>>>(Acat, Wcat, bv, Vf);

  vmean1<<<dim3(Bn * Hn, 16), 256, 0, stream>>>(Vf, vpart);
  vmean2<<<Bn * Hn, 64, 0, stream>>>(vpart, meanV);
  qk_sample_m2<<<Bn * Hn * Ln / 4, 256, 0, stream>>>(Qf, Kf, isamp, Mv);
  topk40<<<Bn * Hn, 256, 0, stream>>>(Mv, Mtop);
  attn_partial<<<dim3(Bn * Hn, NCk), 256, 0, stream>>>(Qf, Kf, Vf, Mtop, pmv, plv, pacc);
  base_proj<<<Bn, 256, 0, stream>>>(meanV, Wo, bo, base);
  base_fill<<<4096, 256, 0, stream>>>(base, out);
  combine_scatter<<<Bn * Hn * UT, 256, 0, stream>>>(pmv, plv, pacc, Mtop, meanV, Wo, out);
}

// Round 6
// 377.061 us; speedup vs baseline: 1.9926x; 1.0019x over previous
//
#include <hip/hip_runtime.h>
#include <math.h>

// Problem constants (fixed by reference: B=4, L=2048, D=512, H=8, dk=64, FACTOR=5)
constexpr int Bn  = 4;
constexpr int Ln  = 2048;
constexpr int Dn  = 512;
constexpr int Hn  = 8;
constexpr int DKn = 64;
constexpr int US  = 40;   // U = min(5*ceil(ln(2049)), 2048) = 40
constexpr int UT  = 40;   // u = 40 (top-k count)
constexpr int NCk = 32;   // key chunks for sparse attention (round 6: 8 -> 32)
constexpr int CKn = 64;   // keys per chunk (NCk*CKn == Ln)

typedef unsigned short ushort_t;

// ---------------------------------------------------------------------------
// bf16 split helpers (RNE)
// ---------------------------------------------------------------------------
__device__ __forceinline__ ushort_t f2bf_rne(float x) {
  unsigned u = __float_as_uint(x);
  unsigned r = u + 0x7fffu + ((u >> 16) & 1u);
  return (ushort_t)(r >> 16);
}
__device__ __forceinline__ float bf2f(ushort_t h) {
  return __uint_as_float(((unsigned)h) << 16);
}

// X f32 [8192][512] -> A ushort [8192][1024] = [hi | lo]
__global__ __launch_bounds__(256) void split_in(const float* __restrict__ X,
                                                ushort_t* __restrict__ A)
{
  int i = blockIdx.x * 256 + threadIdx.x;      // 0..1048575
  int m = i >> 7, c4 = (i & 127) << 2;
  float4 x = *reinterpret_cast<const float4*>(&X[(size_t)m * 512 + c4]);
  ushort_t h0 = f2bf_rne(x.x), h1 = f2bf_rne(x.y), h2 = f2bf_rne(x.z), h3 = f2bf_rne(x.w);
  ushort_t l0 = f2bf_rne(x.x - bf2f(h0)), l1 = f2bf_rne(x.y - bf2f(h1));
  ushort_t l2 = f2bf_rne(x.z - bf2f(h2)), l3 = f2bf_rne(x.w - bf2f(h3));
  *reinterpret_cast<ushort4*>(&A[(size_t)m * 1024 + c4])       = make_ushort4(h0, h1, h2, h3);
  *reinterpret_cast<ushort4*>(&A[(size_t)m * 1024 + 512 + c4]) = make_ushort4(l0, l1, l2, l3);
}

// W f32 [512][512] -> Wcat ushort [512][1536] = [hi | lo | hi]
__global__ __launch_bounds__(256) void split_w(const float* __restrict__ W,
                                               ushort_t* __restrict__ Wc)
{
  int i = blockIdx.x * 256 + threadIdx.x;      // 0..65535
  int n = i >> 7, c4 = (i & 127) << 2;
  float4 x = *reinterpret_cast<const float4*>(&W[(size_t)n * 512 + c4]);
  ushort_t h0 = f2bf_rne(x.x), h1 = f2bf_rne(x.y), h2 = f2bf_rne(x.z), h3 = f2bf_rne(x.w);
  ushort_t l0 = f2bf_rne(x.x - bf2f(h0)), l1 = f2bf_rne(x.y - bf2f(h1));
  ushort_t l2 = f2bf_rne(x.z - bf2f(h2)), l3 = f2bf_rne(x.w - bf2f(h3));
  ushort4 hv = make_ushort4(h0, h1, h2, h3);
  ushort4 lv = make_ushort4(l0, l1, l2, l3);
  *reinterpret_cast<ushort4*>(&Wc[(size_t)n * 1536 + c4])        = hv;
  *reinterpret_cast<ushort4*>(&Wc[(size_t)n * 1536 + 512 + c4])  = lv;
  *reinterpret_cast<ushort4*>(&Wc[(size_t)n * 1536 + 1024 + c4]) = hv;
}

// ---------------------------------------------------------------------------
// bf16 3-term MFMA NT GEMM (unchanged; ref-checked in rounds 2-5)
// ---------------------------------------------------------------------------
using bf16x8 = short __attribute__((ext_vector_type(8)));
using f32x4  = float __attribute__((ext_vector_type(4)));

__device__ __forceinline__ void gload_lds16(const void* g, void* l) {
  __builtin_amdgcn_global_load_lds((const __attribute__((address_space(1))) void*)g,
                                   (__attribute__((address_space(3))) void*)l, 16, 0, 0);
}

__global__ __launch_bounds__(256) void gemm3_bf16(const ushort_t* __restrict__ Ast,
    const ushort_t* __restrict__ Bst, const float* __restrict__ bias,
    float* __restrict__ out)
{
  __shared__ __attribute__((aligned(16))) ushort_t sA[64 * 64];    // 8 KB
  __shared__ __attribute__((aligned(16))) ushort_t sB[128 * 64];   // 16 KB
  const int tid = threadIdx.x;
  const int w = tid >> 6, lane = tid & 63;
  const int m0 = blockIdx.y * 64, n0 = blockIdx.x * 128;
  const int wr = w >> 1, wc = w & 1;          // wave subtile (wr*32, wc*64)
  const int r16 = lane & 15, ko = (lane >> 4) * 8;

  f32x4 acc[2][4];
#pragma unroll
  for (int m = 0; m < 2; ++m)
#pragma unroll
    for (int n = 0; n < 4; ++n) acc[m][n] = (f32x4){0.f, 0.f, 0.f, 0.f};

  for (int k0 = 0; k0 < 1536; k0 += 64) {
    const int ka0 = (k0 < 1024) ? (k0 & 511) : (k0 - 512);
    __syncthreads();   // previous compute done before LDS overwrite
#pragma unroll
    for (int i = 0; i < 2; ++i) {              // stage A: 64 rows x 64 cols
      int e = i * 256 + tid, r = e >> 3, c8 = e & 7;
      gload_lds16(Ast + (size_t)(m0 + r) * 1024 + ka0 + c8 * 8,
                  (void*)(sA + (size_t)(i * 256 + w * 64) * 8));
    }
#pragma unroll
    for (int i = 0; i < 4; ++i) {              // stage B: 128 rows x 64 cols
      int e = i * 256 + tid, r = e >> 3, c8 = e & 7;
      gload_lds16(Bst + (size_t)(n0 + r) * 1536 + k0 + c8 * 8,
                  (void*)(sB + (size_t)(i * 256 + w * 64) * 8));
    }
    __syncthreads();   // drains vmcnt(0) before barrier
#pragma unroll
    for (int kk = 0; kk < 64; kk += 32) {
      bf16x8 a[2], b[4];
#pragma unroll
      for (int m = 0; m < 2; ++m)
        a[m] = *reinterpret_cast<const bf16x8*>(&sA[(wr * 32 + m * 16 + r16) * 64 + kk + ko]);
#pragma unroll
      for (int n = 0; n < 4; ++n)
        b[n] = *reinterpret_cast<const bf16x8*>(&sB[(wc * 64 + n * 16 + r16) * 64 + kk + ko]);
#pragma unroll
      for (int m = 0; m < 2; ++m)
#pragma unroll
        for (int n = 0; n < 4; ++n)
          acc[m][n] = __builtin_amdgcn_mfma_f32_16x16x32_bf16(a[m], b[n], acc[m][n], 0, 0, 0);
    }
  }

  // epilogue: C row = (lane>>4)*4 + reg, col = lane&15 (m89-verified layout)
#pragma unroll
  for (int m = 0; m < 2; ++m) {
#pragma unroll
    for (int n = 0; n < 4; ++n) {
#pragma unroll
      for (int r = 0; r < 4; ++r) {
        int row = m0 + wr * 32 + m * 16 + (lane >> 4) * 4 + r;
        int col = n0 + wc * 64 + n * 16 + (lane & 15);
        float v = acc[m][n][r] + bias[col];
        int b = row >> 11, l = row & 2047, h = col >> 6, dd = col & 63;
        out[(size_t)((b * Hn + h) * Ln + l) * DKn + dd] = v;
      }
    }
  }
}

// ---------------------------------------------------------------------------
// vmean, two-stage
// ---------------------------------------------------------------------------
__global__ __launch_bounds__(256) void vmean1(const float* __restrict__ Vf,
                                              float* __restrict__ part)
{
  int bh = blockIdx.x, ch = blockIdx.y;       // 32 x 16
  int t = threadIdx.x;
  int d4 = t & 15, ls = t >> 4;
  const float* base = Vf + ((size_t)bh * Ln + ch * 128) * DKn;
  float4 s = make_float4(0.f, 0.f, 0.f, 0.f);
#pragma unroll
  for (int i = 0; i < 8; ++i) {
    float4 x = *reinterpret_cast<const float4*>(&base[(size_t)(ls + i * 16) * DKn + d4 * 4]);
    s.x += x.x; s.y += x.y; s.z += x.z; s.w += x.w;
  }
  __shared__ float4 red[16][16];
  red[ls][d4] = s;
  __syncthreads();
  if (t < 64) {
    int dd = t & 15, g = t >> 4;
    float4 a = red[g * 4 + 0][dd], b = red[g * 4 + 1][dd];
    float4 c = red[g * 4 + 2][dd], d = red[g * 4 + 3][dd];
    red[g * 4][dd] = make_float4(a.x + b.x + c.x + d.x, a.y + b.y + c.y + d.y,
                                 a.z + b.z + c.z + d.z, a.w + b.w + c.w + d.w);
  }
  __syncthreads();
  if (t < 16) {
    float4 a = red[0][t], b = red[4][t], c = red[8][t], d = red[12][t];
    float4 r = make_float4(a.x + b.x + c.x + d.x, a.y + b.y + c.y + d.y,
                           a.z + b.z + c.z + d.z, a.w + b.w + c.w + d.w);
    *reinterpret_cast<float4*>(&part[((size_t)(bh * 16 + ch)) * DKn + t * 4]) = r;
  }
}

__global__ __launch_bounds__(64) void vmean2(const float* __restrict__ part,
                                             float* __restrict__ meanV)
{
  int bh = blockIdx.x, d = threadIdx.x;
  float s = 0.f;
#pragma unroll
  for (int ch = 0; ch < 16; ++ch) s += part[((size_t)(bh * 16 + ch)) * DKn + d];
  meanV[bh * DKn + d] = s * (1.f / 2048.f);
}

// ---------------------------------------------------------------------------
// M[bh][q] = max_u(Q[q]·K[idx_u]) - sum_u(Q[q]·K[idx_u]) / LK
// ---------------------------------------------------------------------------
__global__ __launch_bounds__(256) void qk_sample_m2(const float* __restrict__ Qf,
    const float* __restrict__ Kf, const int* __restrict__ isamp,
    float* __restrict__ Mout)
{
  int wq = blockIdx.x * 4 + (threadIdx.x >> 6);  // global q over B*H*L
  int lane = threadIdx.x & 63;
  int g = lane >> 4, s = lane & 15;
  int bh = wq >> 11, q = wq & 2047;
  const float* Kb = Kf + (size_t)bh * Ln * DKn;
  float4 qv = *reinterpret_cast<const float4*>(&Qf[(size_t)(bh * Ln + q) * DKn + s * 4]);
  float mx = -INFINITY, sm = 0.f;
#pragma unroll
  for (int p = 0; p < 10; ++p) {
    int u = p * 4 + g;
    int idx = isamp[q * US + u];
    float4 kv = *reinterpret_cast<const float4*>(&Kb[(size_t)idx * DKn + s * 4]);
    float d = qv.x * kv.x + qv.y * kv.y + qv.z * kv.z + qv.w * kv.w;
#pragma unroll
    for (int off = 1; off < 16; off <<= 1) d += __shfl_xor(d, off);
    mx = fmaxf(mx, d);
    sm += d;
  }
#pragma unroll
  for (int off = 16; off <= 32; off <<= 1) {
    mx = fmaxf(mx, __shfl_xor(mx, off));
    sm += __shfl_xor(sm, off);
  }
  if (lane == 0) Mout[wq] = mx - sm * (1.f / 2048.f);
}

// ---------------------------------------------------------------------------
// top-40 of M[bh][0..2047] via radix-select (unchanged, ref-checked round 5)
// ---------------------------------------------------------------------------
__global__ __launch_bounds__(256) void topk40(const float* __restrict__ Mv,
                                              int* __restrict__ Mtop)
{
  int bh = blockIdx.x, tid = threadIdx.x;
  __shared__ unsigned hist[256];
  __shared__ unsigned sfx[256];
  __shared__ unsigned prefix_s, k_s;
  __shared__ int outcnt, tiecnt;
  __shared__ int tlist[256];

  unsigned key[8];
#pragma unroll
  for (int i = 0; i < 8; ++i) {
    unsigned u = __float_as_uint(Mv[bh * Ln + tid + i * 256]);
    key[i] = (u & 0x80000000u) ? ~u : (u | 0x80000000u);  // monotone inc map
  }
  if (tid == 0) { prefix_s = 0u; k_s = UT; outcnt = 0; tiecnt = 0; }
  __syncthreads();

  for (int d = 24; d >= 0; d -= 8) {
    hist[tid] = 0u;
    __syncthreads();
    unsigned pref = prefix_s;
    unsigned mask = (d == 24) ? 0u : (0xFFFFFFFFu << (d + 8));
#pragma unroll
    for (int i = 0; i < 8; ++i)
      if ((key[i] & mask) == pref) atomicAdd(&hist[(key[i] >> d) & 255u], 1u);
    __syncthreads();
    sfx[tid] = hist[tid];
    __syncthreads();
    for (int off = 1; off < 256; off <<= 1) {
      unsigned add = (tid + off < 256) ? sfx[tid + off] : 0u;
      __syncthreads();
      sfx[tid] += add;
      __syncthreads();
    }
    unsigned k = k_s;
    unsigned nxt = (tid < 255) ? sfx[tid + 1] : 0u;
    if (sfx[tid] >= k && nxt < k) {      // unique crossing bin
      prefix_s = pref | ((unsigned)tid << d);
      k_s = k - nxt;                      // still needed inside this bin
    }
    __syncthreads();
  }

  unsigned T = prefix_s;
  int kf = (int)k_s;                      // # to take among key == T
#pragma unroll
  for (int i = 0; i < 8; ++i) {
    int idx = tid + i * 256;
    if (key[i] > T) {
      int s = atomicAdd(&outcnt, 1);
      Mtop[bh * UT + s] = idx;
    } else if (key[i] == T) {
      int s = atomicAdd(&tiecnt, 1);
      if (s < 256) tlist[s] = idx;
    }
  }
  __syncthreads();
  if (tid == 0) {
    int n = tiecnt < 256 ? tiecnt : 256;
    int basep = outcnt;                   // = 40 - kf
    for (int a = 0; a < kf; ++a) {
      int best = 1 << 30, bj = 0;
      for (int j = 0; j < n; ++j)
        if (tlist[j] < best) { best = tlist[j]; bj = j; }
      Mtop[bh * UT + basep + a] = best;
      tlist[bj] = 1 << 30;
    }
  }
}

// ---------------------------------------------------------------------------
// Sparse attention: block (bh, c) handles CKn=64 keys for all 40 selected
// queries; emits partial (m, l, acc[64]) per (bh, c, i).
// Round 6: 32 chunks of 64 keys (was 8 x 256) -> 1024 blocks, 37 KB LDS.
// ---------------------------------------------------------------------------
__global__ __launch_bounds__(256) void attn_partial(const float* __restrict__ Qf,
    const float* __restrict__ Kf, const float* __restrict__ Vf,
    const int* __restrict__ Mtop, float* __restrict__ pmv,
    float* __restrict__ plv, float* __restrict__ pacc)
{
  const int bh = blockIdx.x, c = blockIdx.y;
  const int tid = threadIdx.x;
  const int w = tid >> 6, lane = tid & 63;
  __shared__ float sQ[UT][DKn];     // 10 KB
  __shared__ float sS[UT][CKn];     // 10 KB (scores -> exp(p))
  __shared__ float sK[CKn * DKn];   // 16 KB, XOR-swizzled (r&15)

  for (int i = tid; i < UT * DKn; i += 256) {
    int r = i >> 6, d = i & 63;
    sQ[r][d] = Qf[(size_t)(bh * Ln + Mtop[bh * UT + r]) * DKn + d];
  }
  const float* Kc = Kf + (size_t)(bh * Ln + c * CKn) * DKn;
  for (int i = tid; i < CKn * DKn; i += 256) {
    int r = i >> 6, d = i & 63;
    sK[r * 64 + (d ^ ((r & 15) << 2))] = Kc[(size_t)r * DKn + d];
  }
  __syncthreads();

  // QK^T: i = w + 4*it (wave-uniform row), kk = lane (key)
  for (int it = 0; it < 10; ++it) {
    int i = w + it * 4, kk = lane;
    float s = 0.f;
#pragma unroll
    for (int g = 0; g < 16; ++g) {
      float4 qv = *reinterpret_cast<const float4*>(&sQ[i][g * 4]);
      float4 kv = *reinterpret_cast<const float4*>(&sK[kk * 64 + ((g * 4) ^ ((kk & 15) << 2))]);
      s += qv.x * kv.x + qv.y * kv.y + qv.z * kv.z + qv.w * kv.w;
    }
    sS[i][kk] = s * 0.125f;
  }
  __syncthreads();

  // partial softmax per row (64 scores, one per lane)
  for (int it = 0; it < 10; ++it) {
    int i = w + it * 4;
    float s0 = sS[i][lane];
    float mx = s0;
#pragma unroll
    for (int off = 32; off; off >>= 1) mx = fmaxf(mx, __shfl_xor(mx, off));
    float p0 = expf(s0 - mx);
    sS[i][lane] = p0;
    float ls = p0;
#pragma unroll
    for (int off = 32; off; off >>= 1) ls += __shfl_xor(ls, off);
    if (lane == 0) {
      pmv[(bh * NCk + c) * UT + i] = mx;
      plv[(bh * NCk + c) * UT + i] = ls;
    }
  }
  __syncthreads();

  // PV partial: lane = (ksub, dq); V read straight from global (coalesced)
  const int ksub = lane >> 4, dq = lane & 15;
  const float* Vc = Vf + (size_t)(bh * Ln + c * CKn) * DKn;
  float4 acc[10];
#pragma unroll
  for (int t = 0; t < 10; ++t) acc[t] = make_float4(0.f, 0.f, 0.f, 0.f);
  for (int ko = 0; ko < 16; ++ko) {
    int kk = ko * 4 + ksub;
    float4 v4 = *reinterpret_cast<const float4*>(&Vc[(size_t)kk * DKn + dq * 4]);
#pragma unroll
    for (int t = 0; t < 10; ++t) {
      float wgt = sS[w + t * 4][kk];
      acc[t].x += wgt * v4.x; acc[t].y += wgt * v4.y;
      acc[t].z += wgt * v4.z; acc[t].w += wgt * v4.w;
    }
  }
#pragma unroll
  for (int t = 0; t < 10; ++t) {
#pragma unroll
    for (int off = 16; off <= 32; off <<= 1) {
      acc[t].x += __shfl_xor(acc[t].x, off);
      acc[t].y += __shfl_xor(acc[t].y, off);
      acc[t].z += __shfl_xor(acc[t].z, off);
      acc[t].w += __shfl_xor(acc[t].w, off);
    }
  }
  if (ksub == 0) {
#pragma unroll
    for (int t = 0; t < 10; ++t) {
      int i = w + t * 4;
      *reinterpret_cast<float4*>(&pacc[(size_t)((bh * NCk + c) * UT + i) * DKn + dq * 4]) = acc[t];
    }
  }
}

// ---------------------------------------------------------------------------
// base[b][n] = meanrow_b @ Wo.T + bo
// ---------------------------------------------------------------------------
__global__ __launch_bounds__(256) void base_proj(const float* __restrict__ meanV,
    const float* __restrict__ Wo, const float* __restrict__ bo,
    float* __restrict__ base)
{
  int b = blockIdx.x, tid = threadIdx.x;
#pragma unroll
  for (int rep = 0; rep < 2; ++rep) {
    int n = tid + rep * 256;
    float s = bo[n];
#pragma unroll 8
    for (int g = 0; g < 128; ++g) {
      float4 wv = *reinterpret_cast<const float4*>(&Wo[(size_t)n * Dn + g * 4]);
      float4 mv = *reinterpret_cast<const float4*>(&meanV[b * Dn + g * 4]);
      s += wv.x * mv.x + wv.y * mv.y + wv.z * mv.z + wv.w * mv.w;
    }
    base[b * Dn + n] = s;
  }
}

__global__ __launch_bounds__(256) void base_fill(const float* __restrict__ base,
                                                 float* __restrict__ out)
{
  int idx = blockIdx.x * 256 + threadIdx.x;  // float4 index, 1048576 total
  int row = idx >> 7, col4 = idx & 127;
  int b = row >> 11;
  reinterpret_cast<float4*>(out)[idx] =
      reinterpret_cast<const float4*>(base)[b * 128 + col4];
}

// ---------------------------------------------------------------------------
// combine partials -> context row; delta = row - meanV; scatter-add
// ---------------------------------------------------------------------------
__global__ __launch_bounds__(256) void combine_scatter(const float* __restrict__ pmv,
    const float* __restrict__ plv, const float* __restrict__ pacc,
    const int* __restrict__ Mtop, const float* __restrict__ meanV,
    const float* __restrict__ Wo, float* __restrict__ out)
{
  int bi = blockIdx.x;            // 0..1279
  int bh = bi / UT, i = bi % UT;
  int b = bh >> 3, h = bh & 7;
  int tid = threadIdx.x;
  __shared__ float v[DKn];
  if (tid < 64) {
    int d = tid;
    float mg = -INFINITY;
    for (int cc = 0; cc < NCk; ++cc) mg = fmaxf(mg, pmv[(bh * NCk + cc) * UT + i]);
    float den = 0.f, num = 0.f;
    for (int cc = 0; cc < NCk; ++cc) {
      float e = expf(pmv[(bh * NCk + cc) * UT + i] - mg);
      den += plv[(bh * NCk + cc) * UT + i] * e;
      num += e * pacc[(size_t)((bh * NCk + cc) * UT + i) * DKn + d];
    }
    v[d] = num / den - meanV[bh * DKn + d];
  }
  __syncthreads();
  int q = Mtop[bh * UT + i];
  float* orow = out + (size_t)(b * Ln + q) * Dn;
  const float* Wh = Wo + h * DKn;
#pragma unroll
  for (int rep = 0; rep < 2; ++rep) {
    int n = tid + rep * 256;
    float s = 0.f;
#pragma unroll
    for (int g = 0; g < 16; ++g) {
      float4 wv = *reinterpret_cast<const float4*>(&Wh[(size_t)n * Dn + g * 4]);
      float4 vv = *reinterpret_cast<const float4*>(&v[g * 4]);
      s += wv.x * vv.x + wv.y * vv.y + wv.z * vv.z + wv.w * vv.w;
    }
    atomicAdd(&orow[n], s);
  }
}

// ---------------------------------------------------------------------------
extern "C" void kernel_launch(void* const* d_in, const int* in_sizes, int n_in,
                              void* d_out, int out_size, void* d_ws, size_t ws_size,
                              hipStream_t stream)
{
  const float* queries = (const float*)d_in[0];
  const float* keys    = (const float*)d_in[1];
  const float* values  = (const float*)d_in[2];
  const float* Wq = (const float*)d_in[3];
  const float* bq = (const float*)d_in[4];
  const float* Wk = (const float*)d_in[5];
  const float* bk = (const float*)d_in[6];
  const float* Wv = (const float*)d_in[7];
  const float* bv = (const float*)d_in[8];
  const float* Wo = (const float*)d_in[9];
  const float* bo = (const float*)d_in[10];
  const int* isamp = (const int*)d_in[11];
  float* out = (float*)d_out;

  float* ws = (float*)d_ws;
  const size_t NBL = (size_t)Bn * Hn * Ln * DKn;  // 4194304
  float* Qf    = ws;
  float* Kf    = Qf + NBL;
  float* Vf    = Kf + NBL;
  float* meanV = Vf + NBL;                        // 2048
  float* Mv    = meanV + Bn * Hn * DKn;           // 65536
  float* pmv   = Mv + Bn * Hn * Ln;               // 32*32*40 = 40960
  float* plv   = pmv + Bn * Hn * NCk * UT;        // 40960
  float* base  = plv + Bn * Hn * NCk * UT;        // 2048
  int* Mtop    = (int*)(base + Bn * Dn);          // 1280 ints
  ushort_t* Acat = (ushort_t*)(Mtop + Bn * Hn * UT);       // 8192*1024 ushort
  ushort_t* Wcat = Acat + (size_t)8192 * 1024;             // 512*1536 ushort
  float* vpart = (float*)(Wcat + (size_t)512 * 1536);      // 32*16*64 floats
  // pacc (32*32*40*64 fl = 10.5 MB) aliases Acat (16 MB): Acat's last reader
  // is the third gemm3_bf16, which completes (stream-ordered) before
  // attn_partial writes pacc. Nothing touches Acat afterwards.
  float* pacc  = (float*)Acat;

  dim3 gg(4, 128);  // (N/128, M/64)
  split_in<<<4096, 256, 0, stream>>>(queries, Acat);
  split_w<<<256, 256, 0, stream>>>(Wq, Wcat);
  gemm3_bf16<<<gg, 256, 0, stream>>>(Acat, Wcat, bq, Qf);
  split_in<<<4096, 256, 0, stream>>>(keys, Acat);
  split_w<<<256, 256, 0, stream>>>(Wk, Wcat);
  gemm3_bf16<<<gg, 256, 0, stream>>>(Acat, Wcat, bk, Kf);
  split_in<<<4096, 256, 0, stream>>>(values, Acat);
  split_w<<<256, 256, 0, stream>>>(Wv, Wcat);
  gemm3_bf16<<<gg, 256, 0, stream>>>(Acat, Wcat, bv, Vf);

  vmean1<<<dim3(Bn * Hn, 16), 256, 0, stream>>>(Vf, vpart);
  vmean2<<<Bn * Hn, 64, 0, stream>>>(vpart, meanV);
  qk_sample_m2<<<Bn * Hn * Ln / 4, 256, 0, stream>>>(Qf, Kf, isamp, Mv);
  topk40<<<Bn * Hn, 256, 0, stream>>>(Mv, Mtop);
  attn_partial<<<dim3(Bn * Hn, NCk), 256, 0, stream>>>(Qf, Kf, Vf, Mtop, pmv, plv, pacc);
  base_proj<<<Bn, 256, 0, stream>>>(meanV, Wo, bo, base);
  base_fill<<<4096, 256, 0, stream>>>(base, out);
  combine_scatter<<<Bn * Hn * UT, 256, 0, stream>>>(pmv, plv, pacc, Mtop, meanV, Wo, out);
}

// Round 7
// 355.195 us; speedup vs baseline: 2.1153x; 1.0616x over previous
//
#include <hip/hip_runtime.h>
#include <math.h>

// Problem constants (fixed by reference: B=4, L=2048, D=512, H=8, dk=64, FACTOR=5)
constexpr int Bn  = 4;
constexpr int Ln  = 2048;
constexpr int Dn  = 512;
constexpr int Hn  = 8;
constexpr int DKn = 64;
constexpr int US  = 40;   // U = min(5*ceil(ln(2049)), 2048) = 40
constexpr int UT  = 40;   // u = 40 (top-k count)
constexpr int NCk = 32;   // key chunks for sparse attention
constexpr int CKn = 64;   // keys per chunk (NCk*CKn == Ln)

typedef unsigned short ushort_t;

// ---------------------------------------------------------------------------
// bf16 split helpers (RNE)
// ---------------------------------------------------------------------------
__device__ __forceinline__ ushort_t f2bf_rne(float x) {
  unsigned u = __float_as_uint(x);
  unsigned r = u + 0x7fffu + ((u >> 16) & 1u);
  return (ushort_t)(r >> 16);
}
__device__ __forceinline__ float bf2f(ushort_t h) {
  return __uint_as_float(((unsigned)h) << 16);
}

// X f32 [8192][512] -> A ushort [8192][1024] = [hi | lo]
__global__ __launch_bounds__(256) void split_in(const float* __restrict__ X,
                                                ushort_t* __restrict__ A)
{
  int i = blockIdx.x * 256 + threadIdx.x;      // 0..1048575
  int m = i >> 7, c4 = (i & 127) << 2;
  float4 x = *reinterpret_cast<const float4*>(&X[(size_t)m * 512 + c4]);
  ushort_t h0 = f2bf_rne(x.x), h1 = f2bf_rne(x.y), h2 = f2bf_rne(x.z), h3 = f2bf_rne(x.w);
  ushort_t l0 = f2bf_rne(x.x - bf2f(h0)), l1 = f2bf_rne(x.y - bf2f(h1));
  ushort_t l2 = f2bf_rne(x.z - bf2f(h2)), l3 = f2bf_rne(x.w - bf2f(h3));
  *reinterpret_cast<ushort4*>(&A[(size_t)m * 1024 + c4])       = make_ushort4(h0, h1, h2, h3);
  *reinterpret_cast<ushort4*>(&A[(size_t)m * 1024 + 512 + c4]) = make_ushort4(l0, l1, l2, l3);
}

// W f32 [512][512] -> Wcat ushort [512][1536] = [hi | lo | hi]
__global__ __launch_bounds__(256) void split_w(const float* __restrict__ W,
                                               ushort_t* __restrict__ Wc)
{
  int i = blockIdx.x * 256 + threadIdx.x;      // 0..65535
  int n = i >> 7, c4 = (i & 127) << 2;
  float4 x = *reinterpret_cast<const float4*>(&W[(size_t)n * 512 + c4]);
  ushort_t h0 = f2bf_rne(x.x), h1 = f2bf_rne(x.y), h2 = f2bf_rne(x.z), h3 = f2bf_rne(x.w);
  ushort_t l0 = f2bf_rne(x.x - bf2f(h0)), l1 = f2bf_rne(x.y - bf2f(h1));
  ushort_t l2 = f2bf_rne(x.z - bf2f(h2)), l3 = f2bf_rne(x.w - bf2f(h3));
  ushort4 hv = make_ushort4(h0, h1, h2, h3);
  ushort4 lv = make_ushort4(l0, l1, l2, l3);
  *reinterpret_cast<ushort4*>(&Wc[(size_t)n * 1536 + c4])        = hv;
  *reinterpret_cast<ushort4*>(&Wc[(size_t)n * 1536 + 512 + c4])  = lv;
  *reinterpret_cast<ushort4*>(&Wc[(size_t)n * 1536 + 1024 + c4]) = hv;
}

// ---------------------------------------------------------------------------
// bf16 3-term MFMA NT GEMM (unchanged; ref-checked in rounds 2-6)
// ---------------------------------------------------------------------------
using bf16x8 = short __attribute__((ext_vector_type(8)));
using f32x4  = float __attribute__((ext_vector_type(4)));

__device__ __forceinline__ void gload_lds16(const void* g, void* l) {
  __builtin_amdgcn_global_load_lds((const __attribute__((address_space(1))) void*)g,
                                   (__attribute__((address_space(3))) void*)l, 16, 0, 0);
}

__global__ __launch_bounds__(256) void gemm3_bf16(const ushort_t* __restrict__ Ast,
    const ushort_t* __restrict__ Bst, const float* __restrict__ bias,
    float* __restrict__ out)
{
  __shared__ __attribute__((aligned(16))) ushort_t sA[64 * 64];    // 8 KB
  __shared__ __attribute__((aligned(16))) ushort_t sB[128 * 64];   // 16 KB
  const int tid = threadIdx.x;
  const int w = tid >> 6, lane = tid & 63;
  const int m0 = blockIdx.y * 64, n0 = blockIdx.x * 128;
  const int wr = w >> 1, wc = w & 1;          // wave subtile (wr*32, wc*64)
  const int r16 = lane & 15, ko = (lane >> 4) * 8;

  f32x4 acc[2][4];
#pragma unroll
  for (int m = 0; m < 2; ++m)
#pragma unroll
    for (int n = 0; n < 4; ++n) acc[m][n] = (f32x4){0.f, 0.f, 0.f, 0.f};

  for (int k0 = 0; k0 < 1536; k0 += 64) {
    const int ka0 = (k0 < 1024) ? (k0 & 511) : (k0 - 512);
    __syncthreads();   // previous compute done before LDS overwrite
#pragma unroll
    for (int i = 0; i < 2; ++i) {              // stage A: 64 rows x 64 cols
      int e = i * 256 + tid, r = e >> 3, c8 = e & 7;
      gload_lds16(Ast + (size_t)(m0 + r) * 1024 + ka0 + c8 * 8,
                  (void*)(sA + (size_t)(i * 256 + w * 64) * 8));
    }
#pragma unroll
    for (int i = 0; i < 4; ++i) {              // stage B: 128 rows x 64 cols
      int e = i * 256 + tid, r = e >> 3, c8 = e & 7;
      gload_lds16(Bst + (size_t)(n0 + r) * 1536 + k0 + c8 * 8,
                  (void*)(sB + (size_t)(i * 256 + w * 64) * 8));
    }
    __syncthreads();   // drains vmcnt(0) before barrier
#pragma unroll
    for (int kk = 0; kk < 64; kk += 32) {
      bf16x8 a[2], b[4];
#pragma unroll
      for (int m = 0; m < 2; ++m)
        a[m] = *reinterpret_cast<const bf16x8*>(&sA[(wr * 32 + m * 16 + r16) * 64 + kk + ko]);
#pragma unroll
      for (int n = 0; n < 4; ++n)
        b[n] = *reinterpret_cast<const bf16x8*>(&sB[(wc * 64 + n * 16 + r16) * 64 + kk + ko]);
#pragma unroll
      for (int m = 0; m < 2; ++m)
#pragma unroll
        for (int n = 0; n < 4; ++n)
          acc[m][n] = __builtin_amdgcn_mfma_f32_16x16x32_bf16(a[m], b[n], acc[m][n], 0, 0, 0);
    }
  }

  // epilogue: C row = (lane>>4)*4 + reg, col = lane&15 (m89-verified layout)
#pragma unroll
  for (int m = 0; m < 2; ++m) {
#pragma unroll
    for (int n = 0; n < 4; ++n) {
#pragma unroll
      for (int r = 0; r < 4; ++r) {
        int row = m0 + wr * 32 + m * 16 + (lane >> 4) * 4 + r;
        int col = n0 + wc * 64 + n * 16 + (lane & 15);
        float v = acc[m][n][r] + bias[col];
        int b = row >> 11, l = row & 2047, h = col >> 6, dd = col & 63;
        out[(size_t)((b * Hn + h) * Ln + l) * DKn + dd] = v;
      }
    }
  }
}

// ---------------------------------------------------------------------------
// vmean, two-stage
// ---------------------------------------------------------------------------
__global__ __launch_bounds__(256) void vmean1(const float* __restrict__ Vf,
                                              float* __restrict__ part)
{
  int bh = blockIdx.x, ch = blockIdx.y;       // 32 x 16
  int t = threadIdx.x;
  int d4 = t & 15, ls = t >> 4;
  const float* base = Vf + ((size_t)bh * Ln + ch * 128) * DKn;
  float4 s = make_float4(0.f, 0.f, 0.f, 0.f);
#pragma unroll
  for (int i = 0; i < 8; ++i) {
    float4 x = *reinterpret_cast<const float4*>(&base[(size_t)(ls + i * 16) * DKn + d4 * 4]);
    s.x += x.x; s.y += x.y; s.z += x.z; s.w += x.w;
  }
  __shared__ float4 red[16][16];
  red[ls][d4] = s;
  __syncthreads();
  if (t < 64) {
    int dd = t & 15, g = t >> 4;
    float4 a = red[g * 4 + 0][dd], b = red[g * 4 + 1][dd];
    float4 c = red[g * 4 + 2][dd], d = red[g * 4 + 3][dd];
    red[g * 4][dd] = make_float4(a.x + b.x + c.x + d.x, a.y + b.y + c.y + d.y,
                                 a.z + b.z + c.z + d.z, a.w + b.w + c.w + d.w);
  }
  __syncthreads();
  if (t < 16) {
    float4 a = red[0][t], b = red[4][t], c = red[8][t], d = red[12][t];
    float4 r = make_float4(a.x + b.x + c.x + d.x, a.y + b.y + c.y + d.y,
                           a.z + b.z + c.z + d.z, a.w + b.w + c.w + d.w);
    *reinterpret_cast<float4*>(&part[((size_t)(bh * 16 + ch)) * DKn + t * 4]) = r;
  }
}

__global__ __launch_bounds__(64) void vmean2(const float* __restrict__ part,
                                             float* __restrict__ meanV)
{
  int bh = blockIdx.x, d = threadIdx.x;
  float s = 0.f;
#pragma unroll
  for (int ch = 0; ch < 16; ++ch) s += part[((size_t)(bh * 16 + ch)) * DKn + d];
  meanV[bh * DKn + d] = s * (1.f / 2048.f);
}

// ---------------------------------------------------------------------------
// M[bh][q] = max_u(Q[q]·K[idx_u]) - sum_u(Q[q]·K[idx_u]) / LK
// ---------------------------------------------------------------------------
__global__ __launch_bounds__(256) void qk_sample_m2(const float* __restrict__ Qf,
    const float* __restrict__ Kf, const int* __restrict__ isamp,
    float* __restrict__ Mout)
{
  int wq = blockIdx.x * 4 + (threadIdx.x >> 6);  // global q over B*H*L
  int lane = threadIdx.x & 63;
  int g = lane >> 4, s = lane & 15;
  int bh = wq >> 11, q = wq & 2047;
  const float* Kb = Kf + (size_t)bh * Ln * DKn;
  float4 qv = *reinterpret_cast<const float4*>(&Qf[(size_t)(bh * Ln + q) * DKn + s * 4]);
  float mx = -INFINITY, sm = 0.f;
#pragma unroll
  for (int p = 0; p < 10; ++p) {
    int u = p * 4 + g;
    int idx = isamp[q * US + u];
    float4 kv = *reinterpret_cast<const float4*>(&Kb[(size_t)idx * DKn + s * 4]);
    float d = qv.x * kv.x + qv.y * kv.y + qv.z * kv.z + qv.w * kv.w;
#pragma unroll
    for (int off = 1; off < 16; off <<= 1) d += __shfl_xor(d, off);
    mx = fmaxf(mx, d);
    sm += d;
  }
#pragma unroll
  for (int off = 16; off <= 32; off <<= 1) {
    mx = fmaxf(mx, __shfl_xor(mx, off));
    sm += __shfl_xor(sm, off);
  }
  if (lane == 0) Mout[wq] = mx - sm * (1.f / 2048.f);
}

// ---------------------------------------------------------------------------
// top-40 of M[bh][0..2047] via radix-select (unchanged, ref-checked round 5)
// ---------------------------------------------------------------------------
__global__ __launch_bounds__(256) void topk40(const float* __restrict__ Mv,
                                              int* __restrict__ Mtop)
{
  int bh = blockIdx.x, tid = threadIdx.x;
  __shared__ unsigned hist[256];
  __shared__ unsigned sfx[256];
  __shared__ unsigned prefix_s, k_s;
  __shared__ int outcnt, tiecnt;
  __shared__ int tlist[256];

  unsigned key[8];
#pragma unroll
  for (int i = 0; i < 8; ++i) {
    unsigned u = __float_as_uint(Mv[bh * Ln + tid + i * 256]);
    key[i] = (u & 0x80000000u) ? ~u : (u | 0x80000000u);  // monotone inc map
  }
  if (tid == 0) { prefix_s = 0u; k_s = UT; outcnt = 0; tiecnt = 0; }
  __syncthreads();

  for (int d = 24; d >= 0; d -= 8) {
    hist[tid] = 0u;
    __syncthreads();
    unsigned pref = prefix_s;
    unsigned mask = (d == 24) ? 0u : (0xFFFFFFFFu << (d + 8));
#pragma unroll
    for (int i = 0; i < 8; ++i)
      if ((key[i] & mask) == pref) atomicAdd(&hist[(key[i] >> d) & 255u], 1u);
    __syncthreads();
    sfx[tid] = hist[tid];
    __syncthreads();
    for (int off = 1; off < 256; off <<= 1) {
      unsigned add = (tid + off < 256) ? sfx[tid + off] : 0u;
      __syncthreads();
      sfx[tid] += add;
      __syncthreads();
    }
    unsigned k = k_s;
    unsigned nxt = (tid < 255) ? sfx[tid + 1] : 0u;
    if (sfx[tid] >= k && nxt < k) {      // unique crossing bin
      prefix_s = pref | ((unsigned)tid << d);
      k_s = k - nxt;                      // still needed inside this bin
    }
    __syncthreads();
  }

  unsigned T = prefix_s;
  int kf = (int)k_s;                      // # to take among key == T
#pragma unroll
  for (int i = 0; i < 8; ++i) {
    int idx = tid + i * 256;
    if (key[i] > T) {
      int s = atomicAdd(&outcnt, 1);
      Mtop[bh * UT + s] = idx;
    } else if (key[i] == T) {
      int s = atomicAdd(&tiecnt, 1);
      if (s < 256) tlist[s] = idx;
    }
  }
  __syncthreads();
  if (tid == 0) {
    int n = tiecnt < 256 ? tiecnt : 256;
    int basep = outcnt;                   // = 40 - kf
    for (int a = 0; a < kf; ++a) {
      int best = 1 << 30, bj = 0;
      for (int j = 0; j < n; ++j)
        if (tlist[j] < best) { best = tlist[j]; bj = j; }
      Mtop[bh * UT + basep + a] = best;
      tlist[bj] = 1 << 30;
    }
  }
}

// ---------------------------------------------------------------------------
// Sparse attention: block (bh, c) handles CKn=64 keys for all 40 selected
// queries (unchanged from round 6)
// ---------------------------------------------------------------------------
__global__ __launch_bounds__(256) void attn_partial(const float* __restrict__ Qf,
    const float* __restrict__ Kf, const float* __restrict__ Vf,
    const int* __restrict__ Mtop, float* __restrict__ pmv,
    float* __restrict__ plv, float* __restrict__ pacc)
{
  const int bh = blockIdx.x, c = blockIdx.y;
  const int tid = threadIdx.x;
  const int w = tid >> 6, lane = tid & 63;
  __shared__ float sQ[UT][DKn];     // 10 KB
  __shared__ float sS[UT][CKn];     // 10 KB (scores -> exp(p))
  __shared__ float sK[CKn * DKn];   // 16 KB, XOR-swizzled (r&15)

  for (int i = tid; i < UT * DKn; i += 256) {
    int r = i >> 6, d = i & 63;
    sQ[r][d] = Qf[(size_t)(bh * Ln + Mtop[bh * UT + r]) * DKn + d];
  }
  const float* Kc = Kf + (size_t)(bh * Ln + c * CKn) * DKn;
  for (int i = tid; i < CKn * DKn; i += 256) {
    int r = i >> 6, d = i & 63;
    sK[r * 64 + (d ^ ((r & 15) << 2))] = Kc[(size_t)r * DKn + d];
  }
  __syncthreads();

  // QK^T: i = w + 4*it (wave-uniform row), kk = lane (key)
  for (int it = 0; it < 10; ++it) {
    int i = w + it * 4, kk = lane;
    float s = 0.f;
#pragma unroll
    for (int g = 0; g < 16; ++g) {
      float4 qv = *reinterpret_cast<const float4*>(&sQ[i][g * 4]);
      float4 kv = *reinterpret_cast<const float4*>(&sK[kk * 64 + ((g * 4) ^ ((kk & 15) << 2))]);
      s += qv.x * kv.x + qv.y * kv.y + qv.z * kv.z + qv.w * kv.w;
    }
    sS[i][kk] = s * 0.125f;
  }
  __syncthreads();

  // partial softmax per row (64 scores, one per lane)
  for (int it = 0; it < 10; ++it) {
    int i = w + it * 4;
    float s0 = sS[i][lane];
    float mx = s0;
#pragma unroll
    for (int off = 32; off; off >>= 1) mx = fmaxf(mx, __shfl_xor(mx, off));
    float p0 = expf(s0 - mx);
    sS[i][lane] = p0;
    float ls = p0;
#pragma unroll
    for (int off = 32; off; off >>= 1) ls += __shfl_xor(ls, off);
    if (lane == 0) {
      pmv[(bh * NCk + c) * UT + i] = mx;
      plv[(bh * NCk + c) * UT + i] = ls;
    }
  }
  __syncthreads();

  // PV partial: lane = (ksub, dq); V read straight from global (coalesced)
  const int ksub = lane >> 4, dq = lane & 15;
  const float* Vc = Vf + (size_t)(bh * Ln + c * CKn) * DKn;
  float4 acc[10];
#pragma unroll
  for (int t = 0; t < 10; ++t) acc[t] = make_float4(0.f, 0.f, 0.f, 0.f);
  for (int ko = 0; ko < 16; ++ko) {
    int kk = ko * 4 + ksub;
    float4 v4 = *reinterpret_cast<const float4*>(&Vc[(size_t)kk * DKn + dq * 4]);
#pragma unroll
    for (int t = 0; t < 10; ++t) {
      float wgt = sS[w + t * 4][kk];
      acc[t].x += wgt * v4.x; acc[t].y += wgt * v4.y;
      acc[t].z += wgt * v4.z; acc[t].w += wgt * v4.w;
    }
  }
#pragma unroll
  for (int t = 0; t < 10; ++t) {
#pragma unroll
    for (int off = 16; off <= 32; off <<= 1) {
      acc[t].x += __shfl_xor(acc[t].x, off);
      acc[t].y += __shfl_xor(acc[t].y, off);
      acc[t].z += __shfl_xor(acc[t].z, off);
      acc[t].w += __shfl_xor(acc[t].w, off);
    }
  }
  if (ksub == 0) {
#pragma unroll
    for (int t = 0; t < 10; ++t) {
      int i = w + t * 4;
      *reinterpret_cast<float4*>(&pacc[(size_t)((bh * NCk + c) * UT + i) * DKn + dq * 4]) = acc[t];
    }
  }
}

// ---------------------------------------------------------------------------
// base[b][n] = meanrow_b @ Wo.T + bo
// ---------------------------------------------------------------------------
__global__ __launch_bounds__(256) void base_proj(const float* __restrict__ meanV,
    const float* __restrict__ Wo, const float* __restrict__ bo,
    float* __restrict__ base)
{
  int b = blockIdx.x, tid = threadIdx.x;
#pragma unroll
  for (int rep = 0; rep < 2; ++rep) {
    int n = tid + rep * 256;
    float s = bo[n];
#pragma unroll 8
    for (int g = 0; g < 128; ++g) {
      float4 wv = *reinterpret_cast<const float4*>(&Wo[(size_t)n * Dn + g * 4]);
      float4 mv = *reinterpret_cast<const float4*>(&meanV[b * Dn + g * 4]);
      s += wv.x * mv.x + wv.y * mv.y + wv.z * mv.z + wv.w * mv.w;
    }
    base[b * Dn + n] = s;
  }
}

__global__ __launch_bounds__(256) void base_fill(const float* __restrict__ base,
                                                 float* __restrict__ out)
{
  int idx = blockIdx.x * 256 + threadIdx.x;  // float4 index, 1048576 total
  int row = idx >> 7, col4 = idx & 127;
  int b = row >> 11;
  reinterpret_cast<float4*>(out)[idx] =
      reinterpret_cast<const float4*>(base)[b * 128 + col4];
}

// ---------------------------------------------------------------------------
// combine_ctx: reduce 32 chunk-partials -> delta rows ctxd[bh][40][64].
// Grid 32 (bh), 256 threads. Coalesced pacc reads (256B segments).
// ---------------------------------------------------------------------------
__global__ __launch_bounds__(256) void combine_ctx(const float* __restrict__ pmv,
    const float* __restrict__ plv, const float* __restrict__ pacc,
    const float* __restrict__ meanV, float* __restrict__ ctxd)
{
  int bh = blockIdx.x, tid = threadIdx.x;
  __shared__ float ew[UT][NCk];    // 5 KB: per-row chunk weights e
  __shared__ float den_s[UT];
  if (tid < UT) {
    float mg = -INFINITY;
#pragma unroll
    for (int cc = 0; cc < NCk; ++cc)
      mg = fmaxf(mg, pmv[(bh * NCk + cc) * UT + tid]);
    float den = 0.f;
#pragma unroll
    for (int cc = 0; cc < NCk; ++cc) {
      float e = expf(pmv[(bh * NCk + cc) * UT + tid] - mg);
      ew[tid][cc] = e;
      den += plv[(bh * NCk + cc) * UT + tid] * e;
    }
    den_s[tid] = den;
  }
  __syncthreads();
  for (int v = tid; v < UT * DKn; v += 256) {
    int i = v >> 6, d = v & 63;
    float num = 0.f;
#pragma unroll
    for (int cc = 0; cc < NCk; ++cc)
      num += ew[i][cc] * pacc[(size_t)((bh * NCk + cc) * UT + i) * DKn + d];
    ctxd[(size_t)(bh * UT + i) * DKn + d] = num / den_s[i] - meanV[bh * DKn + d];
  }
}

// ---------------------------------------------------------------------------
// scatter_proj: out[b, q_i, n] += dot(ctxd[bh][i][:], Wo[n][h*64:...]).
// Grid (8 ncol-chunks, 32 bh), 256 threads. Lane owns one n; its 256B Wo
// row-chunk is loaded ONCE into regs and reused across all 40 rows.
// ---------------------------------------------------------------------------
__global__ __launch_bounds__(256) void scatter_proj(const float* __restrict__ ctxd,
    const int* __restrict__ Mtop, const float* __restrict__ Wo,
    float* __restrict__ out)
{
  int nc = blockIdx.x, bh = blockIdx.y;
  int b = bh >> 3, h = bh & 7;
  int tid = threadIdx.x;
  __shared__ float sd[UT][DKn];    // 10 KB
  __shared__ int qidx[UT];
  for (int v = tid; v < UT * DKn; v += 256)
    sd[v >> 6][v & 63] = ctxd[(size_t)(bh * UT) * DKn + v];
  if (tid < UT) qidx[tid] = Mtop[bh * UT + tid];
  __syncthreads();

  int n = nc * 64 + (tid & 63);
  int i0 = tid >> 6;                       // 0..3
  const float* Wrow = Wo + (size_t)n * Dn + h * DKn;
  float4 wv[16];
#pragma unroll
  for (int g = 0; g < 16; ++g)
    wv[g] = *reinterpret_cast<const float4*>(&Wrow[g * 4]);

#pragma unroll
  for (int t = 0; t < 10; ++t) {
    int i = i0 + t * 4;
    float s = 0.f;
#pragma unroll
    for (int g = 0; g < 16; ++g) {
      float4 dv = *reinterpret_cast<const float4*>(&sd[i][g * 4]);
      s += wv[g].x * dv.x + wv[g].y * dv.y + wv[g].z * dv.z + wv[g].w * dv.w;
    }
    atomicAdd(&out[(size_t)(b * Ln + qidx[i]) * Dn + n], s);
  }
}

// ---------------------------------------------------------------------------
extern "C" void kernel_launch(void* const* d_in, const int* in_sizes, int n_in,
                              void* d_out, int out_size, void* d_ws, size_t ws_size,
                              hipStream_t stream)
{
  const float* queries = (const float*)d_in[0];
  const float* keys    = (const float*)d_in[1];
  const float* values  = (const float*)d_in[2];
  const float* Wq = (const float*)d_in[3];
  const float* bq = (const float*)d_in[4];
  const float* Wk = (const float*)d_in[5];
  const float* bk = (const float*)d_in[6];
  const float* Wv = (const float*)d_in[7];
  const float* bv = (const float*)d_in[8];
  const float* Wo = (const float*)d_in[9];
  const float* bo = (const float*)d_in[10];
  const int* isamp = (const int*)d_in[11];
  float* out = (float*)d_out;

  float* ws = (float*)d_ws;
  const size_t NBL = (size_t)Bn * Hn * Ln * DKn;  // 4194304
  float* Qf    = ws;
  float* Kf    = Qf + NBL;
  float* Vf    = Kf + NBL;
  float* meanV = Vf + NBL;                        // 2048
  float* Mv    = meanV + Bn * Hn * DKn;           // 65536
  float* pmv   = Mv + Bn * Hn * Ln;               // 40960
  float* plv   = pmv + Bn * Hn * NCk * UT;        // 40960
  float* base  = plv + Bn * Hn * NCk * UT;        // 2048
  int* Mtop    = (int*)(base + Bn * Dn);          // 1280 ints
  float* ctxd  = (float*)(Mtop + Bn * Hn * UT);   // 32*40*64 = 81920 floats
  ushort_t* Acat = (ushort_t*)(ctxd + (size_t)Bn * Hn * UT * DKn); // 8192*1024
  ushort_t* Wcat = Acat + (size_t)8192 * 1024;             // 512*1536 ushort
  float* vpart = (float*)(Wcat + (size_t)512 * 1536);      // 32*16*64 floats
  // pacc (10.5 MB) aliases Acat (16 MB): Acat's last reader is the third
  // gemm3_bf16, stream-ordered before attn_partial writes pacc.
  float* pacc  = (float*)Acat;

  dim3 gg(4, 128);  // (N/128, M/64)
  split_in<<<4096, 256, 0, stream>>>(queries, Acat);
  split_w<<<256, 256, 0, stream>>>(Wq, Wcat);
  gemm3_bf16<<<gg, 256, 0, stream>>>(Acat, Wcat, bq, Qf);
  split_in<<<4096, 256, 0, stream>>>(keys, Acat);
  split_w<<<256, 256, 0, stream>>>(Wk, Wcat);
  gemm3_bf16<<<gg, 256, 0, stream>>>(Acat, Wcat, bk, Kf);
  split_in<<<4096, 256, 0, stream>>>(values, Acat);
  split_w<<<256, 256, 0, stream>>>(Wv, Wcat);
  gemm3_bf16<<<gg, 256, 0, stream>>>(Acat, Wcat, bv, Vf);

  vmean1<<<dim3(Bn * Hn, 16), 256, 0, stream>>>(Vf, vpart);
  vmean2<<<Bn * Hn, 64, 0, stream>>>(vpart, meanV);
  qk_sample_m2<<<Bn * Hn * Ln / 4, 256, 0, stream>>>(Qf, Kf, isamp, Mv);
  topk40<<<Bn * Hn, 256, 0, stream>>>(Mv, Mtop);
  attn_partial<<<dim3(Bn * Hn, NCk), 256, 0, stream>>>(Qf, Kf, Vf, Mtop, pmv, plv, pacc);
  base_proj<<<Bn, 256, 0, stream>>>(meanV, Wo, bo, base);
  base_fill<<<4096, 256, 0, stream>>>(base, out);
  combine_ctx<<<Bn * Hn, 256, 0, stream>>>(pmv, plv, pacc, meanV, ctxd);
  scatter_proj<<<dim3(8, Bn * Hn), 256, 0, stream>>>(ctxd, Mtop, Wo, out);
}

// Round 8
// 327.503 us; speedup vs baseline: 2.2941x; 1.0846x over previous
//
#include <hip/hip_runtime.h>
#include <math.h>

// Problem constants (fixed by reference: B=4, L=2048, D=512, H=8, dk=64, FACTOR=5)
constexpr int Bn  = 4;
constexpr int Ln  = 2048;
constexpr int Dn  = 512;
constexpr int Hn  = 8;
constexpr int DKn = 64;
constexpr int US  = 40;   // U = min(5*ceil(ln(2049)), 2048) = 40
constexpr int UT  = 40;   // u = 40 (top-k count)
constexpr int NCk = 32;   // key chunks for sparse attention
constexpr int CKn = 64;   // keys per chunk (NCk*CKn == Ln)

typedef unsigned short ushort_t;

// ---------------------------------------------------------------------------
// bf16 split helpers (RNE)
// ---------------------------------------------------------------------------
__device__ __forceinline__ ushort_t f2bf_rne(float x) {
  unsigned u = __float_as_uint(x);
  unsigned r = u + 0x7fffu + ((u >> 16) & 1u);
  return (ushort_t)(r >> 16);
}
__device__ __forceinline__ float bf2f(ushort_t h) {
  return __uint_as_float(((unsigned)h) << 16);
}

// X f32 [8192][512] -> A ushort [8192][1024] = [hi | lo], batched over z=0..2
__global__ __launch_bounds__(256) void split_in3(const float* __restrict__ X0,
    const float* __restrict__ X1, const float* __restrict__ X2,
    ushort_t* __restrict__ A)
{
  int z = blockIdx.y;
  const float* X = (z == 0) ? X0 : ((z == 1) ? X1 : X2);
  ushort_t* Az = A + (size_t)z * 8192 * 1024;
  int i = blockIdx.x * 256 + threadIdx.x;      // 0..1048575
  int m = i >> 7, c4 = (i & 127) << 2;
  float4 x = *reinterpret_cast<const float4*>(&X[(size_t)m * 512 + c4]);
  ushort_t h0 = f2bf_rne(x.x), h1 = f2bf_rne(x.y), h2 = f2bf_rne(x.z), h3 = f2bf_rne(x.w);
  ushort_t l0 = f2bf_rne(x.x - bf2f(h0)), l1 = f2bf_rne(x.y - bf2f(h1));
  ushort_t l2 = f2bf_rne(x.z - bf2f(h2)), l3 = f2bf_rne(x.w - bf2f(h3));
  *reinterpret_cast<ushort4*>(&Az[(size_t)m * 1024 + c4])       = make_ushort4(h0, h1, h2, h3);
  *reinterpret_cast<ushort4*>(&Az[(size_t)m * 1024 + 512 + c4]) = make_ushort4(l0, l1, l2, l3);
}

// W f32 [512][512] -> Wcat ushort [512][1536] = [hi | lo | hi], batched
__global__ __launch_bounds__(256) void split_w3(const float* __restrict__ W0,
    const float* __restrict__ W1, const float* __restrict__ W2,
    ushort_t* __restrict__ Wc)
{
  int z = blockIdx.y;
  const float* W = (z == 0) ? W0 : ((z == 1) ? W1 : W2);
  ushort_t* Wz = Wc + (size_t)z * 512 * 1536;
  int i = blockIdx.x * 256 + threadIdx.x;      // 0..65535
  int n = i >> 7, c4 = (i & 127) << 2;
  float4 x = *reinterpret_cast<const float4*>(&W[(size_t)n * 512 + c4]);
  ushort_t h0 = f2bf_rne(x.x), h1 = f2bf_rne(x.y), h2 = f2bf_rne(x.z), h3 = f2bf_rne(x.w);
  ushort_t l0 = f2bf_rne(x.x - bf2f(h0)), l1 = f2bf_rne(x.y - bf2f(h1));
  ushort_t l2 = f2bf_rne(x.z - bf2f(h2)), l3 = f2bf_rne(x.w - bf2f(h3));
  ushort4 hv = make_ushort4(h0, h1, h2, h3);
  ushort4 lv = make_ushort4(l0, l1, l2, l3);
  *reinterpret_cast<ushort4*>(&Wz[(size_t)n * 1536 + c4])        = hv;
  *reinterpret_cast<ushort4*>(&Wz[(size_t)n * 1536 + 512 + c4])  = lv;
  *reinterpret_cast<ushort4*>(&Wz[(size_t)n * 1536 + 1024 + c4]) = hv;
}

// ---------------------------------------------------------------------------
// bf16 3-term MFMA NT GEMM, batched over z (Q/K/V). Inner structure
// unchanged from rounds 2-7 (ref-checked).
// ---------------------------------------------------------------------------
using bf16x8 = short __attribute__((ext_vector_type(8)));
using f32x4  = float __attribute__((ext_vector_type(4)));

__device__ __forceinline__ void gload_lds16(const void* g, void* l) {
  __builtin_amdgcn_global_load_lds((const __attribute__((address_space(1))) void*)g,
                                   (__attribute__((address_space(3))) void*)l, 16, 0, 0);
}

__global__ __launch_bounds__(256) void gemm3_bf16_all(const ushort_t* __restrict__ AcatAll,
    const ushort_t* __restrict__ WcatAll, const float* __restrict__ bq,
    const float* __restrict__ bk, const float* __restrict__ bv,
    float* __restrict__ QKVf)
{
  const int z = blockIdx.z;
  const ushort_t* Ast = AcatAll + (size_t)z * 8192 * 1024;
  const ushort_t* Bst = WcatAll + (size_t)z * 512 * 1536;
  const float* bias = (z == 0) ? bq : ((z == 1) ? bk : bv);
  float* out = QKVf + (size_t)z * Bn * Hn * Ln * DKn;

  __shared__ __attribute__((aligned(16))) ushort_t sA[64 * 64];    // 8 KB
  __shared__ __attribute__((aligned(16))) ushort_t sB[128 * 64];   // 16 KB
  const int tid = threadIdx.x;
  const int w = tid >> 6, lane = tid & 63;
  const int m0 = blockIdx.y * 64, n0 = blockIdx.x * 128;
  const int wr = w >> 1, wc = w & 1;          // wave subtile (wr*32, wc*64)
  const int r16 = lane & 15, ko = (lane >> 4) * 8;

  f32x4 acc[2][4];
#pragma unroll
  for (int m = 0; m < 2; ++m)
#pragma unroll
    for (int n = 0; n < 4; ++n) acc[m][n] = (f32x4){0.f, 0.f, 0.f, 0.f};

  for (int k0 = 0; k0 < 1536; k0 += 64) {
    const int ka0 = (k0 < 1024) ? (k0 & 511) : (k0 - 512);
    __syncthreads();   // previous compute done before LDS overwrite
#pragma unroll
    for (int i = 0; i < 2; ++i) {              // stage A: 64 rows x 64 cols
      int e = i * 256 + tid, r = e >> 3, c8 = e & 7;
      gload_lds16(Ast + (size_t)(m0 + r) * 1024 + ka0 + c8 * 8,
                  (void*)(sA + (size_t)(i * 256 + w * 64) * 8));
    }
#pragma unroll
    for (int i = 0; i < 4; ++i) {              // stage B: 128 rows x 64 cols
      int e = i * 256 + tid, r = e >> 3, c8 = e & 7;
      gload_lds16(Bst + (size_t)(n0 + r) * 1536 + k0 + c8 * 8,
                  (void*)(sB + (size_t)(i * 256 + w * 64) * 8));
    }
    __syncthreads();   // drains vmcnt(0) before barrier
#pragma unroll
    for (int kk = 0; kk < 64; kk += 32) {
      bf16x8 a[2], b[4];
#pragma unroll
      for (int m = 0; m < 2; ++m)
        a[m] = *reinterpret_cast<const bf16x8*>(&sA[(wr * 32 + m * 16 + r16) * 64 + kk + ko]);
#pragma unroll
      for (int n = 0; n < 4; ++n)
        b[n] = *reinterpret_cast<const bf16x8*>(&sB[(wc * 64 + n * 16 + r16) * 64 + kk + ko]);
#pragma unroll
      for (int m = 0; m < 2; ++m)
#pragma unroll
        for (int n = 0; n < 4; ++n)
          acc[m][n] = __builtin_amdgcn_mfma_f32_16x16x32_bf16(a[m], b[n], acc[m][n], 0, 0, 0);
    }
  }

  // epilogue: C row = (lane>>4)*4 + reg, col = lane&15 (m89-verified layout)
#pragma unroll
  for (int m = 0; m < 2; ++m) {
#pragma unroll
    for (int n = 0; n < 4; ++n) {
#pragma unroll
      for (int r = 0; r < 4; ++r) {
        int row = m0 + wr * 32 + m * 16 + (lane >> 4) * 4 + r;
        int col = n0 + wc * 64 + n * 16 + (lane & 15);
        float v = acc[m][n][r] + bias[col];
        int b = row >> 11, l = row & 2047, h = col >> 6, dd = col & 63;
        out[(size_t)((b * Hn + h) * Ln + l) * DKn + dd] = v;
      }
    }
  }
}

// ---------------------------------------------------------------------------
// vmean, two-stage
// ---------------------------------------------------------------------------
__global__ __launch_bounds__(256) void vmean1(const float* __restrict__ Vf,
                                              float* __restrict__ part)
{
  int bh = blockIdx.x, ch = blockIdx.y;       // 32 x 16
  int t = threadIdx.x;
  int d4 = t & 15, ls = t >> 4;
  const float* base = Vf + ((size_t)bh * Ln + ch * 128) * DKn;
  float4 s = make_float4(0.f, 0.f, 0.f, 0.f);
#pragma unroll
  for (int i = 0; i < 8; ++i) {
    float4 x = *reinterpret_cast<const float4*>(&base[(size_t)(ls + i * 16) * DKn + d4 * 4]);
    s.x += x.x; s.y += x.y; s.z += x.z; s.w += x.w;
  }
  __shared__ float4 red[16][16];
  red[ls][d4] = s;
  __syncthreads();
  if (t < 64) {
    int dd = t & 15, g = t >> 4;
    float4 a = red[g * 4 + 0][dd], b = red[g * 4 + 1][dd];
    float4 c = red[g * 4 + 2][dd], d = red[g * 4 + 3][dd];
    red[g * 4][dd] = make_float4(a.x + b.x + c.x + d.x, a.y + b.y + c.y + d.y,
                                 a.z + b.z + c.z + d.z, a.w + b.w + c.w + d.w);
  }
  __syncthreads();
  if (t < 16) {
    float4 a = red[0][t], b = red[4][t], c = red[8][t], d = red[12][t];
    float4 r = make_float4(a.x + b.x + c.x + d.x, a.y + b.y + c.y + d.y,
                           a.z + b.z + c.z + d.z, a.w + b.w + c.w + d.w);
    *reinterpret_cast<float4*>(&part[((size_t)(bh * 16 + ch)) * DKn + t * 4]) = r;
  }
}

__global__ __launch_bounds__(64) void vmean2(const float* __restrict__ part,
                                             float* __restrict__ meanV)
{
  int bh = blockIdx.x, d = threadIdx.x;
  float s = 0.f;
#pragma unroll
  for (int ch = 0; ch < 16; ++ch) s += part[((size_t)(bh * 16 + ch)) * DKn + d];
  meanV[bh * DKn + d] = s * (1.f / 2048.f);
}

// ---------------------------------------------------------------------------
// M[bh][q] = max_u(Q[q]·K[idx_u]) - sum_u(Q[q]·K[idx_u]) / LK
// ---------------------------------------------------------------------------
__global__ __launch_bounds__(256) void qk_sample_m2(const float* __restrict__ Qf,
    const float* __restrict__ Kf, const int* __restrict__ isamp,
    float* __restrict__ Mout)
{
  int wq = blockIdx.x * 4 + (threadIdx.x >> 6);  // global q over B*H*L
  int lane = threadIdx.x & 63;
  int g = lane >> 4, s = lane & 15;
  int bh = wq >> 11, q = wq & 2047;
  const float* Kb = Kf + (size_t)bh * Ln * DKn;
  float4 qv = *reinterpret_cast<const float4*>(&Qf[(size_t)(bh * Ln + q) * DKn + s * 4]);
  float mx = -INFINITY, sm = 0.f;
#pragma unroll
  for (int p = 0; p < 10; ++p) {
    int u = p * 4 + g;
    int idx = isamp[q * US + u];
    float4 kv = *reinterpret_cast<const float4*>(&Kb[(size_t)idx * DKn + s * 4]);
    float d = qv.x * kv.x + qv.y * kv.y + qv.z * kv.z + qv.w * kv.w;
#pragma unroll
    for (int off = 1; off < 16; off <<= 1) d += __shfl_xor(d, off);
    mx = fmaxf(mx, d);
    sm += d;
  }
#pragma unroll
  for (int off = 16; off <= 32; off <<= 1) {
    mx = fmaxf(mx, __shfl_xor(mx, off));
    sm += __shfl_xor(sm, off);
  }
  if (lane == 0) Mout[wq] = mx - sm * (1.f / 2048.f);
}

// ---------------------------------------------------------------------------
// top-40 of M[bh][0..2047] via radix-select (unchanged, ref-checked round 5)
// ---------------------------------------------------------------------------
__global__ __launch_bounds__(256) void topk40(const float* __restrict__ Mv,
                                              int* __restrict__ Mtop)
{
  int bh = blockIdx.x, tid = threadIdx.x;
  __shared__ unsigned hist[256];
  __shared__ unsigned sfx[256];
  __shared__ unsigned prefix_s, k_s;
  __shared__ int outcnt, tiecnt;
  __shared__ int tlist[256];

  unsigned key[8];
#pragma unroll
  for (int i = 0; i < 8; ++i) {
    unsigned u = __float_as_uint(Mv[bh * Ln + tid + i * 256]);
    key[i] = (u & 0x80000000u) ? ~u : (u | 0x80000000u);  // monotone inc map
  }
  if (tid == 0) { prefix_s = 0u; k_s = UT; outcnt = 0; tiecnt = 0; }
  __syncthreads();

  for (int d = 24; d >= 0; d -= 8) {
    hist[tid] = 0u;
    __syncthreads();
    unsigned pref = prefix_s;
    unsigned mask = (d == 24) ? 0u : (0xFFFFFFFFu << (d + 8));
#pragma unroll
    for (int i = 0; i < 8; ++i)
      if ((key[i] & mask) == pref) atomicAdd(&hist[(key[i] >> d) & 255u], 1u);
    __syncthreads();
    sfx[tid] = hist[tid];
    __syncthreads();
    for (int off = 1; off < 256; off <<= 1) {
      unsigned add = (tid + off < 256) ? sfx[tid + off] : 0u;
      __syncthreads();
      sfx[tid] += add;
      __syncthreads();
    }
    unsigned k = k_s;
    unsigned nxt = (tid < 255) ? sfx[tid + 1] : 0u;
    if (sfx[tid] >= k && nxt < k) {      // unique crossing bin
      prefix_s = pref | ((unsigned)tid << d);
      k_s = k - nxt;                      // still needed inside this bin
    }
    __syncthreads();
  }

  unsigned T = prefix_s;
  int kf = (int)k_s;                      // # to take among key == T
#pragma unroll
  for (int i = 0; i < 8; ++i) {
    int idx = tid + i * 256;
    if (key[i] > T) {
      int s = atomicAdd(&outcnt, 1);
      Mtop[bh * UT + s] = idx;
    } else if (key[i] == T) {
      int s = atomicAdd(&tiecnt, 1);
      if (s < 256) tlist[s] = idx;
    }
  }
  __syncthreads();
  if (tid == 0) {
    int n = tiecnt < 256 ? tiecnt : 256;
    int basep = outcnt;                   // = 40 - kf
    for (int a = 0; a < kf; ++a) {
      int best = 1 << 30, bj = 0;
      for (int j = 0; j < n; ++j)
        if (tlist[j] < best) { best = tlist[j]; bj = j; }
      Mtop[bh * UT + basep + a] = best;
      tlist[bj] = 1 << 30;
    }
  }
}

// ---------------------------------------------------------------------------
// Sparse attention: block (bh, c) handles CKn=64 keys for all 40 selected
// queries. Round 8: sQ LDS stage removed — Q rows read as wave-uniform
// global loads (L1/L2 broadcast); LDS 36 -> 26 KB for higher occupancy.
// ---------------------------------------------------------------------------
__global__ __launch_bounds__(256) void attn_partial(const float* __restrict__ Qf,
    const float* __restrict__ Kf, const float* __restrict__ Vf,
    const int* __restrict__ Mtop, float* __restrict__ pmv,
    float* __restrict__ plv, float* __restrict__ pacc)
{
  const int bh = blockIdx.x, c = blockIdx.y;
  const int tid = threadIdx.x;
  const int w = tid >> 6, lane = tid & 63;
  __shared__ float sS[UT][CKn];     // 10 KB (scores -> exp(p))
  __shared__ float sK[CKn * DKn];   // 16 KB, XOR-swizzled (r&15)
  __shared__ int qidx[UT];

  if (tid < UT) qidx[tid] = Mtop[bh * UT + tid];
  const float* Kc = Kf + (size_t)(bh * Ln + c * CKn) * DKn;
  for (int i = tid; i < CKn * DKn; i += 256) {
    int r = i >> 6, d = i & 63;
    sK[r * 64 + (d ^ ((r & 15) << 2))] = Kc[(size_t)r * DKn + d];
  }
  __syncthreads();

  // QK^T: i = w + 4*it (wave-uniform row), kk = lane (key)
  const float* Qb = Qf + (size_t)bh * Ln * DKn;
  for (int it = 0; it < 10; ++it) {
    int i = w + it * 4, kk = lane;
    const float* Qrow = Qb + (size_t)qidx[i] * DKn;   // wave-uniform
    float s = 0.f;
#pragma unroll
    for (int g = 0; g < 16; ++g) {
      float4 qv = *reinterpret_cast<const float4*>(&Qrow[g * 4]);
      float4 kv = *reinterpret_cast<const float4*>(&sK[kk * 64 + ((g * 4) ^ ((kk & 15) << 2))]);
      s += qv.x * kv.x + qv.y * kv.y + qv.z * kv.z + qv.w * kv.w;
    }
    sS[i][kk] = s * 0.125f;
  }
  __syncthreads();

  // partial softmax per row (64 scores, one per lane)
  for (int it = 0; it < 10; ++it) {
    int i = w + it * 4;
    float s0 = sS[i][lane];
    float mx = s0;
#pragma unroll
    for (int off = 32; off; off >>= 1) mx = fmaxf(mx, __shfl_xor(mx, off));
    float p0 = expf(s0 - mx);
    sS[i][lane] = p0;
    float ls = p0;
#pragma unroll
    for (int off = 32; off; off >>= 1) ls += __shfl_xor(ls, off);
    if (lane == 0) {
      pmv[(bh * NCk + c) * UT + i] = mx;
      plv[(bh * NCk + c) * UT + i] = ls;
    }
  }
  __syncthreads();

  // PV partial: lane = (ksub, dq); V read straight from global (coalesced)
  const int ksub = lane >> 4, dq = lane & 15;
  const float* Vc = Vf + (size_t)(bh * Ln + c * CKn) * DKn;
  float4 acc[10];
#pragma unroll
  for (int t = 0; t < 10; ++t) acc[t] = make_float4(0.f, 0.f, 0.f, 0.f);
  for (int ko = 0; ko < 16; ++ko) {
    int kk = ko * 4 + ksub;
    float4 v4 = *reinterpret_cast<const float4*>(&Vc[(size_t)kk * DKn + dq * 4]);
#pragma unroll
    for (int t = 0; t < 10; ++t) {
      float wgt = sS[w + t * 4][kk];
      acc[t].x += wgt * v4.x; acc[t].y += wgt * v4.y;
      acc[t].z += wgt * v4.z; acc[t].w += wgt * v4.w;
    }
  }
#pragma unroll
  for (int t = 0; t < 10; ++t) {
#pragma unroll
    for (int off = 16; off <= 32; off <<= 1) {
      acc[t].x += __shfl_xor(acc[t].x, off);
      acc[t].y += __shfl_xor(acc[t].y, off);
      acc[t].z += __shfl_xor(acc[t].z, off);
      acc[t].w += __shfl_xor(acc[t].w, off);
    }
  }
  if (ksub == 0) {
#pragma unroll
    for (int t = 0; t < 10; ++t) {
      int i = w + t * 4;
      *reinterpret_cast<float4*>(&pacc[(size_t)((bh * NCk + c) * UT + i) * DKn + dq * 4]) = acc[t];
    }
  }
}

// ---------------------------------------------------------------------------
// base[b][n] = meanrow_b @ Wo.T + bo
// ---------------------------------------------------------------------------
__global__ __launch_bounds__(256) void base_proj(const float* __restrict__ meanV,
    const float* __restrict__ Wo, const float* __restrict__ bo,
    float* __restrict__ base)
{
  int b = blockIdx.x, tid = threadIdx.x;
#pragma unroll
  for (int rep = 0; rep < 2; ++rep) {
    int n = tid + rep * 256;
    float s = bo[n];
#pragma unroll 8
    for (int g = 0; g < 128; ++g) {
      float4 wv = *reinterpret_cast<const float4*>(&Wo[(size_t)n * Dn + g * 4]);
      float4 mv = *reinterpret_cast<const float4*>(&meanV[b * Dn + g * 4]);
      s += wv.x * mv.x + wv.y * mv.y + wv.z * mv.z + wv.w * mv.w;
    }
    base[b * Dn + n] = s;
  }
}

__global__ __launch_bounds__(256) void base_fill(const float* __restrict__ base,
                                                 float* __restrict__ out)
{
  int idx = blockIdx.x * 256 + threadIdx.x;  // float4 index, 1048576 total
  int row = idx >> 7, col4 = idx & 127;
  int b = row >> 11;
  reinterpret_cast<float4*>(out)[idx] =
      reinterpret_cast<const float4*>(base)[b * 128 + col4];
}

// ---------------------------------------------------------------------------
// combine_ctx: reduce 32 chunk-partials -> delta rows ctxd[bh][40][64].
// ---------------------------------------------------------------------------
__global__ __launch_bounds__(256) void combine_ctx(const float* __restrict__ pmv,
    const float* __restrict__ plv, const float* __restrict__ pacc,
    const float* __restrict__ meanV, float* __restrict__ ctxd)
{
  int bh = blockIdx.x, tid = threadIdx.x;
  __shared__ float ew[UT][NCk];    // 5 KB: per-row chunk weights e
  __shared__ float den_s[UT];
  if (tid < UT) {
    float mg = -INFINITY;
#pragma unroll
    for (int cc = 0; cc < NCk; ++cc)
      mg = fmaxf(mg, pmv[(bh * NCk + cc) * UT + tid]);
    float den = 0.f;
#pragma unroll
    for (int cc = 0; cc < NCk; ++cc) {
      float e = expf(pmv[(bh * NCk + cc) * UT + tid] - mg);
      ew[tid][cc] = e;
      den += plv[(bh * NCk + cc) * UT + tid] * e;
    }
    den_s[tid] = den;
  }
  __syncthreads();
  for (int v = tid; v < UT * DKn; v += 256) {
    int i = v >> 6, d = v & 63;
    float num = 0.f;
#pragma unroll
    for (int cc = 0; cc < NCk; ++cc)
      num += ew[i][cc] * pacc[(size_t)((bh * NCk + cc) * UT + i) * DKn + d];
    ctxd[(size_t)(bh * UT + i) * DKn + d] = num / den_s[i] - meanV[bh * DKn + d];
  }
}

// ---------------------------------------------------------------------------
// scatter_proj: out[b, q_i, n] += dot(ctxd[bh][i][:], Wo[n][h*64:...]).
// ---------------------------------------------------------------------------
__global__ __launch_bounds__(256) void scatter_proj(const float* __restrict__ ctxd,
    const int* __restrict__ Mtop, const float* __restrict__ Wo,
    float* __restrict__ out)
{
  int nc = blockIdx.x, bh = blockIdx.y;
  int b = bh >> 3, h = bh & 7;
  int tid = threadIdx.x;
  __shared__ float sd[UT][DKn];    // 10 KB
  __shared__ int qidx[UT];
  for (int v = tid; v < UT * DKn; v += 256)
    sd[v >> 6][v & 63] = ctxd[(size_t)(bh * UT) * DKn + v];
  if (tid < UT) qidx[tid] = Mtop[bh * UT + tid];
  __syncthreads();

  int n = nc * 64 + (tid & 63);
  int i0 = tid >> 6;                       // 0..3
  const float* Wrow = Wo + (size_t)n * Dn + h * DKn;
  float4 wv[16];
#pragma unroll
  for (int g = 0; g < 16; ++g)
    wv[g] = *reinterpret_cast<const float4*>(&Wrow[g * 4]);

#pragma unroll
  for (int t = 0; t < 10; ++t) {
    int i = i0 + t * 4;
    float s = 0.f;
#pragma unroll
    for (int g = 0; g < 16; ++g) {
      float4 dv = *reinterpret_cast<const float4*>(&sd[i][g * 4]);
      s += wv[g].x * dv.x + wv[g].y * dv.y + wv[g].z * dv.z + wv[g].w * dv.w;
    }
    atomicAdd(&out[(size_t)(b * Ln + qidx[i]) * Dn + n], s);
  }
}

// ---------------------------------------------------------------------------
extern "C" void kernel_launch(void* const* d_in, const int* in_sizes, int n_in,
                              void* d_out, int out_size, void* d_ws, size_t ws_size,
                              hipStream_t stream)
{
  const float* queries = (const float*)d_in[0];
  const float* keys    = (const float*)d_in[1];
  const float* values  = (const float*)d_in[2];
  const float* Wq = (const float*)d_in[3];
  const float* bq = (const float*)d_in[4];
  const float* Wk = (const float*)d_in[5];
  const float* bk = (const float*)d_in[6];
  const float* Wv = (const float*)d_in[7];
  const float* bv = (const float*)d_in[8];
  const float* Wo = (const float*)d_in[9];
  const float* bo = (const float*)d_in[10];
  const int* isamp = (const int*)d_in[11];
  float* out = (float*)d_out;

  float* ws = (float*)d_ws;
  const size_t NBL = (size_t)Bn * Hn * Ln * DKn;  // 4194304
  float* Qf    = ws;                              // QKVf base (z-contiguous)
  float* Kf    = Qf + NBL;
  float* Vf    = Kf + NBL;
  float* meanV = Vf + NBL;                        // 2048
  float* Mv    = meanV + Bn * Hn * DKn;           // 65536
  float* pmv   = Mv + Bn * Hn * Ln;               // 40960
  float* plv   = pmv + Bn * Hn * NCk * UT;        // 40960
  float* base  = plv + Bn * Hn * NCk * UT;        // 2048
  int* Mtop    = (int*)(base + Bn * Dn);          // 1280 ints
  float* ctxd  = (float*)(Mtop + Bn * Hn * UT);   // 81920 floats
  ushort_t* AcatAll = (ushort_t*)(ctxd + (size_t)Bn * Hn * UT * DKn); // 3x8192x1024
  ushort_t* WcatAll = AcatAll + (size_t)3 * 8192 * 1024;   // 3x512x1536
  float* vpart = (float*)(WcatAll + (size_t)3 * 512 * 1536);  // 32*16*64
  // pacc (10.5 MB) aliases AcatAll (50 MB): AcatAll's last reader is
  // gemm3_bf16_all, stream-ordered before attn_partial writes pacc.
  float* pacc  = (float*)AcatAll;

  split_in3<<<dim3(4096, 3), 256, 0, stream>>>(queries, keys, values, AcatAll);
  split_w3<<<dim3(256, 3), 256, 0, stream>>>(Wq, Wk, Wv, WcatAll);
  gemm3_bf16_all<<<dim3(4, 128, 3), 256, 0, stream>>>(AcatAll, WcatAll, bq, bk, bv, Qf);

  vmean1<<<dim3(Bn * Hn, 16), 256, 0, stream>>>(Vf, vpart);
  vmean2<<<Bn * Hn, 64, 0, stream>>>(vpart, meanV);
  qk_sample_m2<<<Bn * Hn * Ln / 4, 256, 0, stream>>>(Qf, Kf, isamp, Mv);
  topk40<<<Bn * Hn, 256, 0, stream>>>(Mv, Mtop);
  attn_partial<<<dim3(Bn * Hn, NCk), 256, 0, stream>>>(Qf, Kf, Vf, Mtop, pmv, plv, pacc);
  base_proj<<<Bn, 256, 0, stream>>>(meanV, Wo, bo, base);
  base_fill<<<4096, 256, 0, stream>>>(base, out);
  combine_ctx<<<Bn * Hn, 256, 0, stream>>>(pmv, plv, pacc, meanV, ctxd);
  scatter_proj<<<dim3(8, Bn * Hn), 256, 0, stream>>>(ctxd, Mtop, Wo, out);
}

// Round 9
// 314.300 us; speedup vs baseline: 2.3905x; 1.0420x over previous
//
#include <hip/hip_runtime.h>
#include <math.h>

// Problem constants (fixed by reference: B=4, L=2048, D=512, H=8, dk=64, FACTOR=5)
constexpr int Bn  = 4;
constexpr int Ln  = 2048;
constexpr int Dn  = 512;
constexpr int Hn  = 8;
constexpr int DKn = 64;
constexpr int US  = 40;   // U = min(5*ceil(ln(2049)), 2048) = 40
constexpr int UT  = 40;   // u = 40 (top-k count)
constexpr int NCk = 32;   // key chunks for sparse attention
constexpr int CKn = 64;   // keys per chunk (NCk*CKn == Ln)

typedef unsigned short ushort_t;

// ---------------------------------------------------------------------------
// bf16 split helpers (RNE)
// ---------------------------------------------------------------------------
__device__ __forceinline__ ushort_t f2bf_rne(float x) {
  unsigned u = __float_as_uint(x);
  unsigned r = u + 0x7fffu + ((u >> 16) & 1u);
  return (ushort_t)(r >> 16);
}
__device__ __forceinline__ float bf2f(ushort_t h) {
  return __uint_as_float(((unsigned)h) << 16);
}

// X f32 [8192][512] -> A ushort [8192][1024] = [hi | lo], batched over z=0..2
__global__ __launch_bounds__(256) void split_in3(const float* __restrict__ X0,
    const float* __restrict__ X1, const float* __restrict__ X2,
    ushort_t* __restrict__ A)
{
  int z = blockIdx.y;
  const float* X = (z == 0) ? X0 : ((z == 1) ? X1 : X2);
  ushort_t* Az = A + (size_t)z * 8192 * 1024;
  int i = blockIdx.x * 256 + threadIdx.x;      // 0..1048575
  int m = i >> 7, c4 = (i & 127) << 2;
  float4 x = *reinterpret_cast<const float4*>(&X[(size_t)m * 512 + c4]);
  ushort_t h0 = f2bf_rne(x.x), h1 = f2bf_rne(x.y), h2 = f2bf_rne(x.z), h3 = f2bf_rne(x.w);
  ushort_t l0 = f2bf_rne(x.x - bf2f(h0)), l1 = f2bf_rne(x.y - bf2f(h1));
  ushort_t l2 = f2bf_rne(x.z - bf2f(h2)), l3 = f2bf_rne(x.w - bf2f(h3));
  *reinterpret_cast<ushort4*>(&Az[(size_t)m * 1024 + c4])       = make_ushort4(h0, h1, h2, h3);
  *reinterpret_cast<ushort4*>(&Az[(size_t)m * 1024 + 512 + c4]) = make_ushort4(l0, l1, l2, l3);
}

// W f32 [512][512] -> Wcat ushort [512][1536] = [hi | lo | hi], batched
__global__ __launch_bounds__(256) void split_w3(const float* __restrict__ W0,
    const float* __restrict__ W1, const float* __restrict__ W2,
    ushort_t* __restrict__ Wc)
{
  int z = blockIdx.y;
  const float* W = (z == 0) ? W0 : ((z == 1) ? W1 : W2);
  ushort_t* Wz = Wc + (size_t)z * 512 * 1536;
  int i = blockIdx.x * 256 + threadIdx.x;      // 0..65535
  int n = i >> 7, c4 = (i & 127) << 2;
  float4 x = *reinterpret_cast<const float4*>(&W[(size_t)n * 512 + c4]);
  ushort_t h0 = f2bf_rne(x.x), h1 = f2bf_rne(x.y), h2 = f2bf_rne(x.z), h3 = f2bf_rne(x.w);
  ushort_t l0 = f2bf_rne(x.x - bf2f(h0)), l1 = f2bf_rne(x.y - bf2f(h1));
  ushort_t l2 = f2bf_rne(x.z - bf2f(h2)), l3 = f2bf_rne(x.w - bf2f(h3));
  ushort4 hv = make_ushort4(h0, h1, h2, h3);
  ushort4 lv = make_ushort4(l0, l1, l2, l3);
  *reinterpret_cast<ushort4*>(&Wz[(size_t)n * 1536 + c4])        = hv;
  *reinterpret_cast<ushort4*>(&Wz[(size_t)n * 1536 + 512 + c4])  = lv;
  *reinterpret_cast<ushort4*>(&Wz[(size_t)n * 1536 + 1024 + c4]) = hv;
}

// ---------------------------------------------------------------------------
// bf16 3-term MFMA NT GEMM, batched over z (Q/K/V).
// Round 9: (1) LDS XOR-swizzle — global_load_lds dest stays LINEAR, the
// per-lane GLOBAL source col-block is XOR'd with (row&7), and ds_read
// applies the same XOR (both-sides pattern, rule #21). Kills the 16-way
// bank conflict of 128B-stride rows. (2) bijective XCD block swizzle so
// the 4 n-tile blocks sharing an A panel land on one XCD's L2.
// ---------------------------------------------------------------------------
using bf16x8 = short __attribute__((ext_vector_type(8)));
using f32x4  = float __attribute__((ext_vector_type(4)));

__device__ __forceinline__ void gload_lds16(const void* g, void* l) {
  __builtin_amdgcn_global_load_lds((const __attribute__((address_space(1))) void*)g,
                                   (__attribute__((address_space(3))) void*)l, 16, 0, 0);
}

__global__ __launch_bounds__(256) void gemm3_bf16_all(const ushort_t* __restrict__ AcatAll,
    const ushort_t* __restrict__ WcatAll, const float* __restrict__ bq,
    const float* __restrict__ bk, const float* __restrict__ bv,
    float* __restrict__ QKVf)
{
  // XCD-aware bijective remap of the (4,128,3) grid: nwg=1536 = 8*192
  const int lid = (blockIdx.z * 128 + blockIdx.y) * 4 + blockIdx.x;  // 0..1535
  const int swz = (lid & 7) * 192 + (lid >> 3);
  const int z   = swz >> 9;          // /512
  const int rem = swz & 511;
  const int m0  = (rem >> 2) * 64;
  const int n0  = (rem & 3) * 128;

  const ushort_t* Ast = AcatAll + (size_t)z * 8192 * 1024;
  const ushort_t* Bst = WcatAll + (size_t)z * 512 * 1536;
  const float* bias = (z == 0) ? bq : ((z == 1) ? bk : bv);
  float* out = QKVf + (size_t)z * Bn * Hn * Ln * DKn;

  __shared__ __attribute__((aligned(16))) ushort_t sA[64 * 64];    // 8 KB
  __shared__ __attribute__((aligned(16))) ushort_t sB[128 * 64];   // 16 KB
  const int tid = threadIdx.x;
  const int w = tid >> 6, lane = tid & 63;
  const int wr = w >> 1, wc = w & 1;          // wave subtile (wr*32, wc*64)
  const int r16 = lane & 15, ko = (lane >> 4) * 8;
  const int rswz = (r16 & 7) << 3;            // ds_read XOR (bits 3-5)

  f32x4 acc[2][4];
#pragma unroll
  for (int m = 0; m < 2; ++m)
#pragma unroll
    for (int n = 0; n < 4; ++n) acc[m][n] = (f32x4){0.f, 0.f, 0.f, 0.f};

  for (int k0 = 0; k0 < 1536; k0 += 64) {
    const int ka0 = (k0 < 1024) ? (k0 & 511) : (k0 - 512);
    __syncthreads();   // previous compute done before LDS overwrite
#pragma unroll
    for (int i = 0; i < 2; ++i) {              // stage A: 64 rows x 64 cols
      int e = i * 256 + tid, r = e >> 3, c8 = e & 7;
      gload_lds16(Ast + (size_t)(m0 + r) * 1024 + ka0 + (c8 ^ (r & 7)) * 8,
                  (void*)(sA + (size_t)(i * 256 + w * 64) * 8));
    }
#pragma unroll
    for (int i = 0; i < 4; ++i) {              // stage B: 128 rows x 64 cols
      int e = i * 256 + tid, r = e >> 3, c8 = e & 7;
      gload_lds16(Bst + (size_t)(n0 + r) * 1536 + k0 + (c8 ^ (r & 7)) * 8,
                  (void*)(sB + (size_t)(i * 256 + w * 64) * 8));
    }
    __syncthreads();   // drains vmcnt(0) before barrier
#pragma unroll
    for (int kk = 0; kk < 64; kk += 32) {
      bf16x8 a[2], b[4];
#pragma unroll
      for (int m = 0; m < 2; ++m)
        a[m] = *reinterpret_cast<const bf16x8*>(
            &sA[(wr * 32 + m * 16 + r16) * 64 + ((kk + ko) ^ rswz)]);
#pragma unroll
      for (int n = 0; n < 4; ++n)
        b[n] = *reinterpret_cast<const bf16x8*>(
            &sB[(wc * 64 + n * 16 + r16) * 64 + ((kk + ko) ^ rswz)]);
#pragma unroll
      for (int m = 0; m < 2; ++m)
#pragma unroll
        for (int n = 0; n < 4; ++n)
          acc[m][n] = __builtin_amdgcn_mfma_f32_16x16x32_bf16(a[m], b[n], acc[m][n], 0, 0, 0);
    }
  }

  // epilogue: C row = (lane>>4)*4 + reg, col = lane&15 (m89-verified layout)
#pragma unroll
  for (int m = 0; m < 2; ++m) {
#pragma unroll
    for (int n = 0; n < 4; ++n) {
#pragma unroll
      for (int r = 0; r < 4; ++r) {
        int row = m0 + wr * 32 + m * 16 + (lane >> 4) * 4 + r;
        int col = n0 + wc * 64 + n * 16 + (lane & 15);
        float v = acc[m][n][r] + bias[col];
        int b = row >> 11, l = row & 2047, h = col >> 6, dd = col & 63;
        out[(size_t)((b * Hn + h) * Ln + l) * DKn + dd] = v;
      }
    }
  }
}

// ---------------------------------------------------------------------------
// vmean, two-stage
// ---------------------------------------------------------------------------
__global__ __launch_bounds__(256) void vmean1(const float* __restrict__ Vf,
                                              float* __restrict__ part)
{
  int bh = blockIdx.x, ch = blockIdx.y;       // 32 x 16
  int t = threadIdx.x;
  int d4 = t & 15, ls = t >> 4;
  const float* base = Vf + ((size_t)bh * Ln + ch * 128) * DKn;
  float4 s = make_float4(0.f, 0.f, 0.f, 0.f);
#pragma unroll
  for (int i = 0; i < 8; ++i) {
    float4 x = *reinterpret_cast<const float4*>(&base[(size_t)(ls + i * 16) * DKn + d4 * 4]);
    s.x += x.x; s.y += x.y; s.z += x.z; s.w += x.w;
  }
  __shared__ float4 red[16][16];
  red[ls][d4] = s;
  __syncthreads();
  if (t < 64) {
    int dd = t & 15, g = t >> 4;
    float4 a = red[g * 4 + 0][dd], b = red[g * 4 + 1][dd];
    float4 c = red[g * 4 + 2][dd], d = red[g * 4 + 3][dd];
    red[g * 4][dd] = make_float4(a.x + b.x + c.x + d.x, a.y + b.y + c.y + d.y,
                                 a.z + b.z + c.z + d.z, a.w + b.w + c.w + d.w);
  }
  __syncthreads();
  if (t < 16) {
    float4 a = red[0][t], b = red[4][t], c = red[8][t], d = red[12][t];
    float4 r = make_float4(a.x + b.x + c.x + d.x, a.y + b.y + c.y + d.y,
                           a.z + b.z + c.z + d.z, a.w + b.w + c.w + d.w);
    *reinterpret_cast<float4*>(&part[((size_t)(bh * 16 + ch)) * DKn + t * 4]) = r;
  }
}

__global__ __launch_bounds__(64) void vmean2(const float* __restrict__ part,
                                             float* __restrict__ meanV)
{
  int bh = blockIdx.x, d = threadIdx.x;
  float s = 0.f;
#pragma unroll
  for (int ch = 0; ch < 16; ++ch) s += part[((size_t)(bh * 16 + ch)) * DKn + d];
  meanV[bh * DKn + d] = s * (1.f / 2048.f);
}

// ---------------------------------------------------------------------------
// M[bh][q] = max_u(Q[q]·K[idx_u]) - sum_u(Q[q]·K[idx_u]) / LK
// ---------------------------------------------------------------------------
__global__ __launch_bounds__(256) void qk_sample_m2(const float* __restrict__ Qf,
    const float* __restrict__ Kf, const int* __restrict__ isamp,
    float* __restrict__ Mout)
{
  int wq = blockIdx.x * 4 + (threadIdx.x >> 6);  // global q over B*H*L
  int lane = threadIdx.x & 63;
  int g = lane >> 4, s = lane & 15;
  int bh = wq >> 11, q = wq & 2047;
  const float* Kb = Kf + (size_t)bh * Ln * DKn;
  float4 qv = *reinterpret_cast<const float4*>(&Qf[(size_t)(bh * Ln + q) * DKn + s * 4]);
  float mx = -INFINITY, sm = 0.f;
#pragma unroll
  for (int p = 0; p < 10; ++p) {
    int u = p * 4 + g;
    int idx = isamp[q * US + u];
    float4 kv = *reinterpret_cast<const float4*>(&Kb[(size_t)idx * DKn + s * 4]);
    float d = qv.x * kv.x + qv.y * kv.y + qv.z * kv.z + qv.w * kv.w;
#pragma unroll
    for (int off = 1; off < 16; off <<= 1) d += __shfl_xor(d, off);
    mx = fmaxf(mx, d);
    sm += d;
  }
#pragma unroll
  for (int off = 16; off <= 32; off <<= 1) {
    mx = fmaxf(mx, __shfl_xor(mx, off));
    sm += __shfl_xor(sm, off);
  }
  if (lane == 0) Mout[wq] = mx - sm * (1.f / 2048.f);
}

// ---------------------------------------------------------------------------
// top-40 of M[bh][0..2047] via radix-select (unchanged, ref-checked round 5)
// ---------------------------------------------------------------------------
__global__ __launch_bounds__(256) void topk40(const float* __restrict__ Mv,
                                              int* __restrict__ Mtop)
{
  int bh = blockIdx.x, tid = threadIdx.x;
  __shared__ unsigned hist[256];
  __shared__ unsigned sfx[256];
  __shared__ unsigned prefix_s, k_s;
  __shared__ int outcnt, tiecnt;
  __shared__ int tlist[256];

  unsigned key[8];
#pragma unroll
  for (int i = 0; i < 8; ++i) {
    unsigned u = __float_as_uint(Mv[bh * Ln + tid + i * 256]);
    key[i] = (u & 0x80000000u) ? ~u : (u | 0x80000000u);  // monotone inc map
  }
  if (tid == 0) { prefix_s = 0u; k_s = UT; outcnt = 0; tiecnt = 0; }
  __syncthreads();

  for (int d = 24; d >= 0; d -= 8) {
    hist[tid] = 0u;
    __syncthreads();
    unsigned pref = prefix_s;
    unsigned mask = (d == 24) ? 0u : (0xFFFFFFFFu << (d + 8));
#pragma unroll
    for (int i = 0; i < 8; ++i)
      if ((key[i] & mask) == pref) atomicAdd(&hist[(key[i] >> d) & 255u], 1u);
    __syncthreads();
    sfx[tid] = hist[tid];
    __syncthreads();
    for (int off = 1; off < 256; off <<= 1) {
      unsigned add = (tid + off < 256) ? sfx[tid + off] : 0u;
      __syncthreads();
      sfx[tid] += add;
      __syncthreads();
    }
    unsigned k = k_s;
    unsigned nxt = (tid < 255) ? sfx[tid + 1] : 0u;
    if (sfx[tid] >= k && nxt < k) {      // unique crossing bin
      prefix_s = pref | ((unsigned)tid << d);
      k_s = k - nxt;                      // still needed inside this bin
    }
    __syncthreads();
  }

  unsigned T = prefix_s;
  int kf = (int)k_s;                      // # to take among key == T
#pragma unroll
  for (int i = 0; i < 8; ++i) {
    int idx = tid + i * 256;
    if (key[i] > T) {
      int s = atomicAdd(&outcnt, 1);
      Mtop[bh * UT + s] = idx;
    } else if (key[i] == T) {
      int s = atomicAdd(&tiecnt, 1);
      if (s < 256) tlist[s] = idx;
    }
  }
  __syncthreads();
  if (tid == 0) {
    int n = tiecnt < 256 ? tiecnt : 256;
    int basep = outcnt;                   // = 40 - kf
    for (int a = 0; a < kf; ++a) {
      int best = 1 << 30, bj = 0;
      for (int j = 0; j < n; ++j)
        if (tlist[j] < best) { best = tlist[j]; bj = j; }
      Mtop[bh * UT + basep + a] = best;
      tlist[bj] = 1 << 30;
    }
  }
}

// ---------------------------------------------------------------------------
// Sparse attention: block (bh, c) handles CKn=64 keys for all 40 selected
// queries (unchanged from round 8)
// ---------------------------------------------------------------------------
__global__ __launch_bounds__(256) void attn_partial(const float* __restrict__ Qf,
    const float* __restrict__ Kf, const float* __restrict__ Vf,
    const int* __restrict__ Mtop, float* __restrict__ pmv,
    float* __restrict__ plv, float* __restrict__ pacc)
{
  const int bh = blockIdx.x, c = blockIdx.y;
  const int tid = threadIdx.x;
  const int w = tid >> 6, lane = tid & 63;
  __shared__ float sS[UT][CKn];     // 10 KB (scores -> exp(p))
  __shared__ float sK[CKn * DKn];   // 16 KB, XOR-swizzled (r&15)
  __shared__ int qidx[UT];

  if (tid < UT) qidx[tid] = Mtop[bh * UT + tid];
  const float* Kc = Kf + (size_t)(bh * Ln + c * CKn) * DKn;
  for (int i = tid; i < CKn * DKn; i += 256) {
    int r = i >> 6, d = i & 63;
    sK[r * 64 + (d ^ ((r & 15) << 2))] = Kc[(size_t)r * DKn + d];
  }
  __syncthreads();

  // QK^T: i = w + 4*it (wave-uniform row), kk = lane (key)
  const float* Qb = Qf + (size_t)bh * Ln * DKn;
  for (int it = 0; it < 10; ++it) {
    int i = w + it * 4, kk = lane;
    const float* Qrow = Qb + (size_t)qidx[i] * DKn;   // wave-uniform
    float s = 0.f;
#pragma unroll
    for (int g = 0; g < 16; ++g) {
      float4 qv = *reinterpret_cast<const float4*>(&Qrow[g * 4]);
      float4 kv = *reinterpret_cast<const float4*>(&sK[kk * 64 + ((g * 4) ^ ((kk & 15) << 2))]);
      s += qv.x * kv.x + qv.y * kv.y + qv.z * kv.z + qv.w * kv.w;
    }
    sS[i][kk] = s * 0.125f;
  }
  __syncthreads();

  // partial softmax per row (64 scores, one per lane)
  for (int it = 0; it < 10; ++it) {
    int i = w + it * 4;
    float s0 = sS[i][lane];
    float mx = s0;
#pragma unroll
    for (int off = 32; off; off >>= 1) mx = fmaxf(mx, __shfl_xor(mx, off));
    float p0 = expf(s0 - mx);
    sS[i][lane] = p0;
    float ls = p0;
#pragma unroll
    for (int off = 32; off; off >>= 1) ls += __shfl_xor(ls, off);
    if (lane == 0) {
      pmv[(bh * NCk + c) * UT + i] = mx;
      plv[(bh * NCk + c) * UT + i] = ls;
    }
  }
  __syncthreads();

  // PV partial: lane = (ksub, dq); V read straight from global (coalesced)
  const int ksub = lane >> 4, dq = lane & 15;
  const float* Vc = Vf + (size_t)(bh * Ln + c * CKn) * DKn;
  float4 acc[10];
#pragma unroll
  for (int t = 0; t < 10; ++t) acc[t] = make_float4(0.f, 0.f, 0.f, 0.f);
  for (int ko = 0; ko < 16; ++ko) {
    int kk = ko * 4 + ksub;
    float4 v4 = *reinterpret_cast<const float4*>(&Vc[(size_t)kk * DKn + dq * 4]);
#pragma unroll
    for (int t = 0; t < 10; ++t) {
      float wgt = sS[w + t * 4][kk];
      acc[t].x += wgt * v4.x; acc[t].y += wgt * v4.y;
      acc[t].z += wgt * v4.z; acc[t].w += wgt * v4.w;
    }
  }
#pragma unroll
  for (int t = 0; t < 10; ++t) {
#pragma unroll
    for (int off = 16; off <= 32; off <<= 1) {
      acc[t].x += __shfl_xor(acc[t].x, off);
      acc[t].y += __shfl_xor(acc[t].y, off);
      acc[t].z += __shfl_xor(acc[t].z, off);
      acc[t].w += __shfl_xor(acc[t].w, off);
    }
  }
  if (ksub == 0) {
#pragma unroll
    for (int t = 0; t < 10; ++t) {
      int i = w + t * 4;
      *reinterpret_cast<float4*>(&pacc[(size_t)((bh * NCk + c) * UT + i) * DKn + dq * 4]) = acc[t];
    }
  }
}

// ---------------------------------------------------------------------------
// base[b][n] = meanrow_b @ Wo.T + bo
// ---------------------------------------------------------------------------
__global__ __launch_bounds__(256) void base_proj(const float* __restrict__ meanV,
    const float* __restrict__ Wo, const float* __restrict__ bo,
    float* __restrict__ base)
{
  int b = blockIdx.x, tid = threadIdx.x;
#pragma unroll
  for (int rep = 0; rep < 2; ++rep) {
    int n = tid + rep * 256;
    float s = bo[n];
#pragma unroll 8
    for (int g = 0; g < 128; ++g) {
      float4 wv = *reinterpret_cast<const float4*>(&Wo[(size_t)n * Dn + g * 4]);
      float4 mv = *reinterpret_cast<const float4*>(&meanV[b * Dn + g * 4]);
      s += wv.x * mv.x + wv.y * mv.y + wv.z * mv.z + wv.w * mv.w;
    }
    base[b * Dn + n] = s;
  }
}

__global__ __launch_bounds__(256) void base_fill(const float* __restrict__ base,
                                                 float* __restrict__ out)
{
  int idx = blockIdx.x * 256 + threadIdx.x;  // float4 index, 1048576 total
  int row = idx >> 7, col4 = idx & 127;
  int b = row >> 11;
  reinterpret_cast<float4*>(out)[idx] =
      reinterpret_cast<const float4*>(base)[b * 128 + col4];
}

// ---------------------------------------------------------------------------
// combine_ctx: reduce 32 chunk-partials -> delta rows ctxd[bh][40][64].
// ---------------------------------------------------------------------------
__global__ __launch_bounds__(256) void combine_ctx(const float* __restrict__ pmv,
    const float* __restrict__ plv, const float* __restrict__ pacc,
    const float* __restrict__ meanV, float* __restrict__ ctxd)
{
  int bh = blockIdx.x, tid = threadIdx.x;
  __shared__ float ew[UT][NCk];    // 5 KB: per-row chunk weights e
  __shared__ float den_s[UT];
  if (tid < UT) {
    float mg = -INFINITY;
#pragma unroll
    for (int cc = 0; cc < NCk; ++cc)
      mg = fmaxf(mg, pmv[(bh * NCk + cc) * UT + tid]);
    float den = 0.f;
#pragma unroll
    for (int cc = 0; cc < NCk; ++cc) {
      float e = expf(pmv[(bh * NCk + cc) * UT + tid] - mg);
      ew[tid][cc] = e;
      den += plv[(bh * NCk + cc) * UT + tid] * e;
    }
    den_s[tid] = den;
  }
  __syncthreads();
  for (int v = tid; v < UT * DKn; v += 256) {
    int i = v >> 6, d = v & 63;
    float num = 0.f;
#pragma unroll
    for (int cc = 0; cc < NCk; ++cc)
      num += ew[i][cc] * pacc[(size_t)((bh * NCk + cc) * UT + i) * DKn + d];
    ctxd[(size_t)(bh * UT + i) * DKn + d] = num / den_s[i] - meanV[bh * DKn + d];
  }
}

// ---------------------------------------------------------------------------
// scatter_proj: out[b, q_i, n] += dot(ctxd[bh][i][:], Wo[n][h*64:...]).
// ---------------------------------------------------------------------------
__global__ __launch_bounds__(256) void scatter_proj(const float* __restrict__ ctxd,
    const int* __restrict__ Mtop, const float* __restrict__ Wo,
    float* __restrict__ out)
{
  int nc = blockIdx.x, bh = blockIdx.y;
  int b = bh >> 3, h = bh & 7;
  int tid = threadIdx.x;
  __shared__ float sd[UT][DKn];    // 10 KB
  __shared__ int qidx[UT];
  for (int v = tid; v < UT * DKn; v += 256)
    sd[v >> 6][v & 63] = ctxd[(size_t)(bh * UT) * DKn + v];
  if (tid < UT) qidx[tid] = Mtop[bh * UT + tid];
  __syncthreads();

  int n = nc * 64 + (tid & 63);
  int i0 = tid >> 6;                       // 0..3
  const float* Wrow = Wo + (size_t)n * Dn + h * DKn;
  float4 wv[16];
#pragma unroll
  for (int g = 0; g < 16; ++g)
    wv[g] = *reinterpret_cast<const float4*>(&Wrow[g * 4]);

#pragma unroll
  for (int t = 0; t < 10; ++t) {
    int i = i0 + t * 4;
    float s = 0.f;
#pragma unroll
    for (int g = 0; g < 16; ++g) {
      float4 dv = *reinterpret_cast<const float4*>(&sd[i][g * 4]);
      s += wv[g].x * dv.x + wv[g].y * dv.y + wv[g].z * dv.z + wv[g].w * dv.w;
    }
    atomicAdd(&out[(size_t)(b * Ln + qidx[i]) * Dn + n], s);
  }
}

// ---------------------------------------------------------------------------
extern "C" void kernel_launch(void* const* d_in, const int* in_sizes, int n_in,
                              void* d_out, int out_size, void* d_ws, size_t ws_size,
                              hipStream_t stream)
{
  const float* queries = (const float*)d_in[0];
  const float* keys    = (const float*)d_in[1];
  const float* values  = (const float*)d_in[2];
  const float* Wq = (const float*)d_in[3];
  const float* bq = (const float*)d_in[4];
  const float* Wk = (const float*)d_in[5];
  const float* bk = (const float*)d_in[6];
  const float* Wv = (const float*)d_in[7];
  const float* bv = (const float*)d_in[8];
  const float* Wo = (const float*)d_in[9];
  const float* bo = (const float*)d_in[10];
  const int* isamp = (const int*)d_in[11];
  float* out = (float*)d_out;

  float* ws = (float*)d_ws;
  const size_t NBL = (size_t)Bn * Hn * Ln * DKn;  // 4194304
  float* Qf    = ws;                              // QKVf base (z-contiguous)
  float* Kf    = Qf + NBL;
  float* Vf    = Kf + NBL;
  float* meanV = Vf + NBL;                        // 2048
  float* Mv    = meanV + Bn * Hn * DKn;           // 65536
  float* pmv   = Mv + Bn * Hn * Ln;               // 40960
  float* plv   = pmv + Bn * Hn * NCk * UT;        // 40960
  float* base  = plv + Bn * Hn * NCk * UT;        // 2048
  int* Mtop    = (int*)(base + Bn * Dn);          // 1280 ints
  float* ctxd  = (float*)(Mtop + Bn * Hn * UT);   // 81920 floats
  ushort_t* AcatAll = (ushort_t*)(ctxd + (size_t)Bn * Hn * UT * DKn); // 3x8192x1024
  ushort_t* WcatAll = AcatAll + (size_t)3 * 8192 * 1024;   // 3x512x1536
  float* vpart = (float*)(WcatAll + (size_t)3 * 512 * 1536);  // 32*16*64
  // pacc (10.5 MB) aliases AcatAll (50 MB): AcatAll's last reader is
  // gemm3_bf16_all, stream-ordered before attn_partial writes pacc.
  float* pacc  = (float*)AcatAll;

  split_in3<<<dim3(4096, 3), 256, 0, stream>>>(queries, keys, values, AcatAll);
  split_w3<<<dim3(256, 3), 256, 0, stream>>>(Wq, Wk, Wv, WcatAll);
  gemm3_bf16_all<<<dim3(4, 128, 3), 256, 0, stream>>>(AcatAll, WcatAll, bq, bk, bv, Qf);

  vmean1<<<dim3(Bn * Hn, 16), 256, 0, stream>>>(Vf, vpart);
  vmean2<<<Bn * Hn, 64, 0, stream>>>(vpart, meanV);
  qk_sample_m2<<<Bn * Hn * Ln / 4, 256, 0, stream>>>(Qf, Kf, isamp, Mv);
  topk40<<<Bn * Hn, 256, 0, stream>>>(Mv, Mtop);
  attn_partial<<<dim3(Bn * Hn, NCk), 256, 0, stream>>>(Qf, Kf, Vf, Mtop, pmv, plv, pacc);
  base_proj<<<Bn, 256, 0, stream>>>(meanV, Wo, bo, base);
  base_fill<<<4096, 256, 0, stream>>>(base, out);
  combine_ctx<<<Bn * Hn, 256, 0, stream>>>(pmv, plv, pacc, meanV, ctxd);
  scatter_proj<<<dim3(8, Bn * Hn), 256, 0, stream>>>(ctxd, Mtop, Wo, out);
}